// Round 1
// baseline (2014.171 us; speedup 1.0000x reference)
//
#include <hip/hip_runtime.h>
#include <cstddef>

// MVMGIN: temporal GNN forward. f32 baseline, algebraically restructured:
//  - attention K/V never materialized: scores via (q@Wk1)·sf + (q@Wk2)·df; V-path
//    folded into two HxH mats A1m=Wo_l@Wv1, A2m=Wo_l@Wv2 (softmax weights sum to 1).
//  - bk_l / bk_g dropped (constant across V -> cancel in softmax).
// Outputs (f32, concat): logits(E,5) | ew(E,8) | h_before(N,8,128) | a_g(E,8)

#define HSZ 128
#define VSZ 8

__device__ __forceinline__ float sigm(float x) { return 1.f / (1.f + __expf(-x)); }

// ---------------- generic f32 tiled GEMM ----------------
// out(M,Nout) = ACT( Asrc(M,K) @ Wop(K,Nout) + bias ) [+ out when ACC]
//  WT:  Wop[k][n] = W[n*K + k]      (out = A @ W^T, W row-major (Nout,K))
//  !WT: Wop[k][n] = W[k*ldw + n]
//  ASRC: 0=A1, 1=A1+A2 (same shape), 2=A1 + rowvec A2[k], 3=concat{A1,A2,A3} each width 128
template<int ASRC, int ACT, bool ACC, bool WT>
__global__ __launch_bounds__(256) void gemm_f32(
    const float* __restrict__ A1, const float* __restrict__ A2, const float* __restrict__ A3,
    const float* __restrict__ W, const float* __restrict__ bias,
    float* __restrict__ out, int M, int K, int Nout, int ldw)
{
  __shared__ float As[64][65];   // pad 65: 2-way LDS aliasing only (free)
  __shared__ float Ws[64][65];
  const int m0 = blockIdx.x * 64;
  const int n0 = blockIdx.y * 64;
  const int tid = threadIdx.x;
  const int ty = tid >> 4, tx = tid & 15;
  float acc[4][4] = {};
  for (int k0 = 0; k0 < K; k0 += 64) {
    for (int idx = tid; idx < 4096; idx += 256) {
      int r = idx >> 6, c = idx & 63;
      int m = m0 + r, k = k0 + c;
      float v = 0.f;
      if (m < M && k < K) {
        if (ASRC == 0)      v = A1[(size_t)m * K + k];
        else if (ASRC == 1) v = A1[(size_t)m * K + k] + A2[(size_t)m * K + k];
        else if (ASRC == 2) v = A1[(size_t)m * K + k] + A2[k];
        else { const float* S = (k < 128) ? A1 : (k < 256) ? A2 : A3;
               v = S[(size_t)m * 128 + (k & 127)]; }
      }
      As[r][c] = v;
    }
    if (WT) {
      for (int idx = tid; idx < 4096; idx += 256) {
        int kk = idx & 63, n = idx >> 6;
        int k = k0 + kk, nn = n0 + n;
        Ws[kk][n] = (k < K && nn < Nout) ? W[(size_t)nn * K + k] : 0.f;
      }
    } else {
      for (int idx = tid; idx < 4096; idx += 256) {
        int n = idx & 63, kk = idx >> 6;
        int k = k0 + kk, nn = n0 + n;
        Ws[kk][n] = (k < K && nn < Nout) ? W[(size_t)k * ldw + nn] : 0.f;
      }
    }
    __syncthreads();
    #pragma unroll 8
    for (int kk = 0; kk < 64; ++kk) {
      float a[4], b[4];
      #pragma unroll
      for (int i = 0; i < 4; ++i) a[i] = As[ty * 4 + i][kk];
      #pragma unroll
      for (int j = 0; j < 4; ++j) b[j] = Ws[kk][tx * 4 + j];
      #pragma unroll
      for (int i = 0; i < 4; ++i)
        #pragma unroll
        for (int j = 0; j < 4; ++j) acc[i][j] += a[i] * b[j];
    }
    __syncthreads();
  }
  #pragma unroll
  for (int i = 0; i < 4; ++i) {
    int m = m0 + ty * 4 + i;
    if (m >= M) continue;
    #pragma unroll
    for (int j = 0; j < 4; ++j) {
      int n = n0 + tx * 4 + j;
      if (n >= Nout) continue;
      float v = acc[i][j];
      if (bias) v += bias[n];
      size_t o = (size_t)m * Nout + n;
      if (ACC) v += out[o];
      if (ACT == 1) v = fmaxf(v, 0.f);
      out[o] = v;
    }
  }
}

// ---------------- edge gate: ew = sigmoid([ea, memory[src]] @ W_ewg^T + b) ----------------
__global__ __launch_bounds__(256) void k_ew(const float* __restrict__ ea,
    const float* __restrict__ memory, const int* __restrict__ srcI,
    const float* __restrict__ W_ewg, const float* __restrict__ b_ewg,
    float* __restrict__ ew, int E)
{
  __shared__ float Wsh[2048];
  __shared__ float bsh[8];
  int tid = threadIdx.x;
  for (int i = tid; i < 2048; i += 256) Wsh[i] = W_ewg[i];
  if (tid < 8) bsh[tid] = b_ewg[tid];
  __syncthreads();
  int wv = tid >> 6, lane = tid & 63;
  int e = blockIdx.x * 4 + wv;
  if (e >= E) return;
  int s = srcI[e];
  float c0 = ea[(size_t)e * 128 + lane];
  float c1 = ea[(size_t)e * 128 + 64 + lane];
  float c2 = memory[(size_t)s * 128 + lane];
  float c3 = memory[(size_t)s * 128 + 64 + lane];
  #pragma unroll
  for (int v = 0; v < 8; ++v) {
    float p = c0 * Wsh[v * 256 + lane] + c1 * Wsh[v * 256 + 64 + lane]
            + c2 * Wsh[v * 256 + 128 + lane] + c3 * Wsh[v * 256 + 192 + lane];
    #pragma unroll
    for (int o = 32; o; o >>= 1) p += __shfl_down(p, o);
    if (lane == 0) ew[(size_t)e * 8 + v] = sigm(p + bsh[v]);
  }
}

// ---------------- h init: broadcast memory over V ----------------
__global__ void k_hinit(const float* __restrict__ memory, float* __restrict__ h, int total)
{
  int idx = blockIdx.x * 256 + threadIdx.x;
  if (idx >= total) return;
  h[idx] = memory[(size_t)(idx >> 10) * 128 + (idx & 127)];
}

// ---------------- GIN message + scatter-add ----------------
__global__ __launch_bounds__(256) void k_msg(const float* __restrict__ h,
    const float* __restrict__ ea, const float* __restrict__ ew,
    const int* __restrict__ srcI, const int* __restrict__ dstI,
    float* __restrict__ agg, int E)
{
  __shared__ float eas[128];
  __shared__ float ews[8];
  int e = blockIdx.x;
  int tid = threadIdx.x;
  if (tid < 128) eas[tid] = ea[(size_t)e * 128 + tid];
  if (tid < 8) ews[tid] = ew[(size_t)e * 8 + tid];
  __syncthreads();
  int s = srcI[e], d = dstI[e];               // cs=dst, cd=src per reference
  const float* hd = h + (size_t)d * 1024;
  float* ag = agg + (size_t)s * 1024;
  #pragma unroll
  for (int i = 0; i < 4; ++i) {
    int idx = i * 256 + tid;
    int x = idx & 127, v = idx >> 7;
    float m = fmaxf(hd[idx] + eas[x], 0.f) * ews[v];
    atomicAdd(&ag[idx], m);
  }
}

// ---------------- te = sin(dt * W_t + b_t) ----------------
__global__ void k_te(const float* __restrict__ delta_t, const float* __restrict__ W_t,
                     const float* __restrict__ b_t, float* __restrict__ te)
{
  int t = threadIdx.x;
  if (t < 128) te[t] = sinf(delta_t[0] * W_t[t] + b_t[t]);
}

// ---------------- GRU elementwise ----------------
__global__ void k_gru(const float* __restrict__ gi, const float* __restrict__ gh,
                      const float* __restrict__ memory, float* __restrict__ h_new, int total)
{
  int idx = blockIdx.x * 256 + threadIdx.x;
  if (idx >= total) return;
  int n = idx >> 10, x = idx & 127, row = idx >> 7;
  size_t gio = (size_t)row * 384 + x;
  size_t gho = (size_t)n * 384 + x;
  float r = sigm(gi[gio] + gh[gho]);
  float z = sigm(gi[gio + 128] + gh[gho + 128]);
  float nn = tanhf(gi[gio + 256] + r * gh[gho + 256]);
  float mem = memory[(size_t)n * 128 + x];
  h_new[idx] = (1.f - z) * nn + z * mem;
}

// ---------------- pooled partial sums ----------------
__global__ __launch_bounds__(256) void k_pool(const float* __restrict__ h_new,
                                              float* __restrict__ prw, int N)
{
  int tid = threadIdx.x;
  float acc[4] = {0.f, 0.f, 0.f, 0.f};
  for (int n = blockIdx.x; n < N; n += gridDim.x) {
    const float* row = h_new + (size_t)n * 1024;
    #pragma unroll
    for (int j = 0; j < 4; ++j) acc[j] += row[tid + j * 256];
  }
  #pragma unroll
  for (int j = 0; j < 4; ++j) atomicAdd(&prw[tid + j * 256], acc[j]);
}

// ---------------- A1m = Wo_l@Wv1, A2m = Wo_l@Wv2, blv = Wo_l@bv_l + bo_l ----------------
__global__ __launch_bounds__(256) void k_smallmats(const float* __restrict__ Wo_l,
    const float* __restrict__ Wv_l, const float* __restrict__ bv_l, const float* __restrict__ bo_l,
    float* __restrict__ A1m, float* __restrict__ A2m, float* __restrict__ blv)
{
  int idx = blockIdx.x * 256 + threadIdx.x;      // 32768 = 2 * 128 * 128
  int which = idx >> 14, rem = idx & 16383, i = rem >> 7, j = rem & 127;
  const float* wo = Wo_l + (size_t)i * 128;
  float a = 0.f;
  for (int k = 0; k < 128; ++k) a += wo[k] * Wv_l[(size_t)k * 256 + which * 128 + j];
  (which ? A2m : A1m)[rem] = a;
  if (blockIdx.x == 0 && threadIdx.x < 128) {
    int i2 = threadIdx.x;
    float b = bo_l[i2];
    for (int k = 0; k < 128; ++k) b += Wo_l[(size_t)i2 * 128 + k] * bv_l[k];
    blv[i2] = b;
  }
}

// ---------------- Kg = pooled@Wk_g^T (no bias: cancels), G = (pooled@Wv_g^T+bv_g)@Wo_g^T ----------------
__global__ __launch_bounds__(256) void k_kgg(const float* __restrict__ prw,
    const float* __restrict__ Wk_g, const float* __restrict__ Wv_g, const float* __restrict__ bv_g,
    const float* __restrict__ Wo_g, float* __restrict__ Kg, float* __restrict__ G, int N)
{
  __shared__ float pl[1024];
  __shared__ float vg[1024];
  int tid = threadIdx.x;
  float invN = 1.f / (float)N;
  for (int i = tid; i < 1024; i += 256) pl[i] = prw[i] * invN;
  __syncthreads();
  for (int o = tid; o < 1024; o += 256) {
    int v = o >> 7, x = o & 127;
    float a = 0.f, b = 0.f;
    for (int k = 0; k < 128; ++k) {
      float p = pl[v * 128 + k];
      a += p * Wk_g[(size_t)x * 128 + k];
      b += p * Wv_g[(size_t)x * 128 + k];
    }
    Kg[o] = a;
    vg[o] = b + bv_g[x];
  }
  __syncthreads();
  for (int o = tid; o < 1024; o += 256) {
    int v = o >> 7, x = o & 127;
    float a = 0.f;
    for (int k = 0; k < 128; ++k) a += vg[v * 128 + k] * Wo_g[(size_t)x * 128 + k];
    G[o] = a;
  }
}

// ---------------- fused local attention: scores->softmax->weighted sums ----------------
__global__ __launch_bounds__(256) void k_local(const float* __restrict__ h_new,
    const float* __restrict__ qk1, const float* __restrict__ qk2,
    const int* __restrict__ srcI, const int* __restrict__ dstI,
    float* __restrict__ wsb, float* __restrict__ wdb, int E)
{
  __shared__ float sf[1024], df[1024], q1[128], q2[128], sc[8];
  int e = blockIdx.x;
  int tid = threadIdx.x;
  int s = srcI[e], d = dstI[e];
  const float* hs = h_new + (size_t)s * 1024;
  const float* hd = h_new + (size_t)d * 1024;
  for (int i = tid; i < 1024; i += 256) { sf[i] = hs[i]; df[i] = hd[i]; }
  if (tid < 128) { q1[tid] = qk1[(size_t)e * 128 + tid]; q2[tid] = qk2[(size_t)e * 128 + tid]; }
  __syncthreads();
  int wv = tid >> 6, lane = tid & 63;
  for (int v = wv; v < 8; v += 4) {
    float p = q1[lane] * sf[v * 128 + lane] + q1[64 + lane] * sf[v * 128 + 64 + lane]
            + q2[lane] * df[v * 128 + lane] + q2[64 + lane] * df[v * 128 + 64 + lane];
    #pragma unroll
    for (int o = 32; o; o >>= 1) p += __shfl_down(p, o);
    if (lane == 0) sc[v] = p * 0.08838834764831845f;   // 1/sqrt(128)
  }
  __syncthreads();
  float mx = sc[0];
  #pragma unroll
  for (int v = 1; v < 8; ++v) mx = fmaxf(mx, sc[v]);
  float a[8], sum = 0.f;
  #pragma unroll
  for (int v = 0; v < 8; ++v) { a[v] = __expf(sc[v] - mx); sum += a[v]; }
  float inv = 1.f / sum;
  int x = tid & 127;
  const float* mat = (tid < 128) ? sf : df;
  float accv = 0.f;
  #pragma unroll
  for (int v = 0; v < 8; ++v) accv += a[v] * mat[v * 128 + x];
  ((tid < 128) ? wsb : wdb)[(size_t)e * 128 + x] = accv * inv;
}

// ---------------- global attention: a_g + global_out ----------------
__global__ __launch_bounds__(256) void k_global(const float* __restrict__ q_g,
    const float* __restrict__ Kg, const float* __restrict__ G, const float* __restrict__ bo_g,
    float* __restrict__ ag_out, float* __restrict__ gout, int E)
{
  __shared__ float Kgs[1024], Gs[1024], bs[128];
  int tid = threadIdx.x;
  for (int i = tid; i < 1024; i += 256) { Kgs[i] = Kg[i]; Gs[i] = G[i]; }
  if (tid < 128) bs[tid] = bo_g[tid];
  __syncthreads();
  int wv = tid >> 6, lane = tid & 63;
  int e = blockIdx.x * 4 + wv;
  if (e >= E) return;
  float qa = q_g[(size_t)e * 128 + lane], qb = q_g[(size_t)e * 128 + 64 + lane];
  float s[8];
  #pragma unroll
  for (int v = 0; v < 8; ++v) {
    float p = qa * Kgs[v * 128 + lane] + qb * Kgs[v * 128 + 64 + lane];
    #pragma unroll
    for (int o = 32; o; o >>= 1) p += __shfl_xor(p, o);
    s[v] = p * 0.08838834764831845f;
  }
  float mx = s[0];
  #pragma unroll
  for (int v = 1; v < 8; ++v) mx = fmaxf(mx, s[v]);
  float sum = 0.f;
  #pragma unroll
  for (int v = 0; v < 8; ++v) { s[v] = __expf(s[v] - mx); sum += s[v]; }
  float inv = 1.f / sum;
  #pragma unroll
  for (int v = 0; v < 8; ++v) s[v] *= inv;
  #pragma unroll
  for (int v = 0; v < 8; ++v) if (lane == v) ag_out[(size_t)e * 8 + v] = s[v];
  float g0 = bs[lane], g1 = bs[64 + lane];
  #pragma unroll
  for (int v = 0; v < 8; ++v) {
    g0 += s[v] * Gs[v * 128 + lane];
    g1 += s[v] * Gs[v * 128 + 64 + lane];
  }
  gout[(size_t)e * 128 + lane] = g0;
  gout[(size_t)e * 128 + 64 + lane] = g1;
}

// ---------------- logits = hid @ Wc2^T + bc2 ----------------
__global__ __launch_bounds__(256) void k_logits(const float* __restrict__ hid,
    const float* __restrict__ Wc2, const float* __restrict__ bc2,
    float* __restrict__ logits, int E)
{
  __shared__ float Wsh[640];
  __shared__ float bsh[5];
  int tid = threadIdx.x;
  for (int i = tid; i < 640; i += 256) Wsh[i] = Wc2[i];
  if (tid < 5) bsh[tid] = bc2[tid];
  __syncthreads();
  int wv = tid >> 6, lane = tid & 63;
  int e = blockIdx.x * 4 + wv;
  if (e >= E) return;
  float h0 = hid[(size_t)e * 128 + lane], h1 = hid[(size_t)e * 128 + 64 + lane];
  #pragma unroll
  for (int c = 0; c < 5; ++c) {
    float p = h0 * Wsh[c * 128 + lane] + h1 * Wsh[c * 128 + 64 + lane];
    #pragma unroll
    for (int o = 32; o; o >>= 1) p += __shfl_down(p, o);
    if (lane == 0) logits[(size_t)e * 5 + c] = p + bsh[c];
  }
}

extern "C" void kernel_launch(void* const* d_in, const int* in_sizes, int n_in,
                              void* d_out, int out_size, void* d_ws, size_t ws_size,
                              hipStream_t stream)
{
  const int*   edge_index = (const int*)d_in[0];
  const float* edge_attr  = (const float*)d_in[1];
  const float* delta_t    = (const float*)d_in[2];
  const float* memory     = (const float*)d_in[3];
  const float* W_ee  = (const float*)d_in[4];
  const float* b_ee  = (const float*)d_in[5];
  const float* W_ewg = (const float*)d_in[6];
  const float* b_ewg = (const float*)d_in[7];
  const float* gin_W1 = (const float*)d_in[8];
  const float* gin_b1 = (const float*)d_in[9];
  const float* gin_W2 = (const float*)d_in[10];
  const float* gin_b2 = (const float*)d_in[11];
  const float* W_t  = (const float*)d_in[12];
  const float* b_t  = (const float*)d_in[13];
  const float* W_ih = (const float*)d_in[14];
  const float* b_ih = (const float*)d_in[15];
  const float* W_hh = (const float*)d_in[16];
  const float* b_hh = (const float*)d_in[17];
  // d_in[18], d_in[19] = W_up, b_up: unused by the reference
  const float* Wq_l = (const float*)d_in[20];
  const float* bq_l = (const float*)d_in[21];
  const float* Wk_l = (const float*)d_in[22];
  // bk_l (23) cancels in softmax
  const float* Wv_l = (const float*)d_in[24];
  const float* bv_l = (const float*)d_in[25];
  const float* Wo_l = (const float*)d_in[26];
  const float* bo_l = (const float*)d_in[27];
  const float* Wq_g = (const float*)d_in[28];
  const float* bq_g = (const float*)d_in[29];
  const float* Wk_g = (const float*)d_in[30];
  // bk_g (31) cancels in softmax
  const float* Wv_g = (const float*)d_in[32];
  const float* bv_g = (const float*)d_in[33];
  const float* Wo_g = (const float*)d_in[34];
  const float* bo_g = (const float*)d_in[35];
  const float* Wc1  = (const float*)d_in[36];
  const float* bc1  = (const float*)d_in[37];
  const float* Wc2  = (const float*)d_in[38];
  const float* bc2  = (const float*)d_in[39];

  const int E = in_sizes[0] / 2;
  const int N = in_sizes[3] / HSZ;
  const int* srcI = edge_index;
  const int* dstI = edge_index + E;

  float* out    = (float*)d_out;
  float* logits = out;
  float* ew     = out + (size_t)E * 5;
  float* h      = out + (size_t)E * 13;                       // h_before lives in d_out
  float* ag_out = out + (size_t)E * 13 + (size_t)N * 1024;

  // ---- workspace arena (lifetime-overlapped) ----
  float* ws = (float*)d_ws;
  size_t off = 0;
  auto alloc = [&](size_t n) { size_t o = off; off += (n + 255) & ~(size_t)255; return o; };
  float* te   = ws + alloc(128);
  float* A1m  = ws + alloc(16384);
  float* A2m  = ws + alloc(16384);
  float* blv  = ws + alloc(128);
  float* Kg   = ws + alloc(1024);
  float* G    = ws + alloc(1024);
  float* prw  = ws + alloc(1024);
  const size_t EH = (size_t)E * 128;
  float* ea    = ws + alloc(EH);
  float* h_new = ws + alloc((size_t)N * 1024);
  float* gh    = ws + alloc((size_t)N * 384);
  size_t brA = (size_t)2 * N * 1024;     // agg + gtmp
  size_t brB = (size_t)N * 8 * 384;      // gi
  size_t brC = 5 * EH;                   // attention peak
  size_t brsz = brA > brB ? brA : brB; if (brC > brsz) brsz = brC;
  float* BR = ws + alloc(brsz);
  if (ws_size < off * sizeof(float)) return;   // needs ~201 MiB

  // BR aliases (sequential-stream lifetimes, all disjoint in time):
  float* agg   = BR;                 // GIN
  float* gtmp  = BR + (size_t)N * 1024;
  float* gi    = BR;                 // GRU
  float* q_l   = BR;                 // attention
  float* qk1   = BR + EH;
  float* qk2   = BR + 2 * EH;
  float* wsb   = BR;                 // overwrites q_l (dead after qk1/qk2)
  float* wdb   = BR + 3 * EH;
  float* lclb  = BR + 4 * EH;
  float* q_g   = BR;                 // overwrites wsb (dead after local GEMMs)
  float* glbb  = BR + EH;            // overwrites qk1
  float* hid   = BR + 2 * EH;        // overwrites qk2

  auto cdiv = [](int a, int b) { return (a + b - 1) / b; };

  // 1. ea = relu(edge_attr @ W_ee^T + b_ee)     (E,59)@(59,128)
  gemm_f32<0, 1, false, true><<<dim3(cdiv(E, 64), 2), 256, 0, stream>>>(
      edge_attr, nullptr, nullptr, W_ee, b_ee, ea, E, 59, 128, 0);
  // 2. ew
  k_ew<<<cdiv(E, 4), 256, 0, stream>>>(ea, memory, srcI, W_ewg, b_ewg, ew, E);
  // 3. h init
  k_hinit<<<cdiv(N * 1024, 256), 256, 0, stream>>>(memory, h, N * 1024);
  // 4. te
  k_te<<<1, 128, 0, stream>>>(delta_t, W_t, b_t, te);
  // 5. GIN layers
  for (int l = 0; l < 2; ++l) {
    hipMemsetAsync(agg, 0, (size_t)N * 1024 * sizeof(float), stream);
    k_msg<<<E, 256, 0, stream>>>(h, ea, ew, srcI, dstI, agg, E);
    gemm_f32<1, 1, false, true><<<dim3(cdiv(N * 8, 64), 2), 256, 0, stream>>>(
        h, agg, nullptr, gin_W1 + l * 16384, gin_b1 + l * 128, gtmp, N * 8, 128, 128, 0);
    gemm_f32<0, 0, true, true><<<dim3(cdiv(N * 8, 64), 2), 256, 0, stream>>>(
        gtmp, nullptr, nullptr, gin_W2 + l * 16384, gin_b2 + l * 128, h, N * 8, 128, 128, 0);
  }
  // 6. GRU
  gemm_f32<0, 0, false, true><<<dim3(cdiv(N, 64), 6), 256, 0, stream>>>(
      memory, nullptr, nullptr, W_hh, b_hh, gh, N, 128, 384, 0);
  gemm_f32<2, 0, false, true><<<dim3(cdiv(N * 8, 64), 6), 256, 0, stream>>>(
      h, te, nullptr, W_ih, b_ih, gi, N * 8, 128, 384, 0);
  k_gru<<<cdiv(N * 1024, 256), 256, 0, stream>>>(gi, gh, memory, h_new, N * 1024);
  // 7. pooled + small fused mats
  hipMemsetAsync(prw, 0, 1024 * sizeof(float), stream);
  k_pool<<<256, 256, 0, stream>>>(h_new, prw, N);
  k_smallmats<<<128, 256, 0, stream>>>(Wo_l, Wv_l, bv_l, bo_l, A1m, A2m, blv);
  k_kgg<<<1, 256, 0, stream>>>(prw, Wk_g, Wv_g, bv_g, Wo_g, Kg, G, N);
  // 8. local attention
  gemm_f32<0, 0, false, true><<<dim3(cdiv(E, 64), 2), 256, 0, stream>>>(
      ea, nullptr, nullptr, Wq_l, bq_l, q_l, E, 128, 128, 0);
  gemm_f32<0, 0, false, false><<<dim3(cdiv(E, 64), 2), 256, 0, stream>>>(
      q_l, nullptr, nullptr, Wk_l, nullptr, qk1, E, 128, 128, 256);
  gemm_f32<0, 0, false, false><<<dim3(cdiv(E, 64), 2), 256, 0, stream>>>(
      q_l, nullptr, nullptr, Wk_l + 128, nullptr, qk2, E, 128, 128, 256);
  k_local<<<E, 256, 0, stream>>>(h_new, qk1, qk2, srcI, dstI, wsb, wdb, E);
  gemm_f32<0, 0, false, true><<<dim3(cdiv(E, 64), 2), 256, 0, stream>>>(
      wsb, nullptr, nullptr, A1m, blv, lclb, E, 128, 128, 0);
  gemm_f32<0, 0, true, true><<<dim3(cdiv(E, 64), 2), 256, 0, stream>>>(
      wdb, nullptr, nullptr, A2m, nullptr, lclb, E, 128, 128, 0);
  // 9. global attention
  gemm_f32<0, 0, false, true><<<dim3(cdiv(E, 64), 2), 256, 0, stream>>>(
      ea, nullptr, nullptr, Wq_g, bq_g, q_g, E, 128, 128, 0);
  k_global<<<cdiv(E, 4), 256, 0, stream>>>(q_g, Kg, G, bo_g, ag_out, glbb, E);
  // 10. classifier
  gemm_f32<3, 1, false, true><<<dim3(cdiv(E, 64), 2), 256, 0, stream>>>(
      ea, lclb, glbb, Wc1, bc1, hid, E, 384, 128, 0);
  k_logits<<<cdiv(E, 4), 256, 0, stream>>>(hid, Wc2, bc2, logits, E);
}

// Round 2
// 1003.930 us; speedup vs baseline: 2.0063x; 2.0063x over previous
//
#include <hip/hip_runtime.h>
#include <cstddef>

// MVMGIN: temporal GNN forward. Round 2: all GEMMs -> bf16 MFMA (f32 accumulate,
// on-the-fly f32->bf16 conversion in LDS staging). Algebra:
//  - q_l folded: qk12 = ea @ [Wq_l^T Wk1 | Wq_l^T Wk2] + bq_l@Wk12  (one GEMM, Nout=256)
//  - local V/O folded: lclb = [ws|wd] @ [Wo_l@Wv1 | Wo_l@Wv2]^T + (Wo_l@bv_l+bo_l)
//  - bk_l / bk_g dropped (constant across V -> cancel in softmax).
// Outputs (f32, concat): logits(E,5) | ew(E,8) | h_before(N,8,128) | a_g(E,8)

#define HSZ 128

typedef short short8 __attribute__((ext_vector_type(8)));
typedef float f32x4 __attribute__((ext_vector_type(4)));

__device__ __forceinline__ float sigm(float x) { return 1.f / (1.f + __expf(-x)); }

__device__ __forceinline__ unsigned short f2bf(float f) {
  unsigned int u = __float_as_uint(f);
  u += 0x7fffu + ((u >> 16) & 1u);
  return (unsigned short)(u >> 16);
}

// ---------------- bf16 MFMA GEMM ----------------
// out(M,Nout) = ACT( Asrc(M,K) @ W^T + bias ) [+ out when ACC];  W row-major (Nout,K).
// ASRC: 0=A1, 1=A1+A2 (same shape), 2=A1 + rowvec A2[k] (K==128), 3=concat{A1,A2,A3} width 128 each
// Tile: BM=128, BN=128, BK=64; 4 waves, each computes 64x64 (4x4 frags of 16x16x32).
template<int ASRC, int ACT, bool ACC>
__global__ __launch_bounds__(256, 2) void gemm_bf(
    const float* __restrict__ A1, const float* __restrict__ A2, const float* __restrict__ A3,
    const float* __restrict__ W, const float* __restrict__ bias,
    float* __restrict__ out, int M, int K, int Nout)
{
  __shared__ short Ash[128 * 72];   // rows stride 72 bf16 (144 B): <=2-way banks on b128
  __shared__ short Bsh[128 * 72];
  const int tid = threadIdx.x;
  const int m0 = blockIdx.x * 128;
  const int n0 = blockIdx.y * 128;
  const int l = tid & 63, w = tid >> 6;
  const int wr = w >> 1, wc = w & 1;
  const int lr = l & 15, lq = l >> 4;
  f32x4 acc[4][4] = {};

  for (int k0 = 0; k0 < K; k0 += 64) {
    __syncthreads();
    const bool fast = (k0 + 64 <= K);
    #pragma unroll
    for (int i = 0; i < 4; ++i) {
      int c = i * 256 + tid;            // 1024 chunks of 8 elements
      int row = c >> 3, seg = c & 7;
      int kb = k0 + seg * 8;
      // ---- stage A ----
      {
        int m = m0 + row;
        float v[8];
        if (fast && m < M) {
          if (ASRC == 3) {
            const float* S = (kb < 128) ? A1 : (kb < 256) ? A2 : A3;
            const float4* p = reinterpret_cast<const float4*>(S + (size_t)m * 128 + (kb & 127));
            float4 x0 = p[0], x1 = p[1];
            v[0]=x0.x; v[1]=x0.y; v[2]=x0.z; v[3]=x0.w;
            v[4]=x1.x; v[5]=x1.y; v[6]=x1.z; v[7]=x1.w;
          } else {
            const float4* p = reinterpret_cast<const float4*>(A1 + (size_t)m * K + kb);
            float4 x0 = p[0], x1 = p[1];
            v[0]=x0.x; v[1]=x0.y; v[2]=x0.z; v[3]=x0.w;
            v[4]=x1.x; v[5]=x1.y; v[6]=x1.z; v[7]=x1.w;
            if (ASRC == 1) {
              const float4* q = reinterpret_cast<const float4*>(A2 + (size_t)m * K + kb);
              float4 y0 = q[0], y1 = q[1];
              v[0]+=y0.x; v[1]+=y0.y; v[2]+=y0.z; v[3]+=y0.w;
              v[4]+=y1.x; v[5]+=y1.y; v[6]+=y1.z; v[7]+=y1.w;
            } else if (ASRC == 2) {
              const float4* q = reinterpret_cast<const float4*>(A2 + kb);
              float4 y0 = q[0], y1 = q[1];
              v[0]+=y0.x; v[1]+=y0.y; v[2]+=y0.z; v[3]+=y0.w;
              v[4]+=y1.x; v[5]+=y1.y; v[6]+=y1.z; v[7]+=y1.w;
            }
          }
        } else {
          #pragma unroll
          for (int j = 0; j < 8; ++j) {
            int k = kb + j;
            float x = 0.f;
            if (m < M && k < K) {
              if (ASRC == 3) { const float* S = (k < 128) ? A1 : (k < 256) ? A2 : A3;
                               x = S[(size_t)m * 128 + (k & 127)]; }
              else { x = A1[(size_t)m * K + k];
                     if (ASRC == 1) x += A2[(size_t)m * K + k];
                     else if (ASRC == 2) x += A2[k]; }
            }
            v[j] = x;
          }
        }
        short8 pk;
        #pragma unroll
        for (int j = 0; j < 8; ++j) pk[j] = (short)f2bf(v[j]);
        *reinterpret_cast<short8*>(&Ash[row * 72 + seg * 8]) = pk;
      }
      // ---- stage B (W rows) ----
      {
        int nn = n0 + row;
        float v[8];
        if (fast && nn < Nout) {
          const float4* p = reinterpret_cast<const float4*>(W + (size_t)nn * K + kb);
          float4 x0 = p[0], x1 = p[1];
          v[0]=x0.x; v[1]=x0.y; v[2]=x0.z; v[3]=x0.w;
          v[4]=x1.x; v[5]=x1.y; v[6]=x1.z; v[7]=x1.w;
        } else {
          #pragma unroll
          for (int j = 0; j < 8; ++j) {
            int k = kb + j;
            v[j] = (nn < Nout && k < K) ? W[(size_t)nn * K + k] : 0.f;
          }
        }
        short8 pk;
        #pragma unroll
        for (int j = 0; j < 8; ++j) pk[j] = (short)f2bf(v[j]);
        *reinterpret_cast<short8*>(&Bsh[row * 72 + seg * 8]) = pk;
      }
    }
    __syncthreads();
    #pragma unroll
    for (int ks = 0; ks < 2; ++ks) {
      short8 a[4], b[4];
      #pragma unroll
      for (int mi = 0; mi < 4; ++mi)
        a[mi] = *reinterpret_cast<const short8*>(&Ash[(wr*64 + mi*16 + lr) * 72 + ks*32 + lq*8]);
      #pragma unroll
      for (int ni = 0; ni < 4; ++ni)
        b[ni] = *reinterpret_cast<const short8*>(&Bsh[(wc*64 + ni*16 + lr) * 72 + ks*32 + lq*8]);
      #pragma unroll
      for (int mi = 0; mi < 4; ++mi)
        #pragma unroll
        for (int ni = 0; ni < 4; ++ni)
          acc[mi][ni] = __builtin_amdgcn_mfma_f32_16x16x32_bf16(a[mi], b[ni], acc[mi][ni], 0, 0, 0);
    }
  }
  // ---- epilogue: D row=(lane>>4)*4+reg, col=lane&15 ----
  #pragma unroll
  for (int ni = 0; ni < 4; ++ni) {
    int col = n0 + wc*64 + ni*16 + lr;
    if (col >= Nout) continue;
    float bz = bias ? bias[col] : 0.f;
    #pragma unroll
    for (int mi = 0; mi < 4; ++mi) {
      int mb = m0 + wr*64 + mi*16 + lq*4;
      #pragma unroll
      for (int r = 0; r < 4; ++r) {
        int m = mb + r;
        if (m >= M) continue;
        float vv = acc[mi][ni][r] + bz;
        size_t o = (size_t)m * Nout + col;
        if (ACC) vv += out[o];
        if (ACT == 1) vv = fmaxf(vv, 0.f);
        out[o] = vv;
      }
    }
  }
}

// ---------------- edge gate ----------------
__global__ __launch_bounds__(256) void k_ew(const float* __restrict__ ea,
    const float* __restrict__ memory, const int* __restrict__ srcI,
    const float* __restrict__ W_ewg, const float* __restrict__ b_ewg,
    float* __restrict__ ew, int E)
{
  __shared__ float Wsh[2048];
  __shared__ float bsh[8];
  int tid = threadIdx.x;
  for (int i = tid; i < 2048; i += 256) Wsh[i] = W_ewg[i];
  if (tid < 8) bsh[tid] = b_ewg[tid];
  __syncthreads();
  int wv = tid >> 6, lane = tid & 63;
  int e = blockIdx.x * 4 + wv;
  if (e >= E) return;
  int s = srcI[e];
  float c0 = ea[(size_t)e * 128 + lane];
  float c1 = ea[(size_t)e * 128 + 64 + lane];
  float c2 = memory[(size_t)s * 128 + lane];
  float c3 = memory[(size_t)s * 128 + 64 + lane];
  #pragma unroll
  for (int v = 0; v < 8; ++v) {
    float p = c0 * Wsh[v * 256 + lane] + c1 * Wsh[v * 256 + 64 + lane]
            + c2 * Wsh[v * 256 + 128 + lane] + c3 * Wsh[v * 256 + 192 + lane];
    #pragma unroll
    for (int o = 32; o; o >>= 1) p += __shfl_down(p, o);
    if (lane == 0) ew[(size_t)e * 8 + v] = sigm(p + bsh[v]);
  }
}

// ---------------- h init ----------------
__global__ void k_hinit(const float* __restrict__ memory, float* __restrict__ h, int total)
{
  int idx = blockIdx.x * 256 + threadIdx.x;
  if (idx >= total) return;
  h[idx] = memory[(size_t)(idx >> 10) * 128 + (idx & 127)];
}

// ---------------- GIN message + scatter-add ----------------
__global__ __launch_bounds__(256) void k_msg(const float* __restrict__ h,
    const float* __restrict__ ea, const float* __restrict__ ew,
    const int* __restrict__ srcI, const int* __restrict__ dstI,
    float* __restrict__ agg, int E)
{
  __shared__ float eas[128];
  __shared__ float ews[8];
  int e = blockIdx.x;
  int tid = threadIdx.x;
  if (tid < 128) eas[tid] = ea[(size_t)e * 128 + tid];
  if (tid < 8) ews[tid] = ew[(size_t)e * 8 + tid];
  __syncthreads();
  int s = srcI[e], d = dstI[e];               // cs=dst, cd=src per reference
  const float* hd = h + (size_t)d * 1024;
  float* ag = agg + (size_t)s * 1024;
  #pragma unroll
  for (int i = 0; i < 4; ++i) {
    int idx = i * 256 + tid;
    int x = idx & 127, v = idx >> 7;
    float m = fmaxf(hd[idx] + eas[x], 0.f) * ews[v];
    atomicAdd(&ag[idx], m);
  }
}

// ---------------- te ----------------
__global__ void k_te(const float* __restrict__ delta_t, const float* __restrict__ W_t,
                     const float* __restrict__ b_t, float* __restrict__ te)
{
  int t = threadIdx.x;
  if (t < 128) te[t] = sinf(delta_t[0] * W_t[t] + b_t[t]);
}

// ---------------- GRU elementwise ----------------
__global__ void k_gru(const float* __restrict__ gi, const float* __restrict__ gh,
                      const float* __restrict__ memory, float* __restrict__ h_new, int total)
{
  int idx = blockIdx.x * 256 + threadIdx.x;
  if (idx >= total) return;
  int n = idx >> 10, x = idx & 127, row = idx >> 7;
  size_t gio = (size_t)row * 384 + x;
  size_t gho = (size_t)n * 384 + x;
  float r = sigm(gi[gio] + gh[gho]);
  float z = sigm(gi[gio + 128] + gh[gho + 128]);
  float nn = tanhf(gi[gio + 256] + r * gh[gho + 256]);
  float mem = memory[(size_t)n * 128 + x];
  h_new[idx] = (1.f - z) * nn + z * mem;
}

// ---------------- pooled partial sums ----------------
__global__ __launch_bounds__(256) void k_pool(const float* __restrict__ h_new,
                                              float* __restrict__ prw, int N)
{
  int tid = threadIdx.x;
  float acc[4] = {0.f, 0.f, 0.f, 0.f};
  for (int n = blockIdx.x; n < N; n += gridDim.x) {
    const float* row = h_new + (size_t)n * 1024;
    #pragma unroll
    for (int j = 0; j < 4; ++j) acc[j] += row[tid + j * 256];
  }
  #pragma unroll
  for (int j = 0; j < 4; ++j) atomicAdd(&prw[tid + j * 256], acc[j]);
}

// ---------------- fused small mats ----------------
// Wl2(128,256): [n][k] = sum_j Wo_l[n][j]*Wv_l[j][k]   (k spans both halves of Wv_l)
// blv(128) = bo_l + Wo_l@bv_l
// Wqk(256,128): [n][j] = sum_k Wq_l[k][j]*Wk_l[k][n]   (n spans both halves of Wk_l)
// bqk(256) = bq_l @ Wk_l
__global__ __launch_bounds__(256) void k_prep(
    const float* __restrict__ Wo_l, const float* __restrict__ Wv_l,
    const float* __restrict__ bv_l, const float* __restrict__ bo_l,
    const float* __restrict__ Wq_l, const float* __restrict__ bq_l,
    const float* __restrict__ Wk_l,
    float* __restrict__ Wl2, float* __restrict__ blv,
    float* __restrict__ Wqk, float* __restrict__ bqk)
{
  int idx = blockIdx.x * 256 + threadIdx.x;    // 65536 total
  if (idx < 32768) {
    int n = idx >> 8, k = idx & 255;
    float a = 0.f;
    for (int j = 0; j < 128; ++j) a += Wo_l[n * 128 + j] * Wv_l[j * 256 + k];
    Wl2[idx] = a;
  } else {
    int rem = idx - 32768;
    int n = rem >> 7, j = rem & 127;
    float a = 0.f;
    for (int k = 0; k < 128; ++k) a += Wq_l[k * 128 + j] * Wk_l[k * 256 + n];
    Wqk[rem] = a;
  }
  if (blockIdx.x == 0 && threadIdx.x < 128) {
    int n = threadIdx.x;
    float a = bo_l[n];
    for (int j = 0; j < 128; ++j) a += Wo_l[n * 128 + j] * bv_l[j];
    blv[n] = a;
  }
  if (blockIdx.x == 1) {
    int n = threadIdx.x;
    float a = 0.f;
    for (int k = 0; k < 128; ++k) a += bq_l[k] * Wk_l[k * 256 + n];
    bqk[n] = a;
  }
}

// ---------------- Kg / G for global attention ----------------
__global__ __launch_bounds__(256) void k_kgg(const float* __restrict__ prw,
    const float* __restrict__ Wk_g, const float* __restrict__ Wv_g, const float* __restrict__ bv_g,
    const float* __restrict__ Wo_g, float* __restrict__ Kg, float* __restrict__ G, int N)
{
  __shared__ float pl[1024];
  __shared__ float vg[1024];
  int tid = threadIdx.x;
  float invN = 1.f / (float)N;
  for (int i = tid; i < 1024; i += 256) pl[i] = prw[i] * invN;
  __syncthreads();
  for (int o = tid; o < 1024; o += 256) {
    int v = o >> 7, x = o & 127;
    float a = 0.f, b = 0.f;
    for (int k = 0; k < 128; ++k) {
      float p = pl[v * 128 + k];
      a += p * Wk_g[(size_t)x * 128 + k];
      b += p * Wv_g[(size_t)x * 128 + k];
    }
    Kg[o] = a;
    vg[o] = b + bv_g[x];
  }
  __syncthreads();
  for (int o = tid; o < 1024; o += 256) {
    int v = o >> 7, x = o & 127;
    float a = 0.f;
    for (int k = 0; k < 128; ++k) a += vg[v * 128 + k] * Wo_g[(size_t)x * 128 + k];
    G[o] = a;
  }
}

// ---------------- fused local attention ----------------
__global__ __launch_bounds__(256) void k_local(const float* __restrict__ h_new,
    const float* __restrict__ qk12,
    const int* __restrict__ srcI, const int* __restrict__ dstI,
    float* __restrict__ wsd, int E)
{
  __shared__ float sf[1024], df[1024], q1[128], q2[128], sc[8];
  int e = blockIdx.x;
  int tid = threadIdx.x;
  int s = srcI[e], d = dstI[e];
  const float* hs = h_new + (size_t)s * 1024;
  const float* hd = h_new + (size_t)d * 1024;
  for (int i = tid; i < 1024; i += 256) { sf[i] = hs[i]; df[i] = hd[i]; }
  if (tid < 128) { q1[tid] = qk12[(size_t)e * 256 + tid]; q2[tid] = qk12[(size_t)e * 256 + 128 + tid]; }
  __syncthreads();
  int wv = tid >> 6, lane = tid & 63;
  for (int v = wv; v < 8; v += 4) {
    float p = q1[lane] * sf[v * 128 + lane] + q1[64 + lane] * sf[v * 128 + 64 + lane]
            + q2[lane] * df[v * 128 + lane] + q2[64 + lane] * df[v * 128 + 64 + lane];
    #pragma unroll
    for (int o = 32; o; o >>= 1) p += __shfl_down(p, o);
    if (lane == 0) sc[v] = p * 0.08838834764831845f;   // 1/sqrt(128)
  }
  __syncthreads();
  float mx = sc[0];
  #pragma unroll
  for (int v = 1; v < 8; ++v) mx = fmaxf(mx, sc[v]);
  float a[8], sum = 0.f;
  #pragma unroll
  for (int v = 0; v < 8; ++v) { a[v] = __expf(sc[v] - mx); sum += a[v]; }
  float inv = 1.f / sum;
  int x = tid & 127;
  const float* mat = (tid < 128) ? sf : df;
  float accv = 0.f;
  #pragma unroll
  for (int v = 0; v < 8; ++v) accv += a[v] * mat[v * 128 + x];
  wsd[(size_t)e * 256 + (tid < 128 ? x : 128 + x)] = accv * inv;
}

// ---------------- global attention ----------------
__global__ __launch_bounds__(256) void k_global(const float* __restrict__ q_g,
    const float* __restrict__ Kg, const float* __restrict__ G, const float* __restrict__ bo_g,
    float* __restrict__ ag_out, float* __restrict__ gout, int E)
{
  __shared__ float Kgs[1024], Gs[1024], bs[128];
  int tid = threadIdx.x;
  for (int i = tid; i < 1024; i += 256) { Kgs[i] = Kg[i]; Gs[i] = G[i]; }
  if (tid < 128) bs[tid] = bo_g[tid];
  __syncthreads();
  int wv = tid >> 6, lane = tid & 63;
  int e = blockIdx.x * 4 + wv;
  if (e >= E) return;
  float qa = q_g[(size_t)e * 128 + lane], qb = q_g[(size_t)e * 128 + 64 + lane];
  float s[8];
  #pragma unroll
  for (int v = 0; v < 8; ++v) {
    float p = qa * Kgs[v * 128 + lane] + qb * Kgs[v * 128 + 64 + lane];
    #pragma unroll
    for (int o = 32; o; o >>= 1) p += __shfl_xor(p, o);
    s[v] = p * 0.08838834764831845f;
  }
  float mx = s[0];
  #pragma unroll
  for (int v = 1; v < 8; ++v) mx = fmaxf(mx, s[v]);
  float sum = 0.f;
  #pragma unroll
  for (int v = 0; v < 8; ++v) { s[v] = __expf(s[v] - mx); sum += s[v]; }
  float inv = 1.f / sum;
  #pragma unroll
  for (int v = 0; v < 8; ++v) s[v] *= inv;
  #pragma unroll
  for (int v = 0; v < 8; ++v) if (lane == v) ag_out[(size_t)e * 8 + v] = s[v];
  float g0 = bs[lane], g1 = bs[64 + lane];
  #pragma unroll
  for (int v = 0; v < 8; ++v) {
    g0 += s[v] * Gs[v * 128 + lane];
    g1 += s[v] * Gs[v * 128 + 64 + lane];
  }
  gout[(size_t)e * 128 + lane] = g0;
  gout[(size_t)e * 128 + 64 + lane] = g1;
}

// ---------------- logits ----------------
__global__ __launch_bounds__(256) void k_logits(const float* __restrict__ hid,
    const float* __restrict__ Wc2, const float* __restrict__ bc2,
    float* __restrict__ logits, int E)
{
  __shared__ float Wsh[640];
  __shared__ float bsh[5];
  int tid = threadIdx.x;
  for (int i = tid; i < 640; i += 256) Wsh[i] = Wc2[i];
  if (tid < 5) bsh[tid] = bc2[tid];
  __syncthreads();
  int wv = tid >> 6, lane = tid & 63;
  int e = blockIdx.x * 4 + wv;
  if (e >= E) return;
  float h0 = hid[(size_t)e * 128 + lane], h1 = hid[(size_t)e * 128 + 64 + lane];
  #pragma unroll
  for (int c = 0; c < 5; ++c) {
    float p = h0 * Wsh[c * 128 + lane] + h1 * Wsh[c * 128 + 64 + lane];
    #pragma unroll
    for (int o = 32; o; o >>= 1) p += __shfl_down(p, o);
    if (lane == 0) logits[(size_t)e * 5 + c] = p + bsh[c];
  }
}

extern "C" void kernel_launch(void* const* d_in, const int* in_sizes, int n_in,
                              void* d_out, int out_size, void* d_ws, size_t ws_size,
                              hipStream_t stream)
{
  const int*   edge_index = (const int*)d_in[0];
  const float* edge_attr  = (const float*)d_in[1];
  const float* delta_t    = (const float*)d_in[2];
  const float* memory     = (const float*)d_in[3];
  const float* W_ee  = (const float*)d_in[4];
  const float* b_ee  = (const float*)d_in[5];
  const float* W_ewg = (const float*)d_in[6];
  const float* b_ewg = (const float*)d_in[7];
  const float* gin_W1 = (const float*)d_in[8];
  const float* gin_b1 = (const float*)d_in[9];
  const float* gin_W2 = (const float*)d_in[10];
  const float* gin_b2 = (const float*)d_in[11];
  const float* W_t  = (const float*)d_in[12];
  const float* b_t  = (const float*)d_in[13];
  const float* W_ih = (const float*)d_in[14];
  const float* b_ih = (const float*)d_in[15];
  const float* W_hh = (const float*)d_in[16];
  const float* b_hh = (const float*)d_in[17];
  // 18,19 = W_up,b_up unused
  const float* Wq_l = (const float*)d_in[20];
  const float* bq_l = (const float*)d_in[21];
  const float* Wk_l = (const float*)d_in[22];
  // bk_l (23) cancels in softmax
  const float* Wv_l = (const float*)d_in[24];
  const float* bv_l = (const float*)d_in[25];
  const float* Wo_l = (const float*)d_in[26];
  const float* bo_l = (const float*)d_in[27];
  const float* Wq_g = (const float*)d_in[28];
  const float* bq_g = (const float*)d_in[29];
  const float* Wk_g = (const float*)d_in[30];
  // bk_g (31) cancels in softmax
  const float* Wv_g = (const float*)d_in[32];
  const float* bv_g = (const float*)d_in[33];
  const float* Wo_g = (const float*)d_in[34];
  const float* bo_g = (const float*)d_in[35];
  const float* Wc1  = (const float*)d_in[36];
  const float* bc1  = (const float*)d_in[37];
  const float* Wc2  = (const float*)d_in[38];
  const float* bc2  = (const float*)d_in[39];

  const int E = in_sizes[0] / 2;
  const int N = in_sizes[3] / HSZ;
  const int* srcI = edge_index;
  const int* dstI = edge_index + E;

  float* out    = (float*)d_out;
  float* logits = out;
  float* ew     = out + (size_t)E * 5;
  float* h      = out + (size_t)E * 13;                       // h_before lives in d_out
  float* ag_out = out + (size_t)E * 13 + (size_t)N * 1024;

  // ---- workspace arena ----
  float* ws = (float*)d_ws;
  size_t off = 0;
  auto alloc = [&](size_t n) { size_t o = off; off += (n + 255) & ~(size_t)255; return o; };
  float* te   = ws + alloc(128);
  float* Wl2  = ws + alloc(32768);
  float* blv  = ws + alloc(128);
  float* Wqk  = ws + alloc(32768);
  float* bqk  = ws + alloc(256);
  float* Kg   = ws + alloc(1024);
  float* G    = ws + alloc(1024);
  float* prw  = ws + alloc(1024);
  const size_t EH = (size_t)E * 128;
  float* ea    = ws + alloc(EH);
  float* h_new = ws + alloc((size_t)N * 1024);
  float* gh    = ws + alloc((size_t)N * 384);
  size_t brA = (size_t)2 * N * 1024;     // agg + gtmp
  size_t brB = (size_t)N * 8 * 384;      // gi
  size_t brC = 4 * EH;                   // attention peak (qk12 + wsd)
  size_t brsz = brA > brB ? brA : brB; if (brC > brsz) brsz = brC;
  float* BR = ws + alloc(brsz);
  if (ws_size < off * sizeof(float)) return;   // needs ~206 MiB

  // BR aliases (time-disjoint):
  float* agg   = BR;                     // GIN
  float* gtmp  = BR + (size_t)N * 1024;
  float* gi    = BR;                     // GRU
  float* qk12  = BR;                     // [0,2EH): fused q@K mats per edge
  float* wsd   = BR + 2 * EH;            // [2EH,4EH): ws|wd weighted sums
  float* lclb  = BR;                     // [0,EH): after k_local (qk12 dead)
  float* q_g   = BR + EH;                // [EH,2EH)
  float* glbb  = BR + 2 * EH;            // [2EH,3EH): after localout (wsd dead)
  float* hid   = BR + 3 * EH;            // [3EH,4EH)

  auto cdiv = [](int a, int b) { return (a + b - 1) / b; };

  // 1. ea = relu(edge_attr @ W_ee^T + b_ee)   (K=59, slow-path staging)
  gemm_bf<0, 1, false><<<dim3(cdiv(E, 128), 1), 256, 0, stream>>>(
      edge_attr, nullptr, nullptr, W_ee, b_ee, ea, E, 59, 128);
  // 2. ew
  k_ew<<<cdiv(E, 4), 256, 0, stream>>>(ea, memory, srcI, W_ewg, b_ewg, ew, E);
  // 3. h init
  k_hinit<<<cdiv(N * 1024, 256), 256, 0, stream>>>(memory, h, N * 1024);
  // 4. te + fused attention mats (independent of GIN)
  k_te<<<1, 128, 0, stream>>>(delta_t, W_t, b_t, te);
  k_prep<<<256, 256, 0, stream>>>(Wo_l, Wv_l, bv_l, bo_l, Wq_l, bq_l, Wk_l, Wl2, blv, Wqk, bqk);
  // 5. GIN layers
  for (int l = 0; l < 2; ++l) {
    hipMemsetAsync(agg, 0, (size_t)N * 1024 * sizeof(float), stream);
    k_msg<<<E, 256, 0, stream>>>(h, ea, ew, srcI, dstI, agg, E);
    gemm_bf<1, 1, false><<<dim3(cdiv(N * 8, 128), 1), 256, 0, stream>>>(
        h, agg, nullptr, gin_W1 + l * 16384, gin_b1 + l * 128, gtmp, N * 8, 128, 128);
    gemm_bf<0, 0, true><<<dim3(cdiv(N * 8, 128), 1), 256, 0, stream>>>(
        gtmp, nullptr, nullptr, gin_W2 + l * 16384, gin_b2 + l * 128, h, N * 8, 128, 128);
  }
  // 6. GRU
  gemm_bf<0, 0, false><<<dim3(cdiv(N, 128), 3), 256, 0, stream>>>(
      memory, nullptr, nullptr, W_hh, b_hh, gh, N, 128, 384);
  gemm_bf<2, 0, false><<<dim3(cdiv(N * 8, 128), 3), 256, 0, stream>>>(
      h, te, nullptr, W_ih, b_ih, gi, N * 8, 128, 384);
  k_gru<<<cdiv(N * 1024, 256), 256, 0, stream>>>(gi, gh, memory, h_new, N * 1024);
  // 7. pooled + global K/G
  hipMemsetAsync(prw, 0, 1024 * sizeof(float), stream);
  k_pool<<<256, 256, 0, stream>>>(h_new, prw, N);
  k_kgg<<<1, 256, 0, stream>>>(prw, Wk_g, Wv_g, bv_g, Wo_g, Kg, G, N);
  // 8. local attention
  gemm_bf<0, 0, false><<<dim3(cdiv(E, 128), 2), 256, 0, stream>>>(
      ea, nullptr, nullptr, Wqk, bqk, qk12, E, 128, 256);
  k_local<<<E, 256, 0, stream>>>(h_new, qk12, srcI, dstI, wsd, E);
  gemm_bf<0, 0, false><<<dim3(cdiv(E, 128), 1), 256, 0, stream>>>(
      wsd, nullptr, nullptr, Wl2, blv, lclb, E, 256, 128);
  // 9. global attention
  gemm_bf<0, 0, false><<<dim3(cdiv(E, 128), 1), 256, 0, stream>>>(
      ea, nullptr, nullptr, Wq_g, bq_g, q_g, E, 128, 128);
  k_global<<<cdiv(E, 4), 256, 0, stream>>>(q_g, Kg, G, bo_g, ag_out, glbb, E);
  // 10. classifier
  gemm_bf<3, 1, false><<<dim3(cdiv(E, 128), 1), 256, 0, stream>>>(
      ea, lclb, glbb, Wc1, bc1, hid, E, 384, 128);
  k_logits<<<cdiv(E, 4), 256, 0, stream>>>(hid, Wc2, bc2, logits, E);
}

// Round 3
// 762.674 us; speedup vs baseline: 2.6409x; 1.3163x over previous
//
#include <hip/hip_runtime.h>
#include <cstddef>

// MVMGIN round 3:
//  - GIN aggregation scatter-atomic -> CSR gather (kills 200MB atomic write traffic)
//  - fused GIN layer kernel (one kernel: relu((h+agg)@W1+b1)@W2 + h, t in LDS bf16)
//  - XOR-swizzled LDS (stride 64 shorts, chunk^=row&7) -> conflict-free ds_read_b128
//  - gi (GRU preact) stored bf16 (halves 246MB of traffic)
// Algebra (from round 2): q_l folded into qk12; local V/O folded into Wl2/blv;
// bk_l/bk_g dropped (cancel in softmax).
// Outputs (f32, concat): logits(E,5) | ew(E,8) | h_before(N,8,128) | a_g(E,8)

#define HSZ 128

typedef short short8 __attribute__((ext_vector_type(8)));
typedef float f32x4 __attribute__((ext_vector_type(4)));

__device__ __forceinline__ float sigm(float x) { return 1.f / (1.f + __expf(-x)); }

__device__ __forceinline__ unsigned short f2bf(float f) {
  unsigned int u = __float_as_uint(f);
  u += 0x7fffu + ((u >> 16) & 1u);
  return (unsigned short)(u >> 16);
}
__device__ __forceinline__ float bf2f(unsigned short u) {
  return __uint_as_float(((unsigned int)u) << 16);
}

// swizzled index (in shorts) of an 8-short chunk: row stride 64 shorts (128B = full
// bank span), chunk index XOR'd with row&7 -> any 16-row x one-chunk column access
// hits each 16B slot exactly 8/64 lanes = conflict-free minimum.
__device__ __forceinline__ int swzA(int row, int chunk) {
  return row * 64 + (((chunk ^ row) & 7) << 3);
}
// 128-short-wide tile (16 chunks): keep bit3, XOR low 3 bits.
__device__ __forceinline__ int swzT(int row, int chunk) {
  return row * 128 + (((chunk & 8) | ((chunk ^ row) & 7)) << 3);
}

// ---------------- bf16 MFMA GEMM ----------------
// out(M,Nout) = ACT( Asrc(M,K) @ W^T + bias ) [+ out when ACC];  W row-major (Nout,K).
// ASRC: 0=A1, 1=A1+A2, 2=A1 + rowvec A2[k], 3=concat{A1,A2,A3} width 128 each
// OUTBF: write bf16 (ushort) instead of f32 (no ACC support).
template<int ASRC, int ACT, bool ACC, bool OUTBF = false>
__global__ __launch_bounds__(256) void gemm_bf(
    const float* __restrict__ A1, const float* __restrict__ A2, const float* __restrict__ A3,
    const float* __restrict__ W, const float* __restrict__ bias,
    void* __restrict__ out_, int M, int K, int Nout)
{
  __shared__ short Ash[128 * 64];
  __shared__ short Bsh[128 * 64];
  float* out = (float*)out_;
  unsigned short* outh = (unsigned short*)out_;
  const int tid = threadIdx.x;
  const int m0 = blockIdx.x * 128;
  const int n0 = blockIdx.y * 128;
  const int l = tid & 63, w = tid >> 6;
  const int wr = w >> 1, wc = w & 1;
  const int lr = l & 15, lq = l >> 4;
  f32x4 acc[4][4] = {};

  for (int k0 = 0; k0 < K; k0 += 64) {
    __syncthreads();
    const bool fast = (k0 + 64 <= K);
    #pragma unroll
    for (int i = 0; i < 4; ++i) {
      int c = i * 256 + tid;            // 1024 chunks of 8 elements
      int row = c >> 3, seg = c & 7;
      int kb = k0 + seg * 8;
      // ---- stage A ----
      {
        int m = m0 + row;
        float v[8];
        if (fast && m < M) {
          if (ASRC == 3) {
            const float* S = (kb < 128) ? A1 : (kb < 256) ? A2 : A3;
            const float4* p = reinterpret_cast<const float4*>(S + (size_t)m * 128 + (kb & 127));
            float4 x0 = p[0], x1 = p[1];
            v[0]=x0.x; v[1]=x0.y; v[2]=x0.z; v[3]=x0.w;
            v[4]=x1.x; v[5]=x1.y; v[6]=x1.z; v[7]=x1.w;
          } else {
            const float4* p = reinterpret_cast<const float4*>(A1 + (size_t)m * K + kb);
            float4 x0 = p[0], x1 = p[1];
            v[0]=x0.x; v[1]=x0.y; v[2]=x0.z; v[3]=x0.w;
            v[4]=x1.x; v[5]=x1.y; v[6]=x1.z; v[7]=x1.w;
            if (ASRC == 1) {
              const float4* q = reinterpret_cast<const float4*>(A2 + (size_t)m * K + kb);
              float4 y0 = q[0], y1 = q[1];
              v[0]+=y0.x; v[1]+=y0.y; v[2]+=y0.z; v[3]+=y0.w;
              v[4]+=y1.x; v[5]+=y1.y; v[6]+=y1.z; v[7]+=y1.w;
            } else if (ASRC == 2) {
              const float4* q = reinterpret_cast<const float4*>(A2 + kb);
              float4 y0 = q[0], y1 = q[1];
              v[0]+=y0.x; v[1]+=y0.y; v[2]+=y0.z; v[3]+=y0.w;
              v[4]+=y1.x; v[5]+=y1.y; v[6]+=y1.z; v[7]+=y1.w;
            }
          }
        } else {
          #pragma unroll
          for (int j = 0; j < 8; ++j) {
            int k = kb + j;
            float x = 0.f;
            if (m < M && k < K) {
              if (ASRC == 3) { const float* S = (k < 128) ? A1 : (k < 256) ? A2 : A3;
                               x = S[(size_t)m * 128 + (k & 127)]; }
              else { x = A1[(size_t)m * K + k];
                     if (ASRC == 1) x += A2[(size_t)m * K + k];
                     else if (ASRC == 2) x += A2[k]; }
            }
            v[j] = x;
          }
        }
        short8 pk;
        #pragma unroll
        for (int j = 0; j < 8; ++j) pk[j] = (short)f2bf(v[j]);
        *reinterpret_cast<short8*>(&Ash[swzA(row, seg)]) = pk;
      }
      // ---- stage B (W rows) ----
      {
        int nn = n0 + row;
        float v[8];
        if (fast && nn < Nout) {
          const float4* p = reinterpret_cast<const float4*>(W + (size_t)nn * K + kb);
          float4 x0 = p[0], x1 = p[1];
          v[0]=x0.x; v[1]=x0.y; v[2]=x0.z; v[3]=x0.w;
          v[4]=x1.x; v[5]=x1.y; v[6]=x1.z; v[7]=x1.w;
        } else {
          #pragma unroll
          for (int j = 0; j < 8; ++j) {
            int k = kb + j;
            v[j] = (nn < Nout && k < K) ? W[(size_t)nn * K + k] : 0.f;
          }
        }
        short8 pk;
        #pragma unroll
        for (int j = 0; j < 8; ++j) pk[j] = (short)f2bf(v[j]);
        *reinterpret_cast<short8*>(&Bsh[swzA(row, seg)]) = pk;
      }
    }
    __syncthreads();
    #pragma unroll
    for (int ks = 0; ks < 2; ++ks) {
      short8 a[4], b[4];
      #pragma unroll
      for (int mi = 0; mi < 4; ++mi)
        a[mi] = *reinterpret_cast<const short8*>(&Ash[swzA(wr*64 + mi*16 + lr, ks*4 + lq)]);
      #pragma unroll
      for (int ni = 0; ni < 4; ++ni)
        b[ni] = *reinterpret_cast<const short8*>(&Bsh[swzA(wc*64 + ni*16 + lr, ks*4 + lq)]);
      #pragma unroll
      for (int mi = 0; mi < 4; ++mi)
        #pragma unroll
        for (int ni = 0; ni < 4; ++ni)
          acc[mi][ni] = __builtin_amdgcn_mfma_f32_16x16x32_bf16(a[mi], b[ni], acc[mi][ni], 0, 0, 0);
    }
  }
  // ---- epilogue: D row=(lane>>4)*4+reg, col=lane&15 ----
  #pragma unroll
  for (int ni = 0; ni < 4; ++ni) {
    int col = n0 + wc*64 + ni*16 + lr;
    if (col >= Nout) continue;
    float bz = bias ? bias[col] : 0.f;
    #pragma unroll
    for (int mi = 0; mi < 4; ++mi) {
      int mb = m0 + wr*64 + mi*16 + lq*4;
      #pragma unroll
      for (int r = 0; r < 4; ++r) {
        int m = mb + r;
        if (m >= M) continue;
        float vv = acc[mi][ni][r] + bz;
        size_t o = (size_t)m * Nout + col;
        if (OUTBF) {
          if (ACT == 1) vv = fmaxf(vv, 0.f);
          outh[o] = f2bf(vv);
        } else {
          if (ACC) vv += out[o];
          if (ACT == 1) vv = fmaxf(vv, 0.f);
          out[o] = vv;
        }
      }
    }
  }
}

// ---------------- fused GIN layer: h += relu((h+agg)@W1^T+b1)@W2^T + b2 ----------------
// M must be a multiple of 128 is NOT required (bound-checked); K=N=128 fixed.
__global__ __launch_bounds__(256, 2) void k_gin(
    float* __restrict__ h, const float* __restrict__ agg,
    const float* __restrict__ W1, const float* __restrict__ b1,
    const float* __restrict__ W2, const float* __restrict__ b2, int M)
{
  __shared__ short Ash[128 * 64];
  __shared__ short Bsh[128 * 64];
  __shared__ short Tsh[128 * 128];
  const int tid = threadIdx.x;
  const int m0 = blockIdx.x * 128;
  const int l = tid & 63, w = tid >> 6;
  const int wr = w >> 1, wc = w & 1;
  const int lr = l & 15, lq = l >> 4;
  f32x4 acc[4][4] = {};

  // ---- phase 1: t = (h+agg) @ W1^T ----
  for (int ks2 = 0; ks2 < 2; ++ks2) {
    __syncthreads();
    #pragma unroll
    for (int i = 0; i < 4; ++i) {
      int c = i * 256 + tid;
      int row = c >> 3, seg = c & 7;
      int kb = ks2 * 64 + seg * 8;
      {
        int m = m0 + row;
        short8 pk;
        if (m < M) {
          const float4* p = reinterpret_cast<const float4*>(h + (size_t)m * 128 + kb);
          const float4* q = reinterpret_cast<const float4*>(agg + (size_t)m * 128 + kb);
          float4 x0 = p[0], x1 = p[1], y0 = q[0], y1 = q[1];
          pk[0]=(short)f2bf(x0.x+y0.x); pk[1]=(short)f2bf(x0.y+y0.y);
          pk[2]=(short)f2bf(x0.z+y0.z); pk[3]=(short)f2bf(x0.w+y0.w);
          pk[4]=(short)f2bf(x1.x+y1.x); pk[5]=(short)f2bf(x1.y+y1.y);
          pk[6]=(short)f2bf(x1.z+y1.z); pk[7]=(short)f2bf(x1.w+y1.w);
        } else {
          #pragma unroll
          for (int j = 0; j < 8; ++j) pk[j] = 0;
        }
        *reinterpret_cast<short8*>(&Ash[swzA(row, seg)]) = pk;
      }
      {
        const float4* p = reinterpret_cast<const float4*>(W1 + (size_t)row * 128 + kb);
        float4 x0 = p[0], x1 = p[1];
        short8 pk;
        pk[0]=(short)f2bf(x0.x); pk[1]=(short)f2bf(x0.y);
        pk[2]=(short)f2bf(x0.z); pk[3]=(short)f2bf(x0.w);
        pk[4]=(short)f2bf(x1.x); pk[5]=(short)f2bf(x1.y);
        pk[6]=(short)f2bf(x1.z); pk[7]=(short)f2bf(x1.w);
        *reinterpret_cast<short8*>(&Bsh[swzA(row, seg)]) = pk;
      }
    }
    __syncthreads();
    #pragma unroll
    for (int ks = 0; ks < 2; ++ks) {
      short8 a[4], b[4];
      #pragma unroll
      for (int mi = 0; mi < 4; ++mi)
        a[mi] = *reinterpret_cast<const short8*>(&Ash[swzA(wr*64 + mi*16 + lr, ks*4 + lq)]);
      #pragma unroll
      for (int ni = 0; ni < 4; ++ni)
        b[ni] = *reinterpret_cast<const short8*>(&Bsh[swzA(wc*64 + ni*16 + lr, ks*4 + lq)]);
      #pragma unroll
      for (int mi = 0; mi < 4; ++mi)
        #pragma unroll
        for (int ni = 0; ni < 4; ++ni)
          acc[mi][ni] = __builtin_amdgcn_mfma_f32_16x16x32_bf16(a[mi], b[ni], acc[mi][ni], 0, 0, 0);
    }
  }
  // ---- t = relu(acc + b1) -> Tsh (bf16, swizzled) ----
  {
    float b1v[4];
    #pragma unroll
    for (int ni = 0; ni < 4; ++ni) b1v[ni] = b1[wc*64 + ni*16 + lr];
    #pragma unroll
    for (int mi = 0; mi < 4; ++mi)
      #pragma unroll
      for (int ni = 0; ni < 4; ++ni) {
        int col = wc*64 + ni*16 + lr;
        #pragma unroll
        for (int r = 0; r < 4; ++r) {
          int row = wr*64 + mi*16 + lq*4 + r;
          float v = fmaxf(acc[mi][ni][r] + b1v[ni], 0.f);
          Tsh[swzT(row, col >> 3) + (col & 7)] = (short)f2bf(v);
        }
      }
  }
  // ---- phase 2: upd = t @ W2^T ----
  f32x4 acc2[4][4] = {};
  for (int ks2 = 0; ks2 < 2; ++ks2) {
    __syncthreads();   // Tsh visible; Bsh safe to overwrite
    #pragma unroll
    for (int i = 0; i < 4; ++i) {
      int c = i * 256 + tid;
      int row = c >> 3, seg = c & 7;
      int kb = ks2 * 64 + seg * 8;
      const float4* p = reinterpret_cast<const float4*>(W2 + (size_t)row * 128 + kb);
      float4 x0 = p[0], x1 = p[1];
      short8 pk;
      pk[0]=(short)f2bf(x0.x); pk[1]=(short)f2bf(x0.y);
      pk[2]=(short)f2bf(x0.z); pk[3]=(short)f2bf(x0.w);
      pk[4]=(short)f2bf(x1.x); pk[5]=(short)f2bf(x1.y);
      pk[6]=(short)f2bf(x1.z); pk[7]=(short)f2bf(x1.w);
      *reinterpret_cast<short8*>(&Bsh[swzA(row, seg)]) = pk;
    }
    __syncthreads();
    #pragma unroll
    for (int ks = 0; ks < 2; ++ks) {
      short8 a[4], b[4];
      #pragma unroll
      for (int mi = 0; mi < 4; ++mi)
        a[mi] = *reinterpret_cast<const short8*>(&Tsh[swzT(wr*64 + mi*16 + lr, ks2*8 + ks*4 + lq)]);
      #pragma unroll
      for (int ni = 0; ni < 4; ++ni)
        b[ni] = *reinterpret_cast<const short8*>(&Bsh[swzA(wc*64 + ni*16 + lr, ks*4 + lq)]);
      #pragma unroll
      for (int mi = 0; mi < 4; ++mi)
        #pragma unroll
        for (int ni = 0; ni < 4; ++ni)
          acc2[mi][ni] = __builtin_amdgcn_mfma_f32_16x16x32_bf16(a[mi], b[ni], acc2[mi][ni], 0, 0, 0);
    }
  }
  // ---- epilogue: h += upd + b2 ----
  {
    float b2v[4];
    #pragma unroll
    for (int ni = 0; ni < 4; ++ni) b2v[ni] = b2[wc*64 + ni*16 + lr];
    #pragma unroll
    for (int ni = 0; ni < 4; ++ni) {
      int col = wc*64 + ni*16 + lr;
      #pragma unroll
      for (int mi = 0; mi < 4; ++mi) {
        int mb = m0 + wr*64 + mi*16 + lq*4;
        #pragma unroll
        for (int r = 0; r < 4; ++r) {
          int m = mb + r;
          if (m >= M) continue;
          size_t o = (size_t)m * 128 + col;
          h[o] += acc2[mi][ni][r] + b2v[ni];
        }
      }
    }
  }
}

// ---------------- CSR build ----------------
__global__ void k_hist(const int* __restrict__ srcI, int* __restrict__ cnt, int E)
{
  int e = blockIdx.x * 256 + threadIdx.x;
  if (e < E) atomicAdd(&cnt[srcI[e]], 1);
}

__global__ __launch_bounds__(1024) void k_scan(const int* __restrict__ cnt,
    int* __restrict__ ofs, int* __restrict__ cur, int N)
{
  __shared__ int buf[1024];
  __shared__ int carry;
  int tid = threadIdx.x;
  if (tid == 0) carry = 0;
  __syncthreads();
  for (int base = 0; base < N; base += 1024) {
    int i = base + tid;
    int v = (i < N) ? cnt[i] : 0;
    buf[tid] = v;
    __syncthreads();
    for (int off = 1; off < 1024; off <<= 1) {
      int t = (tid >= off) ? buf[tid - off] : 0;
      __syncthreads();
      buf[tid] += t;
      __syncthreads();
    }
    int excl = carry + buf[tid] - v;
    if (i < N) { ofs[i] = excl; cur[i] = excl; }
    __syncthreads();
    if (tid == 0) carry += buf[1023];
    __syncthreads();
  }
  if (tid == 0) ofs[N] = carry;
}

__global__ void k_fill(const int* __restrict__ srcI, int* __restrict__ cur,
                       int* __restrict__ eid, int E)
{
  int e = blockIdx.x * 256 + threadIdx.x;
  if (e >= E) return;
  int p = atomicAdd(&cur[srcI[e]], 1);
  eid[p] = e;
}

// ---------------- GIN aggregation: gather over CSR ----------------
// agg[n] = sum_{e: src[e]==n} relu(h[dst[e]] + ea[e]) * ew[e]
__global__ __launch_bounds__(256) void k_agg(const float* __restrict__ h,
    const float* __restrict__ ea, const float* __restrict__ ew,
    const int* __restrict__ dstI, const int* __restrict__ ofs,
    const int* __restrict__ eid, float* __restrict__ agg, int N)
{
  int half = threadIdx.x >> 7;
  int x = threadIdx.x & 127;
  int n = blockIdx.x * 2 + half;
  if (n >= N) return;
  float acc[8] = {};
  int beg = ofs[n], end = ofs[n + 1];
  for (int i = beg; i < end; ++i) {
    int e = eid[i];
    int d = dstI[e];
    float eav = ea[(size_t)e * 128 + x];
    const float* hd = h + (size_t)d * 1024;
    const float* ewp = ew + (size_t)e * 8;
    #pragma unroll
    for (int v = 0; v < 8; ++v)
      acc[v] += fmaxf(hd[v * 128 + x] + eav, 0.f) * ewp[v];
  }
  float* ag = agg + (size_t)n * 1024;
  #pragma unroll
  for (int v = 0; v < 8; ++v) ag[v * 128 + x] = acc[v];
}

// ---------------- edge gate ----------------
__global__ __launch_bounds__(256) void k_ew(const float* __restrict__ ea,
    const float* __restrict__ memory, const int* __restrict__ srcI,
    const float* __restrict__ W_ewg, const float* __restrict__ b_ewg,
    float* __restrict__ ew, int E)
{
  __shared__ float Wsh[2048];
  __shared__ float bsh[8];
  int tid = threadIdx.x;
  for (int i = tid; i < 2048; i += 256) Wsh[i] = W_ewg[i];
  if (tid < 8) bsh[tid] = b_ewg[tid];
  __syncthreads();
  int wv = tid >> 6, lane = tid & 63;
  int e = blockIdx.x * 4 + wv;
  if (e >= E) return;
  int s = srcI[e];
  float c0 = ea[(size_t)e * 128 + lane];
  float c1 = ea[(size_t)e * 128 + 64 + lane];
  float c2 = memory[(size_t)s * 128 + lane];
  float c3 = memory[(size_t)s * 128 + 64 + lane];
  #pragma unroll
  for (int v = 0; v < 8; ++v) {
    float p = c0 * Wsh[v * 256 + lane] + c1 * Wsh[v * 256 + 64 + lane]
            + c2 * Wsh[v * 256 + 128 + lane] + c3 * Wsh[v * 256 + 192 + lane];
    #pragma unroll
    for (int o = 32; o; o >>= 1) p += __shfl_down(p, o);
    if (lane == 0) ew[(size_t)e * 8 + v] = sigm(p + bsh[v]);
  }
}

// ---------------- h init ----------------
__global__ void k_hinit(const float* __restrict__ memory, float* __restrict__ h, int total)
{
  int idx = blockIdx.x * 256 + threadIdx.x;
  if (idx >= total) return;
  h[idx] = memory[(size_t)(idx >> 10) * 128 + (idx & 127)];
}

// ---------------- te ----------------
__global__ void k_te(const float* __restrict__ delta_t, const float* __restrict__ W_t,
                     const float* __restrict__ b_t, float* __restrict__ te)
{
  int t = threadIdx.x;
  if (t < 128) te[t] = sinf(delta_t[0] * W_t[t] + b_t[t]);
}

// ---------------- GRU elementwise (gi in bf16) ----------------
__global__ void k_gru(const unsigned short* __restrict__ gi, const float* __restrict__ gh,
                      const float* __restrict__ memory, float* __restrict__ h_new, int total)
{
  int idx = blockIdx.x * 256 + threadIdx.x;
  if (idx >= total) return;
  int n = idx >> 10, x = idx & 127, row = idx >> 7;
  size_t gio = (size_t)row * 384 + x;
  size_t gho = (size_t)n * 384 + x;
  float r = sigm(bf2f(gi[gio]) + gh[gho]);
  float z = sigm(bf2f(gi[gio + 128]) + gh[gho + 128]);
  float nn = tanhf(bf2f(gi[gio + 256]) + r * gh[gho + 256]);
  float mem = memory[(size_t)n * 128 + x];
  h_new[idx] = (1.f - z) * nn + z * mem;
}

// ---------------- pooled partial sums ----------------
__global__ __launch_bounds__(256) void k_pool(const float* __restrict__ h_new,
                                              float* __restrict__ prw, int N)
{
  int tid = threadIdx.x;
  float acc[4] = {0.f, 0.f, 0.f, 0.f};
  for (int n = blockIdx.x; n < N; n += gridDim.x) {
    const float* row = h_new + (size_t)n * 1024;
    #pragma unroll
    for (int j = 0; j < 4; ++j) acc[j] += row[tid + j * 256];
  }
  #pragma unroll
  for (int j = 0; j < 4; ++j) atomicAdd(&prw[tid + j * 256], acc[j]);
}

// ---------------- fused small mats ----------------
__global__ __launch_bounds__(256) void k_prep(
    const float* __restrict__ Wo_l, const float* __restrict__ Wv_l,
    const float* __restrict__ bv_l, const float* __restrict__ bo_l,
    const float* __restrict__ Wq_l, const float* __restrict__ bq_l,
    const float* __restrict__ Wk_l,
    float* __restrict__ Wl2, float* __restrict__ blv,
    float* __restrict__ Wqk, float* __restrict__ bqk)
{
  int idx = blockIdx.x * 256 + threadIdx.x;    // 65536 total
  if (idx < 32768) {
    int n = idx >> 8, k = idx & 255;
    float a = 0.f;
    for (int j = 0; j < 128; ++j) a += Wo_l[n * 128 + j] * Wv_l[j * 256 + k];
    Wl2[idx] = a;
  } else {
    int rem = idx - 32768;
    int n = rem >> 7, j = rem & 127;
    float a = 0.f;
    for (int k = 0; k < 128; ++k) a += Wq_l[k * 128 + j] * Wk_l[k * 256 + n];
    Wqk[rem] = a;
  }
  if (blockIdx.x == 0 && threadIdx.x < 128) {
    int n = threadIdx.x;
    float a = bo_l[n];
    for (int j = 0; j < 128; ++j) a += Wo_l[n * 128 + j] * bv_l[j];
    blv[n] = a;
  }
  if (blockIdx.x == 1) {
    int n = threadIdx.x;
    float a = 0.f;
    for (int k = 0; k < 128; ++k) a += bq_l[k] * Wk_l[k * 256 + n];
    bqk[n] = a;
  }
}

// ---------------- Kg / G for global attention ----------------
__global__ __launch_bounds__(256) void k_kgg(const float* __restrict__ prw,
    const float* __restrict__ Wk_g, const float* __restrict__ Wv_g, const float* __restrict__ bv_g,
    const float* __restrict__ Wo_g, float* __restrict__ Kg, float* __restrict__ G, int N)
{
  __shared__ float pl[1024];
  __shared__ float vg[1024];
  int tid = threadIdx.x;
  float invN = 1.f / (float)N;
  for (int i = tid; i < 1024; i += 256) pl[i] = prw[i] * invN;
  __syncthreads();
  for (int o = tid; o < 1024; o += 256) {
    int v = o >> 7, x = o & 127;
    float a = 0.f, b = 0.f;
    for (int k = 0; k < 128; ++k) {
      float p = pl[v * 128 + k];
      a += p * Wk_g[(size_t)x * 128 + k];
      b += p * Wv_g[(size_t)x * 128 + k];
    }
    Kg[o] = a;
    vg[o] = b + bv_g[x];
  }
  __syncthreads();
  for (int o = tid; o < 1024; o += 256) {
    int v = o >> 7, x = o & 127;
    float a = 0.f;
    for (int k = 0; k < 128; ++k) a += vg[v * 128 + k] * Wo_g[(size_t)x * 128 + k];
    G[o] = a;
  }
}

// ---------------- fused local attention ----------------
__global__ __launch_bounds__(256) void k_local(const float* __restrict__ h_new,
    const float* __restrict__ qk12,
    const int* __restrict__ srcI, const int* __restrict__ dstI,
    float* __restrict__ wsd, int E)
{
  __shared__ float sf[1024], df[1024], q1[128], q2[128], sc[8];
  int e = blockIdx.x;
  int tid = threadIdx.x;
  int s = srcI[e], d = dstI[e];
  const float4* hs = reinterpret_cast<const float4*>(h_new + (size_t)s * 1024);
  const float4* hd = reinterpret_cast<const float4*>(h_new + (size_t)d * 1024);
  reinterpret_cast<float4*>(sf)[tid] = hs[tid];
  reinterpret_cast<float4*>(df)[tid] = hd[tid];
  if (tid < 128) { q1[tid] = qk12[(size_t)e * 256 + tid]; q2[tid] = qk12[(size_t)e * 256 + 128 + tid]; }
  __syncthreads();
  int wv = tid >> 6, lane = tid & 63;
  for (int v = wv; v < 8; v += 4) {
    float p = q1[lane] * sf[v * 128 + lane] + q1[64 + lane] * sf[v * 128 + 64 + lane]
            + q2[lane] * df[v * 128 + lane] + q2[64 + lane] * df[v * 128 + 64 + lane];
    #pragma unroll
    for (int o = 32; o; o >>= 1) p += __shfl_down(p, o);
    if (lane == 0) sc[v] = p * 0.08838834764831845f;   // 1/sqrt(128)
  }
  __syncthreads();
  float mx = sc[0];
  #pragma unroll
  for (int v = 1; v < 8; ++v) mx = fmaxf(mx, sc[v]);
  float a[8], sum = 0.f;
  #pragma unroll
  for (int v = 0; v < 8; ++v) { a[v] = __expf(sc[v] - mx); sum += a[v]; }
  float inv = 1.f / sum;
  int x = tid & 127;
  const float* mat = (tid < 128) ? sf : df;
  float accv = 0.f;
  #pragma unroll
  for (int v = 0; v < 8; ++v) accv += a[v] * mat[v * 128 + x];
  wsd[(size_t)e * 256 + (tid < 128 ? x : 128 + x)] = accv * inv;
}

// ---------------- global attention ----------------
__global__ __launch_bounds__(256) void k_global(const float* __restrict__ q_g,
    const float* __restrict__ Kg, const float* __restrict__ G, const float* __restrict__ bo_g,
    float* __restrict__ ag_out, float* __restrict__ gout, int E)
{
  __shared__ float Kgs[1024], Gs[1024], bs[128];
  int tid = threadIdx.x;
  for (int i = tid; i < 1024; i += 256) { Kgs[i] = Kg[i]; Gs[i] = G[i]; }
  if (tid < 128) bs[tid] = bo_g[tid];
  __syncthreads();
  int wv = tid >> 6, lane = tid & 63;
  int e = blockIdx.x * 4 + wv;
  if (e >= E) return;
  float qa = q_g[(size_t)e * 128 + lane], qb = q_g[(size_t)e * 128 + 64 + lane];
  float s[8];
  #pragma unroll
  for (int v = 0; v < 8; ++v) {
    float p = qa * Kgs[v * 128 + lane] + qb * Kgs[v * 128 + 64 + lane];
    #pragma unroll
    for (int o = 32; o; o >>= 1) p += __shfl_xor(p, o);
    s[v] = p * 0.08838834764831845f;
  }
  float mx = s[0];
  #pragma unroll
  for (int v = 1; v < 8; ++v) mx = fmaxf(mx, s[v]);
  float sum = 0.f;
  #pragma unroll
  for (int v = 0; v < 8; ++v) { s[v] = __expf(s[v] - mx); sum += s[v]; }
  float inv = 1.f / sum;
  #pragma unroll
  for (int v = 0; v < 8; ++v) s[v] *= inv;
  #pragma unroll
  for (int v = 0; v < 8; ++v) if (lane == v) ag_out[(size_t)e * 8 + v] = s[v];
  float g0 = bs[lane], g1 = bs[64 + lane];
  #pragma unroll
  for (int v = 0; v < 8; ++v) {
    g0 += s[v] * Gs[v * 128 + lane];
    g1 += s[v] * Gs[v * 128 + 64 + lane];
  }
  gout[(size_t)e * 128 + lane] = g0;
  gout[(size_t)e * 128 + 64 + lane] = g1;
}

// ---------------- logits ----------------
__global__ __launch_bounds__(256) void k_logits(const float* __restrict__ hid,
    const float* __restrict__ Wc2, const float* __restrict__ bc2,
    float* __restrict__ logits, int E)
{
  __shared__ float Wsh[640];
  __shared__ float bsh[5];
  int tid = threadIdx.x;
  for (int i = tid; i < 640; i += 256) Wsh[i] = Wc2[i];
  if (tid < 5) bsh[tid] = bc2[tid];
  __syncthreads();
  int wv = tid >> 6, lane = tid & 63;
  int e = blockIdx.x * 4 + wv;
  if (e >= E) return;
  float h0 = hid[(size_t)e * 128 + lane], h1 = hid[(size_t)e * 128 + 64 + lane];
  #pragma unroll
  for (int c = 0; c < 5; ++c) {
    float p = h0 * Wsh[c * 128 + lane] + h1 * Wsh[c * 128 + 64 + lane];
    #pragma unroll
    for (int o = 32; o; o >>= 1) p += __shfl_down(p, o);
    if (lane == 0) logits[(size_t)e * 5 + c] = p + bsh[c];
  }
}

extern "C" void kernel_launch(void* const* d_in, const int* in_sizes, int n_in,
                              void* d_out, int out_size, void* d_ws, size_t ws_size,
                              hipStream_t stream)
{
  const int*   edge_index = (const int*)d_in[0];
  const float* edge_attr  = (const float*)d_in[1];
  const float* delta_t    = (const float*)d_in[2];
  const float* memory     = (const float*)d_in[3];
  const float* W_ee  = (const float*)d_in[4];
  const float* b_ee  = (const float*)d_in[5];
  const float* W_ewg = (const float*)d_in[6];
  const float* b_ewg = (const float*)d_in[7];
  const float* gin_W1 = (const float*)d_in[8];
  const float* gin_b1 = (const float*)d_in[9];
  const float* gin_W2 = (const float*)d_in[10];
  const float* gin_b2 = (const float*)d_in[11];
  const float* W_t  = (const float*)d_in[12];
  const float* b_t  = (const float*)d_in[13];
  const float* W_ih = (const float*)d_in[14];
  const float* b_ih = (const float*)d_in[15];
  const float* W_hh = (const float*)d_in[16];
  const float* b_hh = (const float*)d_in[17];
  // 18,19 = W_up,b_up unused
  const float* Wq_l = (const float*)d_in[20];
  const float* bq_l = (const float*)d_in[21];
  const float* Wk_l = (const float*)d_in[22];
  // bk_l (23) cancels in softmax
  const float* Wv_l = (const float*)d_in[24];
  const float* bv_l = (const float*)d_in[25];
  const float* Wo_l = (const float*)d_in[26];
  const float* bo_l = (const float*)d_in[27];
  const float* Wq_g = (const float*)d_in[28];
  const float* bq_g = (const float*)d_in[29];
  const float* Wk_g = (const float*)d_in[30];
  // bk_g (31) cancels in softmax
  const float* Wv_g = (const float*)d_in[32];
  const float* bv_g = (const float*)d_in[33];
  const float* Wo_g = (const float*)d_in[34];
  const float* bo_g = (const float*)d_in[35];
  const float* Wc1  = (const float*)d_in[36];
  const float* bc1  = (const float*)d_in[37];
  const float* Wc2  = (const float*)d_in[38];
  const float* bc2  = (const float*)d_in[39];

  const int E = in_sizes[0] / 2;
  const int N = in_sizes[3] / HSZ;
  const int* srcI = edge_index;
  const int* dstI = edge_index + E;

  float* out    = (float*)d_out;
  float* logits = out;
  float* ew     = out + (size_t)E * 5;
  float* h      = out + (size_t)E * 13;                       // h_before lives in d_out
  float* ag_out = out + (size_t)E * 13 + (size_t)N * 1024;

  // ---- workspace arena ----
  float* ws = (float*)d_ws;
  size_t off = 0;
  auto alloc = [&](size_t n) { size_t o = off; off += (n + 255) & ~(size_t)255; return o; };
  float* te   = ws + alloc(128);
  float* Wl2  = ws + alloc(32768);
  float* blv  = ws + alloc(128);
  float* Wqk  = ws + alloc(32768);
  float* bqk  = ws + alloc(256);
  float* Kg   = ws + alloc(1024);
  float* G    = ws + alloc(1024);
  float* prw  = ws + alloc(1024);
  // CSR (ints carved from float slots)
  int* cnt = (int*)(ws + alloc(N));
  int* ofs = (int*)(ws + alloc(N + 1));
  int* cur = (int*)(ws + alloc(N));
  int* eid = (int*)(ws + alloc(E));
  const size_t EH = (size_t)E * 128;
  float* ea    = ws + alloc(EH);
  float* h_new = ws + alloc((size_t)N * 1024);
  float* gh    = ws + alloc((size_t)N * 384);
  size_t brA = (size_t)N * 1024;               // agg
  size_t brB = (size_t)N * 8 * 384 / 2 + 256;  // gi (bf16, in float slots)
  size_t brC = 4 * EH;                         // attention peak (qk12 + wsd)
  size_t brsz = brA > brB ? brA : brB; if (brC > brsz) brsz = brC;
  float* BR = ws + alloc(brsz);
  if (ws_size < off * sizeof(float)) return;   // needs ~185 MiB

  // BR aliases (time-disjoint):
  float* agg            = BR;                  // GIN
  unsigned short* gi    = (unsigned short*)BR; // GRU preact (bf16)
  float* qk12  = BR;                           // [0,2EH)
  float* wsd   = BR + 2 * EH;                  // [2EH,4EH)
  float* lclb  = BR;                           // after k_local (qk12 dead)
  float* q_g   = BR + EH;
  float* glbb  = BR + 2 * EH;                  // after localout (wsd dead)
  float* hid   = BR + 3 * EH;

  auto cdiv = [](int a, int b) { return (a + b - 1) / b; };

  // 0. CSR build (depends only on edge_index; reused by both GIN layers)
  hipMemsetAsync(cnt, 0, (size_t)N * sizeof(int), stream);
  k_hist<<<cdiv(E, 256), 256, 0, stream>>>(srcI, cnt, E);
  k_scan<<<1, 1024, 0, stream>>>(cnt, ofs, cur, N);
  k_fill<<<cdiv(E, 256), 256, 0, stream>>>(srcI, cur, eid, E);
  // 1. ea = relu(edge_attr @ W_ee^T + b_ee)
  gemm_bf<0, 1, false><<<dim3(cdiv(E, 128), 1), 256, 0, stream>>>(
      edge_attr, nullptr, nullptr, W_ee, b_ee, ea, E, 59, 128);
  // 2. ew
  k_ew<<<cdiv(E, 4), 256, 0, stream>>>(ea, memory, srcI, W_ewg, b_ewg, ew, E);
  // 3. h init
  k_hinit<<<cdiv(N * 1024, 256), 256, 0, stream>>>(memory, h, N * 1024);
  // 4. te + fused attention mats
  k_te<<<1, 128, 0, stream>>>(delta_t, W_t, b_t, te);
  k_prep<<<256, 256, 0, stream>>>(Wo_l, Wv_l, bv_l, bo_l, Wq_l, bq_l, Wk_l, Wl2, blv, Wqk, bqk);
  // 5. GIN layers: gather + fused update
  for (int l = 0; l < 2; ++l) {
    k_agg<<<cdiv(N, 2), 256, 0, stream>>>(h, ea, ew, dstI, ofs, eid, agg, N);
    k_gin<<<cdiv(N * 8, 128), 256, 0, stream>>>(
        h, agg, gin_W1 + l * 16384, gin_b1 + l * 128, gin_W2 + l * 16384, gin_b2 + l * 128, N * 8);
  }
  // 6. GRU
  gemm_bf<0, 0, false><<<dim3(cdiv(N, 128), 3), 256, 0, stream>>>(
      memory, nullptr, nullptr, W_hh, b_hh, gh, N, 128, 384);
  gemm_bf<2, 0, false, true><<<dim3(cdiv(N * 8, 128), 3), 256, 0, stream>>>(
      h, te, nullptr, W_ih, b_ih, gi, N * 8, 128, 384);
  k_gru<<<cdiv(N * 1024, 256), 256, 0, stream>>>(gi, gh, memory, h_new, N * 1024);
  // 7. pooled + global K/G
  hipMemsetAsync(prw, 0, 1024 * sizeof(float), stream);
  k_pool<<<256, 256, 0, stream>>>(h_new, prw, N);
  k_kgg<<<1, 256, 0, stream>>>(prw, Wk_g, Wv_g, bv_g, Wo_g, Kg, G, N);
  // 8. local attention
  gemm_bf<0, 0, false><<<dim3(cdiv(E, 128), 2), 256, 0, stream>>>(
      ea, nullptr, nullptr, Wqk, bqk, qk12, E, 128, 256);
  k_local<<<E, 256, 0, stream>>>(h_new, qk12, srcI, dstI, wsd, E);
  gemm_bf<0, 0, false><<<dim3(cdiv(E, 128), 1), 256, 0, stream>>>(
      wsd, nullptr, nullptr, Wl2, blv, lclb, E, 256, 128);
  // 9. global attention
  gemm_bf<0, 0, false><<<dim3(cdiv(E, 128), 1), 256, 0, stream>>>(
      ea, nullptr, nullptr, Wq_g, bq_g, q_g, E, 128, 128);
  k_global<<<cdiv(E, 4), 256, 0, stream>>>(q_g, Kg, G, bo_g, ag_out, glbb, E);
  // 10. classifier
  gemm_bf<3, 1, false><<<dim3(cdiv(E, 128), 1), 256, 0, stream>>>(
      ea, lclb, glbb, Wc1, bc1, hid, E, 384, 128);
  k_logits<<<cdiv(E, 4), 256, 0, stream>>>(hid, Wc2, bc2, logits, E);
}

// Round 4
// 680.121 us; speedup vs baseline: 2.9615x; 1.1214x over previous
//
#include <hip/hip_runtime.h>
#include <cstddef>

// MVMGIN round 4: bf16 everywhere.
//  - All edge/node intermediates stored bf16 (ea, qk12, wsd, lclb, q_g, glbb, hid,
//    gi, agg, h_new) + bf16 mirrors of memory/h for gathers; f32 residual chain
//    memory -> h1f -> h(d_out) kept for accuracy.
//  - Layer-1 GIN specialization: h == broadcast(memory) -> gather 256B memb rows
//    instead of 4KB h rows; k_hinit deleted.
//  - GEMM A-staging reads bf16 directly (ABF path).
// Algebra (earlier rounds): q_l folded into qk12; local V/O folded into Wl2/blv;
// bk_l/bk_g dropped (cancel in softmax); scatter-add -> CSR gather.
// Outputs (f32, concat): logits(E,5) | ew(E,8) | h_before(N,8,128) | a_g(E,8)

#define HSZ 128
typedef unsigned short ushortT;
typedef short short8 __attribute__((ext_vector_type(8)));
typedef float f32x4 __attribute__((ext_vector_type(4)));

__device__ __forceinline__ float sigm(float x) { return 1.f / (1.f + __expf(-x)); }

__device__ __forceinline__ ushortT f2bf(float f) {
  unsigned int u = __float_as_uint(f);
  u += 0x7fffu + ((u >> 16) & 1u);
  return (ushortT)(u >> 16);
}
__device__ __forceinline__ float bf2f(ushortT u) {
  return __uint_as_float(((unsigned int)u) << 16);
}

// XOR-swizzled LDS chunk index (in shorts): row stride 64 shorts.
__device__ __forceinline__ int swzA(int row, int chunk) {
  return row * 64 + (((chunk ^ row) & 7) << 3);
}
__device__ __forceinline__ int swzT(int row, int chunk) {
  return row * 128 + (((chunk & 8) | ((chunk ^ row) & 7)) << 3);
}

// ---------------- bf16 MFMA GEMM ----------------
// out(M,Nout) = ACT( Asrc(M,K) @ W^T + bias ); W row-major (Nout,K), f32.
// ASRC: 0=A1, 2=A1 + f32 rowvec A2[k], 3=concat{A1,A2,A3} width 128 each
// ABF: A sources are bf16 (K must be mult of 64). OUTBF: bf16 output.
template<int ASRC, int ACT, bool ACC, bool OUTBF, bool ABF>
__global__ __launch_bounds__(256) void gemm_bf(
    const void* __restrict__ A1, const void* __restrict__ A2, const void* __restrict__ A3,
    const float* __restrict__ W, const float* __restrict__ bias,
    void* __restrict__ out_, int M, int K, int Nout)
{
  __shared__ short Ash[128 * 64];
  __shared__ short Bsh[128 * 64];
  float* out = (float*)out_;
  ushortT* outh = (ushortT*)out_;
  const int tid = threadIdx.x;
  const int m0 = blockIdx.x * 128;
  const int n0 = blockIdx.y * 128;
  const int l = tid & 63, w = tid >> 6;
  const int wr = w >> 1, wc = w & 1;
  const int lr = l & 15, lq = l >> 4;
  f32x4 acc[4][4] = {};

  for (int k0 = 0; k0 < K; k0 += 64) {
    __syncthreads();
    const bool fast = (k0 + 64 <= K);
    #pragma unroll
    for (int i = 0; i < 4; ++i) {
      int c = i * 256 + tid;
      int row = c >> 3, seg = c & 7;
      int kb = k0 + seg * 8;
      // ---- stage A ----
      {
        int m = m0 + row;
        short8 pk;
        if (ABF) {
          const ushortT* A1h = (const ushortT*)A1;
          if (m < M) {  // K%64==0 guaranteed for ABF users
            if (ASRC == 3) {
              const ushortT* S = (kb < 128) ? (const ushortT*)A1
                               : (kb < 256) ? (const ushortT*)A2 : (const ushortT*)A3;
              pk = *reinterpret_cast<const short8*>(S + (size_t)m * 128 + (kb & 127));
            } else if (ASRC == 2) {
              short8 x = *reinterpret_cast<const short8*>(A1h + (size_t)m * K + kb);
              const float* t = (const float*)A2;
              #pragma unroll
              for (int j = 0; j < 8; ++j) pk[j] = (short)f2bf(bf2f((ushortT)x[j]) + t[kb + j]);
            } else {
              pk = *reinterpret_cast<const short8*>(A1h + (size_t)m * K + kb);
            }
          } else {
            #pragma unroll
            for (int j = 0; j < 8; ++j) pk[j] = 0;
          }
        } else {
          const float* A1f = (const float*)A1;
          float v[8];
          if (fast && m < M) {
            const float4* p = reinterpret_cast<const float4*>(A1f + (size_t)m * K + kb);
            float4 x0 = p[0], x1 = p[1];
            v[0]=x0.x; v[1]=x0.y; v[2]=x0.z; v[3]=x0.w;
            v[4]=x1.x; v[5]=x1.y; v[6]=x1.z; v[7]=x1.w;
          } else {
            #pragma unroll
            for (int j = 0; j < 8; ++j) {
              int k = kb + j;
              v[j] = (m < M && k < K) ? A1f[(size_t)m * K + k] : 0.f;
            }
          }
          #pragma unroll
          for (int j = 0; j < 8; ++j) pk[j] = (short)f2bf(v[j]);
        }
        *reinterpret_cast<short8*>(&Ash[swzA(row, seg)]) = pk;
      }
      // ---- stage B (W rows, f32) ----
      {
        int nn = n0 + row;
        float v[8];
        if (fast && nn < Nout) {
          const float4* p = reinterpret_cast<const float4*>(W + (size_t)nn * K + kb);
          float4 x0 = p[0], x1 = p[1];
          v[0]=x0.x; v[1]=x0.y; v[2]=x0.z; v[3]=x0.w;
          v[4]=x1.x; v[5]=x1.y; v[6]=x1.z; v[7]=x1.w;
        } else {
          #pragma unroll
          for (int j = 0; j < 8; ++j) {
            int k = kb + j;
            v[j] = (nn < Nout && k < K) ? W[(size_t)nn * K + k] : 0.f;
          }
        }
        short8 pk;
        #pragma unroll
        for (int j = 0; j < 8; ++j) pk[j] = (short)f2bf(v[j]);
        *reinterpret_cast<short8*>(&Bsh[swzA(row, seg)]) = pk;
      }
    }
    __syncthreads();
    #pragma unroll
    for (int ks = 0; ks < 2; ++ks) {
      short8 a[4], b[4];
      #pragma unroll
      for (int mi = 0; mi < 4; ++mi)
        a[mi] = *reinterpret_cast<const short8*>(&Ash[swzA(wr*64 + mi*16 + lr, ks*4 + lq)]);
      #pragma unroll
      for (int ni = 0; ni < 4; ++ni)
        b[ni] = *reinterpret_cast<const short8*>(&Bsh[swzA(wc*64 + ni*16 + lr, ks*4 + lq)]);
      #pragma unroll
      for (int mi = 0; mi < 4; ++mi)
        #pragma unroll
        for (int ni = 0; ni < 4; ++ni)
          acc[mi][ni] = __builtin_amdgcn_mfma_f32_16x16x32_bf16(a[mi], b[ni], acc[mi][ni], 0, 0, 0);
    }
  }
  #pragma unroll
  for (int ni = 0; ni < 4; ++ni) {
    int col = n0 + wc*64 + ni*16 + lr;
    if (col >= Nout) continue;
    float bz = bias ? bias[col] : 0.f;
    #pragma unroll
    for (int mi = 0; mi < 4; ++mi) {
      int mb = m0 + wr*64 + mi*16 + lq*4;
      #pragma unroll
      for (int r = 0; r < 4; ++r) {
        int m = mb + r;
        if (m >= M) continue;
        float vv = acc[mi][ni][r] + bz;
        size_t o = (size_t)m * Nout + col;
        if (OUTBF) {
          if (ACT == 1) vv = fmaxf(vv, 0.f);
          outh[o] = f2bf(vv);
        } else {
          if (ACC) vv += out[o];
          if (ACT == 1) vv = fmaxf(vv, 0.f);
          out[o] = vv;
        }
      }
    }
  }
}

// ---------------- fused GIN layer ----------------
// LMODE 1: A = memb(bcast over v) + aggb; base = memory f32 (per node)
// LMODE 2: A = h1b + aggb;               base = h1f f32 (per row)
// hout = base + relu(A@W1^T+b1)@W2^T + b2 ; write houtf (f32) + houtb (bf16)
template<int LMODE>
__global__ __launch_bounds__(256, 2) void k_gin(
    const ushortT* __restrict__ hb, const ushortT* __restrict__ aggb,
    const float* __restrict__ basef,
    float* __restrict__ houtf, ushortT* __restrict__ houtb,
    const float* __restrict__ W1, const float* __restrict__ b1,
    const float* __restrict__ W2, const float* __restrict__ b2, int M)
{
  __shared__ short Ash[128 * 64];
  __shared__ short Bsh[128 * 64];
  __shared__ short Tsh[128 * 128];
  const int tid = threadIdx.x;
  const int m0 = blockIdx.x * 128;
  const int l = tid & 63, w = tid >> 6;
  const int wr = w >> 1, wc = w & 1;
  const int lr = l & 15, lq = l >> 4;
  f32x4 acc[4][4] = {};

  for (int ks2 = 0; ks2 < 2; ++ks2) {
    __syncthreads();
    #pragma unroll
    for (int i = 0; i < 4; ++i) {
      int c = i * 256 + tid;
      int row = c >> 3, seg = c & 7;
      int kb = ks2 * 64 + seg * 8;
      {
        int r = m0 + row;
        short8 pk;
        if (r < M) {
          short8 hv, av;
          if (LMODE == 1) hv = *reinterpret_cast<const short8*>(hb + ((size_t)(r >> 3)) * 128 + kb);
          else            hv = *reinterpret_cast<const short8*>(hb + (size_t)r * 128 + kb);
          av = *reinterpret_cast<const short8*>(aggb + (size_t)r * 128 + kb);
          #pragma unroll
          for (int j = 0; j < 8; ++j)
            pk[j] = (short)f2bf(bf2f((ushortT)hv[j]) + bf2f((ushortT)av[j]));
        } else {
          #pragma unroll
          for (int j = 0; j < 8; ++j) pk[j] = 0;
        }
        *reinterpret_cast<short8*>(&Ash[swzA(row, seg)]) = pk;
      }
      {
        const float4* p = reinterpret_cast<const float4*>(W1 + (size_t)row * 128 + kb);
        float4 x0 = p[0], x1 = p[1];
        short8 pk;
        pk[0]=(short)f2bf(x0.x); pk[1]=(short)f2bf(x0.y);
        pk[2]=(short)f2bf(x0.z); pk[3]=(short)f2bf(x0.w);
        pk[4]=(short)f2bf(x1.x); pk[5]=(short)f2bf(x1.y);
        pk[6]=(short)f2bf(x1.z); pk[7]=(short)f2bf(x1.w);
        *reinterpret_cast<short8*>(&Bsh[swzA(row, seg)]) = pk;
      }
    }
    __syncthreads();
    #pragma unroll
    for (int ks = 0; ks < 2; ++ks) {
      short8 a[4], b[4];
      #pragma unroll
      for (int mi = 0; mi < 4; ++mi)
        a[mi] = *reinterpret_cast<const short8*>(&Ash[swzA(wr*64 + mi*16 + lr, ks*4 + lq)]);
      #pragma unroll
      for (int ni = 0; ni < 4; ++ni)
        b[ni] = *reinterpret_cast<const short8*>(&Bsh[swzA(wc*64 + ni*16 + lr, ks*4 + lq)]);
      #pragma unroll
      for (int mi = 0; mi < 4; ++mi)
        #pragma unroll
        for (int ni = 0; ni < 4; ++ni)
          acc[mi][ni] = __builtin_amdgcn_mfma_f32_16x16x32_bf16(a[mi], b[ni], acc[mi][ni], 0, 0, 0);
    }
  }
  {
    float b1v[4];
    #pragma unroll
    for (int ni = 0; ni < 4; ++ni) b1v[ni] = b1[wc*64 + ni*16 + lr];
    #pragma unroll
    for (int mi = 0; mi < 4; ++mi)
      #pragma unroll
      for (int ni = 0; ni < 4; ++ni) {
        int col = wc*64 + ni*16 + lr;
        #pragma unroll
        for (int r = 0; r < 4; ++r) {
          int row = wr*64 + mi*16 + lq*4 + r;
          float v = fmaxf(acc[mi][ni][r] + b1v[ni], 0.f);
          Tsh[swzT(row, col >> 3) + (col & 7)] = (short)f2bf(v);
        }
      }
  }
  f32x4 acc2[4][4] = {};
  for (int ks2 = 0; ks2 < 2; ++ks2) {
    __syncthreads();
    #pragma unroll
    for (int i = 0; i < 4; ++i) {
      int c = i * 256 + tid;
      int row = c >> 3, seg = c & 7;
      int kb = ks2 * 64 + seg * 8;
      const float4* p = reinterpret_cast<const float4*>(W2 + (size_t)row * 128 + kb);
      float4 x0 = p[0], x1 = p[1];
      short8 pk;
      pk[0]=(short)f2bf(x0.x); pk[1]=(short)f2bf(x0.y);
      pk[2]=(short)f2bf(x0.z); pk[3]=(short)f2bf(x0.w);
      pk[4]=(short)f2bf(x1.x); pk[5]=(short)f2bf(x1.y);
      pk[6]=(short)f2bf(x1.z); pk[7]=(short)f2bf(x1.w);
      *reinterpret_cast<short8*>(&Bsh[swzA(row, seg)]) = pk;
    }
    __syncthreads();
    #pragma unroll
    for (int ks = 0; ks < 2; ++ks) {
      short8 a[4], b[4];
      #pragma unroll
      for (int mi = 0; mi < 4; ++mi)
        a[mi] = *reinterpret_cast<const short8*>(&Tsh[swzT(wr*64 + mi*16 + lr, ks2*8 + ks*4 + lq)]);
      #pragma unroll
      for (int ni = 0; ni < 4; ++ni)
        b[ni] = *reinterpret_cast<const short8*>(&Bsh[swzA(wc*64 + ni*16 + lr, ks*4 + lq)]);
      #pragma unroll
      for (int mi = 0; mi < 4; ++mi)
        #pragma unroll
        for (int ni = 0; ni < 4; ++ni)
          acc2[mi][ni] = __builtin_amdgcn_mfma_f32_16x16x32_bf16(a[mi], b[ni], acc2[mi][ni], 0, 0, 0);
    }
  }
  {
    float b2v[4];
    #pragma unroll
    for (int ni = 0; ni < 4; ++ni) b2v[ni] = b2[wc*64 + ni*16 + lr];
    #pragma unroll
    for (int ni = 0; ni < 4; ++ni) {
      int col = wc*64 + ni*16 + lr;
      #pragma unroll
      for (int mi = 0; mi < 4; ++mi) {
        int mb = m0 + wr*64 + mi*16 + lq*4;
        #pragma unroll
        for (int r = 0; r < 4; ++r) {
          int m = mb + r;
          if (m >= M) continue;
          float base = (LMODE == 1) ? basef[((size_t)(m >> 3)) * 128 + col]
                                    : basef[(size_t)m * 128 + col];
          float ho = base + acc2[mi][ni][r] + b2v[ni];
          size_t o = (size_t)m * 128 + col;
          houtf[o] = ho;
          houtb[o] = f2bf(ho);
        }
      }
    }
  }
}

// ---------------- CSR build ----------------
__global__ void k_hist(const int* __restrict__ srcI, int* __restrict__ cnt, int E)
{
  int e = blockIdx.x * 256 + threadIdx.x;
  if (e < E) atomicAdd(&cnt[srcI[e]], 1);
}

__global__ __launch_bounds__(1024) void k_scan(const int* __restrict__ cnt,
    int* __restrict__ ofs, int* __restrict__ cur, int N)
{
  __shared__ int buf[1024];
  __shared__ int carry;
  int tid = threadIdx.x;
  if (tid == 0) carry = 0;
  __syncthreads();
  for (int base = 0; base < N; base += 1024) {
    int i = base + tid;
    int v = (i < N) ? cnt[i] : 0;
    buf[tid] = v;
    __syncthreads();
    for (int off = 1; off < 1024; off <<= 1) {
      int t = (tid >= off) ? buf[tid - off] : 0;
      __syncthreads();
      buf[tid] += t;
      __syncthreads();
    }
    int excl = carry + buf[tid] - v;
    if (i < N) { ofs[i] = excl; cur[i] = excl; }
    __syncthreads();
    if (tid == 0) carry += buf[1023];
    __syncthreads();
  }
  if (tid == 0) ofs[N] = carry;
}

__global__ void k_fill(const int* __restrict__ srcI, int* __restrict__ cur,
                       int* __restrict__ eid, int E)
{
  int e = blockIdx.x * 256 + threadIdx.x;
  if (e >= E) return;
  int p = atomicAdd(&cur[srcI[e]], 1);
  eid[p] = e;
}

// ---------------- GIN aggregation (CSR gather, bf16) ----------------
// LMODE 1: h row = memb[d] (broadcast over v, 256B); LMODE 2: h1b rows (2KB)
template<int LMODE>
__global__ __launch_bounds__(256) void k_agg(const ushortT* __restrict__ hb,
    const ushortT* __restrict__ eab, const float* __restrict__ ew,
    const int* __restrict__ dstI, const int* __restrict__ ofs,
    const int* __restrict__ eid, ushortT* __restrict__ aggb, int N)
{
  int half = threadIdx.x >> 7;
  int x = threadIdx.x & 127;
  int n = blockIdx.x * 2 + half;
  if (n >= N) return;
  float acc[8] = {};
  int beg = ofs[n], end = ofs[n + 1];
  for (int i = beg; i < end; ++i) {
    int e = eid[i];
    int d = dstI[e];
    float eav = bf2f(eab[(size_t)e * 128 + x]);
    const float* ewp = ew + (size_t)e * 8;
    if (LMODE == 1) {
      float m = fmaxf(bf2f(hb[(size_t)d * 128 + x]) + eav, 0.f);
      #pragma unroll
      for (int v = 0; v < 8; ++v) acc[v] += m * ewp[v];
    } else {
      const ushortT* hd = hb + (size_t)d * 1024;
      #pragma unroll
      for (int v = 0; v < 8; ++v)
        acc[v] += fmaxf(bf2f(hd[v * 128 + x]) + eav, 0.f) * ewp[v];
    }
  }
  ushortT* ag = aggb + (size_t)n * 1024;
  #pragma unroll
  for (int v = 0; v < 8; ++v) ag[v * 128 + x] = f2bf(acc[v]);
}

// ---------------- edge gate (bf16 inputs) ----------------
__global__ __launch_bounds__(256) void k_ew(const ushortT* __restrict__ eab,
    const ushortT* __restrict__ memb, const int* __restrict__ srcI,
    const float* __restrict__ W_ewg, const float* __restrict__ b_ewg,
    float* __restrict__ ew, int E)
{
  __shared__ float Wsh[2048];
  __shared__ float bsh[8];
  int tid = threadIdx.x;
  for (int i = tid; i < 2048; i += 256) Wsh[i] = W_ewg[i];
  if (tid < 8) bsh[tid] = b_ewg[tid];
  __syncthreads();
  int wv = tid >> 6, lane = tid & 63;
  int e = blockIdx.x * 4 + wv;
  if (e >= E) return;
  int s = srcI[e];
  float c0 = bf2f(eab[(size_t)e * 128 + lane]);
  float c1 = bf2f(eab[(size_t)e * 128 + 64 + lane]);
  float c2 = bf2f(memb[(size_t)s * 128 + lane]);
  float c3 = bf2f(memb[(size_t)s * 128 + 64 + lane]);
  #pragma unroll
  for (int v = 0; v < 8; ++v) {
    float p = c0 * Wsh[v * 256 + lane] + c1 * Wsh[v * 256 + 64 + lane]
            + c2 * Wsh[v * 256 + 128 + lane] + c3 * Wsh[v * 256 + 192 + lane];
    #pragma unroll
    for (int o = 32; o; o >>= 1) p += __shfl_down(p, o);
    if (lane == 0) ew[(size_t)e * 8 + v] = sigm(p + bsh[v]);
  }
}

// ---------------- f32 -> bf16 copy ----------------
__global__ void k_cvt(const float* __restrict__ src, ushortT* __restrict__ dst, int total)
{
  int i = blockIdx.x * 256 + threadIdx.x;
  if (i < total) dst[i] = f2bf(src[i]);
}

// ---------------- te ----------------
__global__ void k_te(const float* __restrict__ delta_t, const float* __restrict__ W_t,
                     const float* __restrict__ b_t, float* __restrict__ te)
{
  int t = threadIdx.x;
  if (t < 128) te[t] = sinf(delta_t[0] * W_t[t] + b_t[t]);
}

// ---------------- GRU elementwise (gi bf16 -> h_new bf16) ----------------
__global__ void k_gru(const ushortT* __restrict__ gi, const float* __restrict__ gh,
                      const float* __restrict__ memory, ushortT* __restrict__ hnb, int total)
{
  int idx = blockIdx.x * 256 + threadIdx.x;
  if (idx >= total) return;
  int n = idx >> 10, x = idx & 127, row = idx >> 7;
  size_t gio = (size_t)row * 384 + x;
  size_t gho = (size_t)n * 384 + x;
  float r = sigm(bf2f(gi[gio]) + gh[gho]);
  float z = sigm(bf2f(gi[gio + 128]) + gh[gho + 128]);
  float nn = tanhf(bf2f(gi[gio + 256]) + r * gh[gho + 256]);
  float mem = memory[(size_t)n * 128 + x];
  hnb[idx] = f2bf((1.f - z) * nn + z * mem);
}

// ---------------- pooled partial sums (bf16 in) ----------------
__global__ __launch_bounds__(256) void k_pool(const ushortT* __restrict__ hnb,
                                              float* __restrict__ prw, int N)
{
  int tid = threadIdx.x;
  float acc[4] = {0.f, 0.f, 0.f, 0.f};
  for (int n = blockIdx.x; n < N; n += gridDim.x) {
    const ushortT* row = hnb + (size_t)n * 1024;
    #pragma unroll
    for (int j = 0; j < 4; ++j) acc[j] += bf2f(row[tid + j * 256]);
  }
  #pragma unroll
  for (int j = 0; j < 4; ++j) atomicAdd(&prw[tid + j * 256], acc[j]);
}

// ---------------- fused small mats ----------------
__global__ __launch_bounds__(256) void k_prep(
    const float* __restrict__ Wo_l, const float* __restrict__ Wv_l,
    const float* __restrict__ bv_l, const float* __restrict__ bo_l,
    const float* __restrict__ Wq_l, const float* __restrict__ bq_l,
    const float* __restrict__ Wk_l,
    float* __restrict__ Wl2, float* __restrict__ blv,
    float* __restrict__ Wqk, float* __restrict__ bqk)
{
  int idx = blockIdx.x * 256 + threadIdx.x;
  if (idx < 32768) {
    int n = idx >> 8, k = idx & 255;
    float a = 0.f;
    for (int j = 0; j < 128; ++j) a += Wo_l[n * 128 + j] * Wv_l[j * 256 + k];
    Wl2[idx] = a;
  } else {
    int rem = idx - 32768;
    int n = rem >> 7, j = rem & 127;
    float a = 0.f;
    for (int k = 0; k < 128; ++k) a += Wq_l[k * 128 + j] * Wk_l[k * 256 + n];
    Wqk[rem] = a;
  }
  if (blockIdx.x == 0 && threadIdx.x < 128) {
    int n = threadIdx.x;
    float a = bo_l[n];
    for (int j = 0; j < 128; ++j) a += Wo_l[n * 128 + j] * bv_l[j];
    blv[n] = a;
  }
  if (blockIdx.x == 1) {
    int n = threadIdx.x;
    float a = 0.f;
    for (int k = 0; k < 128; ++k) a += bq_l[k] * Wk_l[k * 256 + n];
    bqk[n] = a;
  }
}

// ---------------- Kg / G for global attention ----------------
__global__ __launch_bounds__(256) void k_kgg(const float* __restrict__ prw,
    const float* __restrict__ Wk_g, const float* __restrict__ Wv_g, const float* __restrict__ bv_g,
    const float* __restrict__ Wo_g, float* __restrict__ Kg, float* __restrict__ G, int N)
{
  __shared__ float pl[1024];
  __shared__ float vg[1024];
  int tid = threadIdx.x;
  float invN = 1.f / (float)N;
  for (int i = tid; i < 1024; i += 256) pl[i] = prw[i] * invN;
  __syncthreads();
  for (int o = tid; o < 1024; o += 256) {
    int v = o >> 7, x = o & 127;
    float a = 0.f, b = 0.f;
    for (int k = 0; k < 128; ++k) {
      float p = pl[v * 128 + k];
      a += p * Wk_g[(size_t)x * 128 + k];
      b += p * Wv_g[(size_t)x * 128 + k];
    }
    Kg[o] = a;
    vg[o] = b + bv_g[x];
  }
  __syncthreads();
  for (int o = tid; o < 1024; o += 256) {
    int v = o >> 7, x = o & 127;
    float a = 0.f;
    for (int k = 0; k < 128; ++k) a += vg[v * 128 + k] * Wo_g[(size_t)x * 128 + k];
    G[o] = a;
  }
}

// ---------------- fused local attention (bf16) ----------------
__global__ __launch_bounds__(256) void k_local(const ushortT* __restrict__ hnb,
    const ushortT* __restrict__ qk12b,
    const int* __restrict__ srcI, const int* __restrict__ dstI,
    ushortT* __restrict__ wsd, int E)
{
  __shared__ float sf[1024], df[1024], q12[256], sc[8];
  int e = blockIdx.x;
  int tid = threadIdx.x;
  int s = srcI[e], d = dstI[e];
  {
    int c = tid & 127;
    const ushortT* srcp = (tid < 128) ? hnb + (size_t)s * 1024 : hnb + (size_t)d * 1024;
    short8 v = *reinterpret_cast<const short8*>(srcp + c * 8);
    float* dl = (tid < 128) ? sf : df;
    #pragma unroll
    for (int j = 0; j < 8; ++j) dl[c * 8 + j] = bf2f((ushortT)v[j]);
  }
  if (tid < 32) {
    short8 v = *reinterpret_cast<const short8*>(qk12b + (size_t)e * 256 + tid * 8);
    #pragma unroll
    for (int j = 0; j < 8; ++j) q12[tid * 8 + j] = bf2f((ushortT)v[j]);
  }
  __syncthreads();
  int wv = tid >> 6, lane = tid & 63;
  for (int v = wv; v < 8; v += 4) {
    float p = q12[lane] * sf[v * 128 + lane] + q12[64 + lane] * sf[v * 128 + 64 + lane]
            + q12[128 + lane] * df[v * 128 + lane] + q12[192 + lane] * df[v * 128 + 64 + lane];
    #pragma unroll
    for (int o = 32; o; o >>= 1) p += __shfl_down(p, o);
    if (lane == 0) sc[v] = p * 0.08838834764831845f;   // 1/sqrt(128)
  }
  __syncthreads();
  float mx = sc[0];
  #pragma unroll
  for (int v = 1; v < 8; ++v) mx = fmaxf(mx, sc[v]);
  float a[8], sum = 0.f;
  #pragma unroll
  for (int v = 0; v < 8; ++v) { a[v] = __expf(sc[v] - mx); sum += a[v]; }
  float inv = 1.f / sum;
  int x = tid & 127;
  const float* mat = (tid < 128) ? sf : df;
  float accv = 0.f;
  #pragma unroll
  for (int v = 0; v < 8; ++v) accv += a[v] * mat[v * 128 + x];
  wsd[(size_t)e * 256 + (tid < 128 ? x : 128 + x)] = f2bf(accv * inv);
}

// ---------------- global attention (bf16 q/out) ----------------
__global__ __launch_bounds__(256) void k_global(const ushortT* __restrict__ qgb,
    const float* __restrict__ Kg, const float* __restrict__ G, const float* __restrict__ bo_g,
    float* __restrict__ ag_out, ushortT* __restrict__ goutb, int E)
{
  __shared__ float Kgs[1024], Gs[1024], bs[128];
  int tid = threadIdx.x;
  for (int i = tid; i < 1024; i += 256) { Kgs[i] = Kg[i]; Gs[i] = G[i]; }
  if (tid < 128) bs[tid] = bo_g[tid];
  __syncthreads();
  int wv = tid >> 6, lane = tid & 63;
  int e = blockIdx.x * 4 + wv;
  if (e >= E) return;
  float qa = bf2f(qgb[(size_t)e * 128 + lane]), qb = bf2f(qgb[(size_t)e * 128 + 64 + lane]);
  float s[8];
  #pragma unroll
  for (int v = 0; v < 8; ++v) {
    float p = qa * Kgs[v * 128 + lane] + qb * Kgs[v * 128 + 64 + lane];
    #pragma unroll
    for (int o = 32; o; o >>= 1) p += __shfl_xor(p, o);
    s[v] = p * 0.08838834764831845f;
  }
  float mx = s[0];
  #pragma unroll
  for (int v = 1; v < 8; ++v) mx = fmaxf(mx, s[v]);
  float sum = 0.f;
  #pragma unroll
  for (int v = 0; v < 8; ++v) { s[v] = __expf(s[v] - mx); sum += s[v]; }
  float inv = 1.f / sum;
  #pragma unroll
  for (int v = 0; v < 8; ++v) s[v] *= inv;
  #pragma unroll
  for (int v = 0; v < 8; ++v) if (lane == v) ag_out[(size_t)e * 8 + v] = s[v];
  float g0 = bs[lane], g1 = bs[64 + lane];
  #pragma unroll
  for (int v = 0; v < 8; ++v) {
    g0 += s[v] * Gs[v * 128 + lane];
    g1 += s[v] * Gs[v * 128 + 64 + lane];
  }
  goutb[(size_t)e * 128 + lane] = f2bf(g0);
  goutb[(size_t)e * 128 + 64 + lane] = f2bf(g1);
}

// ---------------- logits (bf16 in) ----------------
__global__ __launch_bounds__(256) void k_logits(const ushortT* __restrict__ hid,
    const float* __restrict__ Wc2, const float* __restrict__ bc2,
    float* __restrict__ logits, int E)
{
  __shared__ float Wsh[640];
  __shared__ float bsh[5];
  int tid = threadIdx.x;
  for (int i = tid; i < 640; i += 256) Wsh[i] = Wc2[i];
  if (tid < 5) bsh[tid] = bc2[tid];
  __syncthreads();
  int wv = tid >> 6, lane = tid & 63;
  int e = blockIdx.x * 4 + wv;
  if (e >= E) return;
  float h0 = bf2f(hid[(size_t)e * 128 + lane]), h1 = bf2f(hid[(size_t)e * 128 + 64 + lane]);
  #pragma unroll
  for (int c = 0; c < 5; ++c) {
    float p = h0 * Wsh[c * 128 + lane] + h1 * Wsh[c * 128 + 64 + lane];
    #pragma unroll
    for (int o = 32; o; o >>= 1) p += __shfl_down(p, o);
    if (lane == 0) logits[(size_t)e * 5 + c] = p + bsh[c];
  }
}

extern "C" void kernel_launch(void* const* d_in, const int* in_sizes, int n_in,
                              void* d_out, int out_size, void* d_ws, size_t ws_size,
                              hipStream_t stream)
{
  const int*   edge_index = (const int*)d_in[0];
  const float* edge_attr  = (const float*)d_in[1];
  const float* delta_t    = (const float*)d_in[2];
  const float* memory     = (const float*)d_in[3];
  const float* W_ee  = (const float*)d_in[4];
  const float* b_ee  = (const float*)d_in[5];
  const float* W_ewg = (const float*)d_in[6];
  const float* b_ewg = (const float*)d_in[7];
  const float* gin_W1 = (const float*)d_in[8];
  const float* gin_b1 = (const float*)d_in[9];
  const float* gin_W2 = (const float*)d_in[10];
  const float* gin_b2 = (const float*)d_in[11];
  const float* W_t  = (const float*)d_in[12];
  const float* b_t  = (const float*)d_in[13];
  const float* W_ih = (const float*)d_in[14];
  const float* b_ih = (const float*)d_in[15];
  const float* W_hh = (const float*)d_in[16];
  const float* b_hh = (const float*)d_in[17];
  const float* Wq_l = (const float*)d_in[20];
  const float* bq_l = (const float*)d_in[21];
  const float* Wk_l = (const float*)d_in[22];
  const float* Wv_l = (const float*)d_in[24];
  const float* bv_l = (const float*)d_in[25];
  const float* Wo_l = (const float*)d_in[26];
  const float* bo_l = (const float*)d_in[27];
  const float* Wq_g = (const float*)d_in[28];
  const float* bq_g = (const float*)d_in[29];
  const float* Wk_g = (const float*)d_in[30];
  const float* Wv_g = (const float*)d_in[32];
  const float* bv_g = (const float*)d_in[33];
  const float* Wo_g = (const float*)d_in[34];
  const float* bo_g = (const float*)d_in[35];
  const float* Wc1  = (const float*)d_in[36];
  const float* bc1  = (const float*)d_in[37];
  const float* Wc2  = (const float*)d_in[38];
  const float* bc2  = (const float*)d_in[39];

  const int E = in_sizes[0] / 2;
  const int N = in_sizes[3] / HSZ;
  const int* srcI = edge_index;
  const int* dstI = edge_index + E;

  float* out    = (float*)d_out;
  float* logits = out;
  float* ew     = out + (size_t)E * 5;
  float* h      = out + (size_t)E * 13;                       // h_before (N,8,128) f32
  float* ag_out = out + (size_t)E * 13 + (size_t)N * 1024;

  // ---- workspace arena (units: f32 slots) ----
  float* ws = (float*)d_ws;
  size_t off = 0;
  auto alloc = [&](size_t n) { size_t o = off; off += (n + 255) & ~(size_t)255; return o; };
  float* te   = ws + alloc(128);
  float* Wl2  = ws + alloc(32768);
  float* blv  = ws + alloc(128);
  float* Wqk  = ws + alloc(32768);
  float* bqk  = ws + alloc(256);
  float* Kg   = ws + alloc(1024);
  float* G    = ws + alloc(1024);
  float* prw  = ws + alloc(1024);
  int* cnt = (int*)(ws + alloc(N));
  int* ofs = (int*)(ws + alloc(N + 1));
  int* cur = (int*)(ws + alloc(N));
  int* eid = (int*)(ws + alloc(E));
  ushortT* memb = (ushortT*)(ws + alloc((size_t)N * 64));          // (N,128) bf16
  ushortT* eab  = (ushortT*)(ws + alloc((size_t)E * 64));          // (E,128) bf16
  ushortT* h1b  = (ushortT*)(ws + alloc((size_t)N * 512));         // (N*8,128) bf16
  ushortT* h2b  = (ushortT*)(ws + alloc((size_t)N * 512));
  ushortT* hnb  = (ushortT*)(ws + alloc((size_t)N * 512));
  float*   gh   = ws + alloc((size_t)N * 384);
  // BR union: GIN {aggb(N*512) + h1f(N*1024)} | gi(N*1536) | attn(E*256)
  size_t brA = (size_t)N * 1536;
  size_t brC = (size_t)E * 256;
  size_t brsz = brA > brC ? brA : brC;
  float* BR = ws + alloc(brsz);
  if (ws_size < off * sizeof(float)) return;   // needs ~158 MiB

  ushortT* aggb = (ushortT*)BR;                      // N*512 slots
  float*   h1f  = BR + (size_t)N * 512;              // N*1024 slots
  ushortT* gi   = (ushortT*)BR;                      // N*1536 slots
  // attention phase (E*256 slots):
  ushortT* qk12b = (ushortT*)BR;                             // [0, E*128)
  ushortT* wsd   = (ushortT*)(BR + (size_t)E * 128);         // [E*128, E*256)
  ushortT* lclb  = (ushortT*)BR;                             // [0, E*64)   after k_local
  ushortT* qgb   = (ushortT*)(BR + (size_t)E * 64);          // [E*64, E*128)
  ushortT* glbb  = (ushortT*)(BR + (size_t)E * 128);         // over dead wsd
  ushortT* hid   = (ushortT*)(BR + (size_t)E * 192);

  auto cdiv = [](int a, int b) { return (a + b - 1) / b; };

  // 0. CSR build + memb
  hipMemsetAsync(cnt, 0, (size_t)N * sizeof(int), stream);
  k_hist<<<cdiv(E, 256), 256, 0, stream>>>(srcI, cnt, E);
  k_scan<<<1, 1024, 0, stream>>>(cnt, ofs, cur, N);
  k_fill<<<cdiv(E, 256), 256, 0, stream>>>(srcI, cur, eid, E);
  k_cvt<<<cdiv(N * 128, 256), 256, 0, stream>>>(memory, memb, N * 128);
  // 1. ea = relu(edge_attr @ W_ee^T + b_ee) -> bf16
  gemm_bf<0, 1, false, true, false><<<dim3(cdiv(E, 128), 1), 256, 0, stream>>>(
      edge_attr, nullptr, nullptr, W_ee, b_ee, eab, E, 59, 128);
  // 2. ew
  k_ew<<<cdiv(E, 4), 256, 0, stream>>>(eab, memb, srcI, W_ewg, b_ewg, ew, E);
  // 3. te + fused attention mats
  k_te<<<1, 128, 0, stream>>>(delta_t, W_t, b_t, te);
  k_prep<<<256, 256, 0, stream>>>(Wo_l, Wv_l, bv_l, bo_l, Wq_l, bq_l, Wk_l, Wl2, blv, Wqk, bqk);
  // 4. GIN layer 1 (h == broadcast memory)
  k_agg<1><<<cdiv(N, 2), 256, 0, stream>>>(memb, eab, ew, dstI, ofs, eid, aggb, N);
  k_gin<1><<<cdiv(N * 8, 128), 256, 0, stream>>>(
      memb, aggb, memory, h1f, h1b, gin_W1, gin_b1, gin_W2, gin_b2, N * 8);
  // 5. GIN layer 2 -> h (d_out) + h2b
  k_agg<2><<<cdiv(N, 2), 256, 0, stream>>>(h1b, eab, ew, dstI, ofs, eid, aggb, N);
  k_gin<2><<<cdiv(N * 8, 128), 256, 0, stream>>>(
      h1b, aggb, h1f, h, h2b, gin_W1 + 16384, gin_b1 + 128, gin_W2 + 16384, gin_b2 + 128, N * 8);
  // 6. GRU
  gemm_bf<0, 0, false, false, false><<<dim3(cdiv(N, 128), 3), 256, 0, stream>>>(
      memory, nullptr, nullptr, W_hh, b_hh, gh, N, 128, 384);
  gemm_bf<2, 0, false, true, true><<<dim3(cdiv(N * 8, 128), 3), 256, 0, stream>>>(
      h2b, te, nullptr, W_ih, b_ih, gi, N * 8, 128, 384);
  k_gru<<<cdiv(N * 1024, 256), 256, 0, stream>>>(gi, gh, memory, hnb, N * 1024);
  // 7. pooled + global K/G
  hipMemsetAsync(prw, 0, 1024 * sizeof(float), stream);
  k_pool<<<256, 256, 0, stream>>>(hnb, prw, N);
  k_kgg<<<1, 256, 0, stream>>>(prw, Wk_g, Wv_g, bv_g, Wo_g, Kg, G, N);
  // 8. local attention
  gemm_bf<0, 0, false, true, true><<<dim3(cdiv(E, 128), 2), 256, 0, stream>>>(
      eab, nullptr, nullptr, Wqk, bqk, qk12b, E, 128, 256);
  k_local<<<E, 256, 0, stream>>>(hnb, qk12b, srcI, dstI, wsd, E);
  gemm_bf<0, 0, false, true, true><<<dim3(cdiv(E, 128), 1), 256, 0, stream>>>(
      wsd, nullptr, nullptr, Wl2, blv, lclb, E, 256, 128);
  // 9. global attention
  gemm_bf<0, 0, false, true, true><<<dim3(cdiv(E, 128), 1), 256, 0, stream>>>(
      eab, nullptr, nullptr, Wq_g, bq_g, qgb, E, 128, 128);
  k_global<<<cdiv(E, 4), 256, 0, stream>>>(qgb, Kg, G, bo_g, ag_out, glbb, E);
  // 10. classifier
  gemm_bf<3, 1, false, true, true><<<dim3(cdiv(E, 128), 1), 256, 0, stream>>>(
      eab, lclb, glbb, Wc1, bc1, hid, E, 384, 128);
  k_logits<<<cdiv(E, 4), 256, 0, stream>>>(hid, Wc2, bc2, logits, E);
}

// Round 5
// 585.542 us; speedup vs baseline: 3.4398x; 1.1615x over previous
//
#include <hip/hip_runtime.h>
#include <cstddef>

// MVMGIN round 5:
//  - k_gin: LDS 64->48KB (Tsh unioned over Ash/Bsh, W2 staged in 2 chunks),
//    bf16 weights, residual base from bf16 h1b (h1f dropped).
//  - k_giru: gi GEMM + GRU fused (gi 123MB round-trip + k_gru deleted).
//  - q-projections fused: one Nout=384 GEMM over [Wqk|Wq_g] bf16.
// Algebra (earlier rounds): q_l folded into qk; local V/O folded into Wl2/blv;
// bk_l/bk_g dropped (cancel in softmax); scatter-add -> CSR gather.
// Outputs (f32, concat): logits(E,5) | ew(E,8) | h_before(N,8,128) | a_g(E,8)

#define HSZ 128
typedef unsigned short ushortT;
typedef short short8 __attribute__((ext_vector_type(8)));
typedef float f32x4 __attribute__((ext_vector_type(4)));

__device__ __forceinline__ float sigm(float x) { return 1.f / (1.f + __expf(-x)); }

__device__ __forceinline__ ushortT f2bf(float f) {
  unsigned int u = __float_as_uint(f);
  u += 0x7fffu + ((u >> 16) & 1u);
  return (ushortT)(u >> 16);
}
__device__ __forceinline__ float bf2f(ushortT u) {
  return __uint_as_float(((unsigned int)u) << 16);
}

// XOR-swizzled LDS chunk index (in shorts): row stride 64 shorts.
__device__ __forceinline__ int swzA(int row, int chunk) {
  return row * 64 + (((chunk ^ row) & 7) << 3);
}
// 128-short-wide tile (16 chunks): keep bit3, XOR low 3 bits.
__device__ __forceinline__ int swzT(int row, int chunk) {
  return row * 128 + (((chunk & 8) | ((chunk ^ row) & 7)) << 3);
}

// ---------------- bf16 MFMA GEMM ----------------
// out(M,Nout) = ACT( Asrc(M,K) @ W^T + bias );  W row-major (Nout,K).
// ASRC: 0=A1, 3=concat{A1,A2,A3} width 128 each. ABF: A bf16 (K%64==0).
// WBF: W bf16. OUTBF: bf16 out.
template<int ASRC, int ACT, bool OUTBF, bool ABF, bool WBF>
__global__ __launch_bounds__(256) void gemm_bf(
    const void* __restrict__ A1, const void* __restrict__ A2, const void* __restrict__ A3,
    const void* __restrict__ W, const float* __restrict__ bias,
    void* __restrict__ out_, int M, int K, int Nout)
{
  __shared__ short Ash[128 * 64];
  __shared__ short Bsh[128 * 64];
  float* out = (float*)out_;
  ushortT* outh = (ushortT*)out_;
  const int tid = threadIdx.x;
  const int m0 = blockIdx.x * 128;
  const int n0 = blockIdx.y * 128;
  const int l = tid & 63, w = tid >> 6;
  const int wr = w >> 1, wc = w & 1;
  const int lr = l & 15, lq = l >> 4;
  f32x4 acc[4][4] = {};

  for (int k0 = 0; k0 < K; k0 += 64) {
    __syncthreads();
    const bool fast = (k0 + 64 <= K);
    #pragma unroll
    for (int i = 0; i < 4; ++i) {
      int c = i * 256 + tid;
      int row = c >> 3, seg = c & 7;
      int kb = k0 + seg * 8;
      // ---- stage A ----
      {
        int m = m0 + row;
        short8 pk;
        if (ABF) {
          if (m < M) {
            if (ASRC == 3) {
              const ushortT* S = (kb < 128) ? (const ushortT*)A1
                               : (kb < 256) ? (const ushortT*)A2 : (const ushortT*)A3;
              pk = *reinterpret_cast<const short8*>(S + (size_t)m * 128 + (kb & 127));
            } else {
              pk = *reinterpret_cast<const short8*>((const ushortT*)A1 + (size_t)m * K + kb);
            }
          } else {
            #pragma unroll
            for (int j = 0; j < 8; ++j) pk[j] = 0;
          }
        } else {
          const float* A1f = (const float*)A1;
          float v[8];
          if (fast && m < M) {
            const float4* p = reinterpret_cast<const float4*>(A1f + (size_t)m * K + kb);
            float4 x0 = p[0], x1 = p[1];
            v[0]=x0.x; v[1]=x0.y; v[2]=x0.z; v[3]=x0.w;
            v[4]=x1.x; v[5]=x1.y; v[6]=x1.z; v[7]=x1.w;
          } else {
            #pragma unroll
            for (int j = 0; j < 8; ++j) {
              int k = kb + j;
              v[j] = (m < M && k < K) ? A1f[(size_t)m * K + k] : 0.f;
            }
          }
          #pragma unroll
          for (int j = 0; j < 8; ++j) pk[j] = (short)f2bf(v[j]);
        }
        *reinterpret_cast<short8*>(&Ash[swzA(row, seg)]) = pk;
      }
      // ---- stage B ----
      {
        int nn = n0 + row;
        short8 pk;
        if (WBF) {
          if (nn < Nout)
            pk = *reinterpret_cast<const short8*>((const ushortT*)W + (size_t)nn * K + kb);
          else {
            #pragma unroll
            for (int j = 0; j < 8; ++j) pk[j] = 0;
          }
        } else {
          const float* Wf = (const float*)W;
          float v[8];
          if (fast && nn < Nout) {
            const float4* p = reinterpret_cast<const float4*>(Wf + (size_t)nn * K + kb);
            float4 x0 = p[0], x1 = p[1];
            v[0]=x0.x; v[1]=x0.y; v[2]=x0.z; v[3]=x0.w;
            v[4]=x1.x; v[5]=x1.y; v[6]=x1.z; v[7]=x1.w;
          } else {
            #pragma unroll
            for (int j = 0; j < 8; ++j) {
              int k = kb + j;
              v[j] = (nn < Nout && k < K) ? Wf[(size_t)nn * K + k] : 0.f;
            }
          }
          #pragma unroll
          for (int j = 0; j < 8; ++j) pk[j] = (short)f2bf(v[j]);
        }
        *reinterpret_cast<short8*>(&Bsh[swzA(row, seg)]) = pk;
      }
    }
    __syncthreads();
    #pragma unroll
    for (int ks = 0; ks < 2; ++ks) {
      short8 a[4], b[4];
      #pragma unroll
      for (int mi = 0; mi < 4; ++mi)
        a[mi] = *reinterpret_cast<const short8*>(&Ash[swzA(wr*64 + mi*16 + lr, ks*4 + lq)]);
      #pragma unroll
      for (int ni = 0; ni < 4; ++ni)
        b[ni] = *reinterpret_cast<const short8*>(&Bsh[swzA(wc*64 + ni*16 + lr, ks*4 + lq)]);
      #pragma unroll
      for (int mi = 0; mi < 4; ++mi)
        #pragma unroll
        for (int ni = 0; ni < 4; ++ni)
          acc[mi][ni] = __builtin_amdgcn_mfma_f32_16x16x32_bf16(a[mi], b[ni], acc[mi][ni], 0, 0, 0);
    }
  }
  #pragma unroll
  for (int ni = 0; ni < 4; ++ni) {
    int col = n0 + wc*64 + ni*16 + lr;
    if (col >= Nout) continue;
    float bz = bias ? bias[col] : 0.f;
    #pragma unroll
    for (int mi = 0; mi < 4; ++mi) {
      int mb = m0 + wr*64 + mi*16 + lq*4;
      #pragma unroll
      for (int r = 0; r < 4; ++r) {
        int m = mb + r;
        if (m >= M) continue;
        float vv = acc[mi][ni][r] + bz;
        if (ACT == 1) vv = fmaxf(vv, 0.f);
        size_t o = (size_t)m * Nout + col;
        if (OUTBF) outh[o] = f2bf(vv); else out[o] = vv;
      }
    }
  }
}

// ---------------- fused GIN layer (48KB LDS) ----------------
// LMODE 1: A = memb(bcast) + aggb; base = memory f32; out -> houtb (bf16)
// LMODE 2: A = h1b + aggb;         base = bf2f(h1b);  out -> houtf (f32)
template<int LMODE>
__global__ __launch_bounds__(256) void k_gin(
    const ushortT* __restrict__ hb, const ushortT* __restrict__ aggb,
    const float* __restrict__ memf,
    float* __restrict__ houtf, ushortT* __restrict__ houtb,
    const ushortT* __restrict__ W1b, const float* __restrict__ b1,
    const ushortT* __restrict__ W2b, const float* __restrict__ b2, int M)
{
  __shared__ short smem[24576];            // 48 KB
  short* Ash  = smem;                      // [0, 8192)
  short* Bsh  = smem + 8192;               // [8192, 16384)
  short* Tsh  = smem;                      // [0, 16384) overlaps Ash+Bsh
  short* B2sh = smem + 16384;              // [16384, 24576)
  const int tid = threadIdx.x;
  const int m0 = blockIdx.x * 128;
  const int l = tid & 63, w = tid >> 6;
  const int wr = w >> 1, wc = w & 1;
  const int lr = l & 15, lq = l >> 4;
  f32x4 acc[4][4] = {};

  // ---- phase 1: t = (h+agg) @ W1^T ----
  for (int ks2 = 0; ks2 < 2; ++ks2) {
    if (ks2) __syncthreads();
    #pragma unroll
    for (int i = 0; i < 4; ++i) {
      int c = i * 256 + tid;
      int row = c >> 3, seg = c & 7;
      int kb = ks2 * 64 + seg * 8;
      {
        int m = m0 + row;
        short8 pk;
        if (m < M) {
          short8 hv;
          if (LMODE == 1) hv = *reinterpret_cast<const short8*>(hb + ((size_t)(m >> 3)) * 128 + kb);
          else            hv = *reinterpret_cast<const short8*>(hb + (size_t)m * 128 + kb);
          short8 av = *reinterpret_cast<const short8*>(aggb + (size_t)m * 128 + kb);
          #pragma unroll
          for (int j = 0; j < 8; ++j)
            pk[j] = (short)f2bf(bf2f((ushortT)hv[j]) + bf2f((ushortT)av[j]));
        } else {
          #pragma unroll
          for (int j = 0; j < 8; ++j) pk[j] = 0;
        }
        *reinterpret_cast<short8*>(&Ash[swzA(row, seg)]) = pk;
      }
      *reinterpret_cast<short8*>(&Bsh[swzA(row, seg)]) =
          *reinterpret_cast<const short8*>(W1b + (size_t)row * 128 + kb);
      if (ks2 == 0)   // prefetch W2 chunk 0 during first staging
        *reinterpret_cast<short8*>(&B2sh[swzA(row, seg)]) =
            *reinterpret_cast<const short8*>(W2b + (size_t)row * 128 + seg * 8);
    }
    __syncthreads();
    #pragma unroll
    for (int ks = 0; ks < 2; ++ks) {
      short8 a[4], b[4];
      #pragma unroll
      for (int mi = 0; mi < 4; ++mi)
        a[mi] = *reinterpret_cast<const short8*>(&Ash[swzA(wr*64 + mi*16 + lr, ks*4 + lq)]);
      #pragma unroll
      for (int ni = 0; ni < 4; ++ni)
        b[ni] = *reinterpret_cast<const short8*>(&Bsh[swzA(wc*64 + ni*16 + lr, ks*4 + lq)]);
      #pragma unroll
      for (int mi = 0; mi < 4; ++mi)
        #pragma unroll
        for (int ni = 0; ni < 4; ++ni)
          acc[mi][ni] = __builtin_amdgcn_mfma_f32_16x16x32_bf16(a[mi], b[ni], acc[mi][ni], 0, 0, 0);
    }
  }
  __syncthreads();     // all waves done reading Ash/Bsh
  // ---- t = relu(acc + b1) -> Tsh ----
  {
    float b1v[4];
    #pragma unroll
    for (int ni = 0; ni < 4; ++ni) b1v[ni] = b1[wc*64 + ni*16 + lr];
    #pragma unroll
    for (int mi = 0; mi < 4; ++mi)
      #pragma unroll
      for (int ni = 0; ni < 4; ++ni) {
        int col = wc*64 + ni*16 + lr;
        #pragma unroll
        for (int r = 0; r < 4; ++r) {
          int row = wr*64 + mi*16 + lq*4 + r;
          float v = fmaxf(acc[mi][ni][r] + b1v[ni], 0.f);
          Tsh[swzT(row, col >> 3) + (col & 7)] = (short)f2bf(v);
        }
      }
  }
  __syncthreads();     // Tsh ready (B2sh chunk 0 already staged)
  // ---- phase 2: upd = t @ W2^T ----
  f32x4 acc2[4][4] = {};
  for (int ks2 = 0; ks2 < 2; ++ks2) {
    if (ks2) {
      __syncthreads();
      #pragma unroll
      for (int i = 0; i < 4; ++i) {
        int c = i * 256 + tid;
        int row = c >> 3, seg = c & 7;
        *reinterpret_cast<short8*>(&B2sh[swzA(row, seg)]) =
            *reinterpret_cast<const short8*>(W2b + (size_t)row * 128 + 64 + seg * 8);
      }
      __syncthreads();
    }
    #pragma unroll
    for (int ks = 0; ks < 2; ++ks) {
      short8 a[4], b[4];
      #pragma unroll
      for (int mi = 0; mi < 4; ++mi)
        a[mi] = *reinterpret_cast<const short8*>(&Tsh[swzT(wr*64 + mi*16 + lr, ks2*8 + ks*4 + lq)]);
      #pragma unroll
      for (int ni = 0; ni < 4; ++ni)
        b[ni] = *reinterpret_cast<const short8*>(&B2sh[swzA(wc*64 + ni*16 + lr, ks*4 + lq)]);
      #pragma unroll
      for (int mi = 0; mi < 4; ++mi)
        #pragma unroll
        for (int ni = 0; ni < 4; ++ni)
          acc2[mi][ni] = __builtin_amdgcn_mfma_f32_16x16x32_bf16(a[mi], b[ni], acc2[mi][ni], 0, 0, 0);
    }
  }
  // ---- epilogue: out = base + upd + b2 ----
  {
    float b2v[4];
    #pragma unroll
    for (int ni = 0; ni < 4; ++ni) b2v[ni] = b2[wc*64 + ni*16 + lr];
    #pragma unroll
    for (int ni = 0; ni < 4; ++ni) {
      int col = wc*64 + ni*16 + lr;
      #pragma unroll
      for (int mi = 0; mi < 4; ++mi) {
        int mb = m0 + wr*64 + mi*16 + lq*4;
        #pragma unroll
        for (int r = 0; r < 4; ++r) {
          int m = mb + r;
          if (m >= M) continue;
          float base = (LMODE == 1) ? memf[((size_t)(m >> 3)) * 128 + col]
                                    : bf2f(hb[(size_t)m * 128 + col]);
          float ho = base + acc2[mi][ni][r] + b2v[ni];
          if (LMODE == 1) houtb[(size_t)m * 128 + col] = f2bf(ho);
          else            houtf[(size_t)m * 128 + col] = ho;
        }
      }
    }
  }
}

// ---------------- fused gi GEMM + GRU ----------------
// M=N*8. Per block: 64 rows, 8 waves; wave w: rows (w>>1)*16, col-triple (w&1)*64.
// gi = (h + te) @ W_ih^T (+b_ih in epilogue); then GRU -> hnb bf16.
__global__ __launch_bounds__(512) void k_giru(
    const float* __restrict__ hf, const float* __restrict__ te,
    const ushortT* __restrict__ Wihb, const float* __restrict__ b_ih,
    const float* __restrict__ gh, const float* __restrict__ memory,
    ushortT* __restrict__ hnb, int M)
{
  __shared__ short Ash[8192];     // 64 x 128 (swzT)
  __shared__ short Bsh[24576];    // 384 x 64 (swzA)
  const int tid = threadIdx.x;
  const int m0 = blockIdx.x * 64;
  const int l = tid & 63, w = tid >> 6;
  const int lr = l & 15, lq = l >> 4;
  const int r0 = (w >> 1) * 16, c0 = (w & 1) * 64;
  f32x4 acc[3][4] = {};

  // stage A (full K=128): h + te, cvt bf16
  #pragma unroll
  for (int i = 0; i < 2; ++i) {
    int c = i * 512 + tid;
    int row = c >> 4, seg = c & 15;
    int m = m0 + row;
    short8 pk;
    if (m < M) {
      const float4* p = reinterpret_cast<const float4*>(hf + (size_t)m * 128 + seg * 8);
      const float4* t = reinterpret_cast<const float4*>(te + seg * 8);
      float4 x0 = p[0], x1 = p[1], t0 = t[0], t1 = t[1];
      pk[0]=(short)f2bf(x0.x+t0.x); pk[1]=(short)f2bf(x0.y+t0.y);
      pk[2]=(short)f2bf(x0.z+t0.z); pk[3]=(short)f2bf(x0.w+t0.w);
      pk[4]=(short)f2bf(x1.x+t1.x); pk[5]=(short)f2bf(x1.y+t1.y);
      pk[6]=(short)f2bf(x1.z+t1.z); pk[7]=(short)f2bf(x1.w+t1.w);
    } else {
      #pragma unroll
      for (int j = 0; j < 8; ++j) pk[j] = 0;
    }
    *reinterpret_cast<short8*>(&Ash[swzT(row, seg)]) = pk;
  }
  for (int ks2 = 0; ks2 < 2; ++ks2) {
    if (ks2) __syncthreads();
    #pragma unroll
    for (int i = 0; i < 6; ++i) {           // 3072 chunks / 512 threads
      int c = i * 512 + tid;
      int row = c >> 3, seg = c & 7;        // row = W col 0..383
      *reinterpret_cast<short8*>(&Bsh[swzA(row, seg)]) =
          *reinterpret_cast<const short8*>(Wihb + (size_t)row * 128 + ks2 * 64 + seg * 8);
    }
    __syncthreads();
    #pragma unroll
    for (int ks = 0; ks < 2; ++ks) {
      short8 a = *reinterpret_cast<const short8*>(&Ash[swzT(r0 + lr, ks2*8 + ks*4 + lq)]);
      #pragma unroll
      for (int s = 0; s < 3; ++s)
        #pragma unroll
        for (int xi = 0; xi < 4; ++xi) {
          short8 b = *reinterpret_cast<const short8*>(
              &Bsh[swzA(s*128 + c0 + xi*16 + lr, ks*4 + lq)]);
          acc[s][xi] = __builtin_amdgcn_mfma_f32_16x16x32_bf16(a, b, acc[s][xi], 0, 0, 0);
        }
    }
  }
  // GRU epilogue (per-lane: r,z,n of same (row, x))
  #pragma unroll
  for (int xi = 0; xi < 4; ++xi) {
    int x = c0 + xi * 16 + lr;
    float br = b_ih[x], bz = b_ih[128 + x], bn = b_ih[256 + x];
    #pragma unroll
    for (int rr = 0; rr < 4; ++rr) {
      int m = m0 + r0 + lq * 4 + rr;
      if (m >= M) continue;
      int node = m >> 3;
      float ghr = gh[(size_t)node * 384 + x];
      float ghz = gh[(size_t)node * 384 + 128 + x];
      float ghn = gh[(size_t)node * 384 + 256 + x];
      float mem = memory[(size_t)node * 128 + x];
      float rv = sigm(acc[0][xi][rr] + br + ghr);
      float zv = sigm(acc[1][xi][rr] + bz + ghz);
      float nv = tanhf(acc[2][xi][rr] + bn + rv * ghn);
      hnb[(size_t)m * 128 + x] = f2bf((1.f - zv) * nv + zv * mem);
    }
  }
}

// ---------------- CSR build ----------------
__global__ void k_hist(const int* __restrict__ srcI, int* __restrict__ cnt, int E)
{
  int e = blockIdx.x * 256 + threadIdx.x;
  if (e < E) atomicAdd(&cnt[srcI[e]], 1);
}

__global__ __launch_bounds__(1024) void k_scan(const int* __restrict__ cnt,
    int* __restrict__ ofs, int* __restrict__ cur, int N)
{
  __shared__ int buf[1024];
  __shared__ int carry;
  int tid = threadIdx.x;
  if (tid == 0) carry = 0;
  __syncthreads();
  for (int base = 0; base < N; base += 1024) {
    int i = base + tid;
    int v = (i < N) ? cnt[i] : 0;
    buf[tid] = v;
    __syncthreads();
    for (int off = 1; off < 1024; off <<= 1) {
      int t = (tid >= off) ? buf[tid - off] : 0;
      __syncthreads();
      buf[tid] += t;
      __syncthreads();
    }
    int excl = carry + buf[tid] - v;
    if (i < N) { ofs[i] = excl; cur[i] = excl; }
    __syncthreads();
    if (tid == 0) carry += buf[1023];
    __syncthreads();
  }
  if (tid == 0) ofs[N] = carry;
}

__global__ void k_fill(const int* __restrict__ srcI, int* __restrict__ cur,
                       int* __restrict__ eid, int E)
{
  int e = blockIdx.x * 256 + threadIdx.x;
  if (e >= E) return;
  int p = atomicAdd(&cur[srcI[e]], 1);
  eid[p] = e;
}

// ---------------- GIN aggregation (CSR gather, bf16) ----------------
template<int LMODE>
__global__ __launch_bounds__(256) void k_agg(const ushortT* __restrict__ hb,
    const ushortT* __restrict__ eab, const float* __restrict__ ew,
    const int* __restrict__ dstI, const int* __restrict__ ofs,
    const int* __restrict__ eid, ushortT* __restrict__ aggb, int N)
{
  int half = threadIdx.x >> 7;
  int x = threadIdx.x & 127;
  int n = blockIdx.x * 2 + half;
  if (n >= N) return;
  float acc[8] = {};
  int beg = ofs[n], end = ofs[n + 1];
  for (int i = beg; i < end; ++i) {
    int e = eid[i];
    int d = dstI[e];
    float eav = bf2f(eab[(size_t)e * 128 + x]);
    const float* ewp = ew + (size_t)e * 8;
    if (LMODE == 1) {
      float m = fmaxf(bf2f(hb[(size_t)d * 128 + x]) + eav, 0.f);
      #pragma unroll
      for (int v = 0; v < 8; ++v) acc[v] += m * ewp[v];
    } else {
      const ushortT* hd = hb + (size_t)d * 1024;
      #pragma unroll
      for (int v = 0; v < 8; ++v)
        acc[v] += fmaxf(bf2f(hd[v * 128 + x]) + eav, 0.f) * ewp[v];
    }
  }
  ushortT* ag = aggb + (size_t)n * 1024;
  #pragma unroll
  for (int v = 0; v < 8; ++v) ag[v * 128 + x] = f2bf(acc[v]);
}

// ---------------- edge gate ----------------
__global__ __launch_bounds__(256) void k_ew(const ushortT* __restrict__ eab,
    const ushortT* __restrict__ memb, const int* __restrict__ srcI,
    const float* __restrict__ W_ewg, const float* __restrict__ b_ewg,
    float* __restrict__ ew, int E)
{
  __shared__ float Wsh[2048];
  __shared__ float bsh[8];
  int tid = threadIdx.x;
  for (int i = tid; i < 2048; i += 256) Wsh[i] = W_ewg[i];
  if (tid < 8) bsh[tid] = b_ewg[tid];
  __syncthreads();
  int wv = tid >> 6, lane = tid & 63;
  int e = blockIdx.x * 4 + wv;
  if (e >= E) return;
  int s = srcI[e];
  float c0 = bf2f(eab[(size_t)e * 128 + lane]);
  float c1 = bf2f(eab[(size_t)e * 128 + 64 + lane]);
  float c2 = bf2f(memb[(size_t)s * 128 + lane]);
  float c3 = bf2f(memb[(size_t)s * 128 + 64 + lane]);
  #pragma unroll
  for (int v = 0; v < 8; ++v) {
    float p = c0 * Wsh[v * 256 + lane] + c1 * Wsh[v * 256 + 64 + lane]
            + c2 * Wsh[v * 256 + 128 + lane] + c3 * Wsh[v * 256 + 192 + lane];
    #pragma unroll
    for (int o = 32; o; o >>= 1) p += __shfl_down(p, o);
    if (lane == 0) ew[(size_t)e * 8 + v] = sigm(p + bsh[v]);
  }
}

// ---------------- f32 -> bf16 copy ----------------
__global__ void k_cvt(const float* __restrict__ src, ushortT* __restrict__ dst, int total)
{
  int i = blockIdx.x * 256 + threadIdx.x;
  if (i < total) dst[i] = f2bf(src[i]);
}

// ---------------- te ----------------
__global__ void k_te(const float* __restrict__ delta_t, const float* __restrict__ W_t,
                     const float* __restrict__ b_t, float* __restrict__ te)
{
  int t = threadIdx.x;
  if (t < 128) te[t] = sinf(delta_t[0] * W_t[t] + b_t[t]);
}

// ---------------- pooled partial sums ----------------
__global__ __launch_bounds__(256) void k_pool(const ushortT* __restrict__ hnb,
                                              float* __restrict__ prw, int N)
{
  int tid = threadIdx.x;
  float acc[4] = {0.f, 0.f, 0.f, 0.f};
  for (int n = blockIdx.x; n < N; n += gridDim.x) {
    const ushortT* row = hnb + (size_t)n * 1024;
    #pragma unroll
    for (int j = 0; j < 4; ++j) acc[j] += bf2f(row[tid + j * 256]);
  }
  #pragma unroll
  for (int j = 0; j < 4; ++j) atomicAdd(&prw[tid + j * 256], acc[j]);
}

// ---------------- fused small mats (bf16 out) ----------------
// Wl2b(128,256) = Wo_l@Wv_l; blv = bo_l + Wo_l@bv_l
// Wqkgb(384,128): rows 0..255 = (Wq_l^T Wk_l)^T, rows 256..383 = Wq_g
// bqkg(384): [bq_l@Wk_l | bq_g]
__global__ __launch_bounds__(256) void k_prep(
    const float* __restrict__ Wo_l, const float* __restrict__ Wv_l,
    const float* __restrict__ bv_l, const float* __restrict__ bo_l,
    const float* __restrict__ Wq_l, const float* __restrict__ bq_l,
    const float* __restrict__ Wk_l, const float* __restrict__ Wq_g,
    const float* __restrict__ bq_g,
    ushortT* __restrict__ Wl2b, float* __restrict__ blv,
    ushortT* __restrict__ Wqkgb, float* __restrict__ bqkg)
{
  int idx = blockIdx.x * 256 + threadIdx.x;    // 81920 total
  if (idx < 32768) {
    int n = idx >> 8, k = idx & 255;
    float a = 0.f;
    for (int j = 0; j < 128; ++j) a += Wo_l[n * 128 + j] * Wv_l[j * 256 + k];
    Wl2b[idx] = f2bf(a);
  } else if (idx < 65536) {
    int rem = idx - 32768;
    int n = rem >> 7, j = rem & 127;
    float a = 0.f;
    for (int k = 0; k < 128; ++k) a += Wq_l[k * 128 + j] * Wk_l[k * 256 + n];
    Wqkgb[rem] = f2bf(a);
  } else {
    int rem = idx - 65536;                     // 16384: copy Wq_g
    Wqkgb[32768 + rem] = f2bf(Wq_g[rem]);
  }
  if (blockIdx.x == 0 && threadIdx.x < 128) {
    int n = threadIdx.x;
    float a = bo_l[n];
    for (int j = 0; j < 128; ++j) a += Wo_l[n * 128 + j] * bv_l[j];
    blv[n] = a;
  }
  if (blockIdx.x == 1) {
    int n = threadIdx.x;
    float a = 0.f;
    for (int k = 0; k < 128; ++k) a += bq_l[k] * Wk_l[k * 256 + n];
    bqkg[n] = a;
  }
  if (blockIdx.x == 2 && threadIdx.x < 128) bqkg[256 + threadIdx.x] = bq_g[threadIdx.x];
}

// ---------------- Kg / G for global attention ----------------
__global__ __launch_bounds__(256) void k_kgg(const float* __restrict__ prw,
    const float* __restrict__ Wk_g, const float* __restrict__ Wv_g, const float* __restrict__ bv_g,
    const float* __restrict__ Wo_g, float* __restrict__ Kg, float* __restrict__ G, int N)
{
  __shared__ float pl[1024];
  __shared__ float vg[1024];
  int tid = threadIdx.x;
  float invN = 1.f / (float)N;
  for (int i = tid; i < 1024; i += 256) pl[i] = prw[i] * invN;
  __syncthreads();
  for (int o = tid; o < 1024; o += 256) {
    int v = o >> 7, x = o & 127;
    float a = 0.f, b = 0.f;
    for (int k = 0; k < 128; ++k) {
      float p = pl[v * 128 + k];
      a += p * Wk_g[(size_t)x * 128 + k];
      b += p * Wv_g[(size_t)x * 128 + k];
    }
    Kg[o] = a;
    vg[o] = b + bv_g[x];
  }
  __syncthreads();
  for (int o = tid; o < 1024; o += 256) {
    int v = o >> 7, x = o & 127;
    float a = 0.f;
    for (int k = 0; k < 128; ++k) a += vg[v * 128 + k] * Wo_g[(size_t)x * 128 + k];
    G[o] = a;
  }
}

// ---------------- fused local attention (qkg stride 384) ----------------
__global__ __launch_bounds__(256) void k_local(const ushortT* __restrict__ hnb,
    const ushortT* __restrict__ qkgb,
    const int* __restrict__ srcI, const int* __restrict__ dstI,
    ushortT* __restrict__ wsd, int E)
{
  __shared__ float sf[1024], df[1024], q12[256], sc[8];
  int e = blockIdx.x;
  int tid = threadIdx.x;
  int s = srcI[e], d = dstI[e];
  {
    int c = tid & 127;
    const ushortT* srcp = (tid < 128) ? hnb + (size_t)s * 1024 : hnb + (size_t)d * 1024;
    short8 v = *reinterpret_cast<const short8*>(srcp + c * 8);
    float* dl = (tid < 128) ? sf : df;
    #pragma unroll
    for (int j = 0; j < 8; ++j) dl[c * 8 + j] = bf2f((ushortT)v[j]);
  }
  if (tid < 32) {
    short8 v = *reinterpret_cast<const short8*>(qkgb + (size_t)e * 384 + tid * 8);
    #pragma unroll
    for (int j = 0; j < 8; ++j) q12[tid * 8 + j] = bf2f((ushortT)v[j]);
  }
  __syncthreads();
  int wv = tid >> 6, lane = tid & 63;
  for (int v = wv; v < 8; v += 4) {
    float p = q12[lane] * sf[v * 128 + lane] + q12[64 + lane] * sf[v * 128 + 64 + lane]
            + q12[128 + lane] * df[v * 128 + lane] + q12[192 + lane] * df[v * 128 + 64 + lane];
    #pragma unroll
    for (int o = 32; o; o >>= 1) p += __shfl_down(p, o);
    if (lane == 0) sc[v] = p * 0.08838834764831845f;   // 1/sqrt(128)
  }
  __syncthreads();
  float mx = sc[0];
  #pragma unroll
  for (int v = 1; v < 8; ++v) mx = fmaxf(mx, sc[v]);
  float a[8], sum = 0.f;
  #pragma unroll
  for (int v = 0; v < 8; ++v) { a[v] = __expf(sc[v] - mx); sum += a[v]; }
  float inv = 1.f / sum;
  int x = tid & 127;
  const float* mat = (tid < 128) ? sf : df;
  float accv = 0.f;
  #pragma unroll
  for (int v = 0; v < 8; ++v) accv += a[v] * mat[v * 128 + x];
  wsd[(size_t)e * 256 + (tid < 128 ? x : 128 + x)] = f2bf(accv * inv);
}

// ---------------- global attention (qg = qkgb[:,256:384]) ----------------
__global__ __launch_bounds__(256) void k_global(const ushortT* __restrict__ qkgb,
    const float* __restrict__ Kg, const float* __restrict__ G, const float* __restrict__ bo_g,
    float* __restrict__ ag_out, ushortT* __restrict__ goutb, int E)
{
  __shared__ float Kgs[1024], Gs[1024], bs[128];
  int tid = threadIdx.x;
  for (int i = tid; i < 1024; i += 256) { Kgs[i] = Kg[i]; Gs[i] = G[i]; }
  if (tid < 128) bs[tid] = bo_g[tid];
  __syncthreads();
  int wv = tid >> 6, lane = tid & 63;
  int e = blockIdx.x * 4 + wv;
  if (e >= E) return;
  float qa = bf2f(qkgb[(size_t)e * 384 + 256 + lane]);
  float qb = bf2f(qkgb[(size_t)e * 384 + 320 + lane]);
  float s[8];
  #pragma unroll
  for (int v = 0; v < 8; ++v) {
    float p = qa * Kgs[v * 128 + lane] + qb * Kgs[v * 128 + 64 + lane];
    #pragma unroll
    for (int o = 32; o; o >>= 1) p += __shfl_xor(p, o);
    s[v] = p * 0.08838834764831845f;
  }
  float mx = s[0];
  #pragma unroll
  for (int v = 1; v < 8; ++v) mx = fmaxf(mx, s[v]);
  float sum = 0.f;
  #pragma unroll
  for (int v = 0; v < 8; ++v) { s[v] = __expf(s[v] - mx); sum += s[v]; }
  float inv = 1.f / sum;
  #pragma unroll
  for (int v = 0; v < 8; ++v) s[v] *= inv;
  #pragma unroll
  for (int v = 0; v < 8; ++v) if (lane == v) ag_out[(size_t)e * 8 + v] = s[v];
  float g0 = bs[lane], g1 = bs[64 + lane];
  #pragma unroll
  for (int v = 0; v < 8; ++v) {
    g0 += s[v] * Gs[v * 128 + lane];
    g1 += s[v] * Gs[v * 128 + 64 + lane];
  }
  goutb[(size_t)e * 128 + lane] = f2bf(g0);
  goutb[(size_t)e * 128 + 64 + lane] = f2bf(g1);
}

// ---------------- logits ----------------
__global__ __launch_bounds__(256) void k_logits(const ushortT* __restrict__ hid,
    const float* __restrict__ Wc2, const float* __restrict__ bc2,
    float* __restrict__ logits, int E)
{
  __shared__ float Wsh[640];
  __shared__ float bsh[5];
  int tid = threadIdx.x;
  for (int i = tid; i < 640; i += 256) Wsh[i] = Wc2[i];
  if (tid < 5) bsh[tid] = bc2[tid];
  __syncthreads();
  int wv = tid >> 6, lane = tid & 63;
  int e = blockIdx.x * 4 + wv;
  if (e >= E) return;
  float h0 = bf2f(hid[(size_t)e * 128 + lane]), h1 = bf2f(hid[(size_t)e * 128 + 64 + lane]);
  #pragma unroll
  for (int c = 0; c < 5; ++c) {
    float p = h0 * Wsh[c * 128 + lane] + h1 * Wsh[c * 128 + 64 + lane];
    #pragma unroll
    for (int o = 32; o; o >>= 1) p += __shfl_down(p, o);
    if (lane == 0) logits[(size_t)e * 5 + c] = p + bsh[c];
  }
}

extern "C" void kernel_launch(void* const* d_in, const int* in_sizes, int n_in,
                              void* d_out, int out_size, void* d_ws, size_t ws_size,
                              hipStream_t stream)
{
  const int*   edge_index = (const int*)d_in[0];
  const float* edge_attr  = (const float*)d_in[1];
  const float* delta_t    = (const float*)d_in[2];
  const float* memory     = (const float*)d_in[3];
  const float* W_ee  = (const float*)d_in[4];
  const float* b_ee  = (const float*)d_in[5];
  const float* W_ewg = (const float*)d_in[6];
  const float* b_ewg = (const float*)d_in[7];
  const float* gin_W1 = (const float*)d_in[8];
  const float* gin_b1 = (const float*)d_in[9];
  const float* gin_W2 = (const float*)d_in[10];
  const float* gin_b2 = (const float*)d_in[11];
  const float* W_t  = (const float*)d_in[12];
  const float* b_t  = (const float*)d_in[13];
  const float* W_ih = (const float*)d_in[14];
  const float* b_ih = (const float*)d_in[15];
  const float* W_hh = (const float*)d_in[16];
  const float* b_hh = (const float*)d_in[17];
  const float* Wq_l = (const float*)d_in[20];
  const float* bq_l = (const float*)d_in[21];
  const float* Wk_l = (const float*)d_in[22];
  const float* Wv_l = (const float*)d_in[24];
  const float* bv_l = (const float*)d_in[25];
  const float* Wo_l = (const float*)d_in[26];
  const float* bo_l = (const float*)d_in[27];
  const float* Wq_g = (const float*)d_in[28];
  const float* bq_g = (const float*)d_in[29];
  const float* Wk_g = (const float*)d_in[30];
  const float* Wv_g = (const float*)d_in[32];
  const float* bv_g = (const float*)d_in[33];
  const float* Wo_g = (const float*)d_in[34];
  const float* bo_g = (const float*)d_in[35];
  const float* Wc1  = (const float*)d_in[36];
  const float* bc1  = (const float*)d_in[37];
  const float* Wc2  = (const float*)d_in[38];
  const float* bc2  = (const float*)d_in[39];

  const int E = in_sizes[0] / 2;
  const int N = in_sizes[3] / HSZ;
  const int* srcI = edge_index;
  const int* dstI = edge_index + E;

  float* out    = (float*)d_out;
  float* logits = out;
  float* ew     = out + (size_t)E * 5;
  float* h      = out + (size_t)E * 13;                       // h_before (N,8,128) f32
  float* ag_out = out + (size_t)E * 13 + (size_t)N * 1024;

  // ---- workspace arena (units: f32 slots) ----
  float* ws = (float*)d_ws;
  size_t off = 0;
  auto alloc = [&](size_t n) { size_t o = off; off += (n + 255) & ~(size_t)255; return o; };
  float* te   = ws + alloc(128);
  float* blv  = ws + alloc(128);
  float* bqkg = ws + alloc(384);
  float* Kg   = ws + alloc(1024);
  float* G    = ws + alloc(1024);
  float* prw  = ws + alloc(1024);
  int* cnt = (int*)(ws + alloc(N));
  int* ofs = (int*)(ws + alloc(N + 1));
  int* cur = (int*)(ws + alloc(N));
  int* eid = (int*)(ws + alloc(E));
  ushortT* memb   = (ushortT*)(ws + alloc((size_t)N * 64));
  ushortT* eab    = (ushortT*)(ws + alloc((size_t)E * 64));
  ushortT* h1b    = (ushortT*)(ws + alloc((size_t)N * 512));
  ushortT* hnb    = (ushortT*)(ws + alloc((size_t)N * 512));
  float*   gh     = ws + alloc((size_t)N * 384);
  ushortT* ginW1b = (ushortT*)(ws + alloc(16384));   // 2 layers x 128x128 bf16
  ushortT* ginW2b = (ushortT*)(ws + alloc(16384));
  ushortT* Wihb   = (ushortT*)(ws + alloc(24576));   // 384x128 bf16
  ushortT* Wc1b   = (ushortT*)(ws + alloc(24576));   // 128x384 bf16
  ushortT* Wl2b   = (ushortT*)(ws + alloc(16384));   // 128x256 bf16
  ushortT* Wqkgb  = (ushortT*)(ws + alloc(24576));   // 384x128 bf16
  // BR union: aggb (N*512) | attn (E*448)
  size_t brA = (size_t)N * 512, brC = (size_t)E * 448;
  size_t brsz = brA > brC ? brA : brC;
  float* BR = ws + alloc(brsz);
  if (ws_size < off * sizeof(float)) return;   // needs ~160 MiB

  ushortT* aggb = (ushortT*)BR;
  ushortT* qkgb = (ushortT*)BR;                        // E x 384
  ushortT* wsd  = (ushortT*)(BR + (size_t)E * 192);    // E x 256
  ushortT* lclb = (ushortT*)(BR + (size_t)E * 320);    // E x 128
  ushortT* glbb = (ushortT*)(BR + (size_t)E * 384);    // E x 128
  ushortT* hid  = (ushortT*)BR;                        // E x 128 (over dead qkgb)

  auto cdiv = [](int a, int b) { return (a + b - 1) / b; };

  // 0. CSR + bf16 mirrors/weights
  hipMemsetAsync(cnt, 0, (size_t)N * sizeof(int), stream);
  k_hist<<<cdiv(E, 256), 256, 0, stream>>>(srcI, cnt, E);
  k_scan<<<1, 1024, 0, stream>>>(cnt, ofs, cur, N);
  k_fill<<<cdiv(E, 256), 256, 0, stream>>>(srcI, cur, eid, E);
  k_cvt<<<cdiv(N * 128, 256), 256, 0, stream>>>(memory, memb, N * 128);
  k_cvt<<<128, 256, 0, stream>>>(gin_W1, ginW1b, 32768);
  k_cvt<<<128, 256, 0, stream>>>(gin_W2, ginW2b, 32768);
  k_cvt<<<192, 256, 0, stream>>>(W_ih, Wihb, 49152);
  k_cvt<<<192, 256, 0, stream>>>(Wc1, Wc1b, 49152);
  // 1. ea = relu(edge_attr @ W_ee^T + b_ee) -> bf16
  gemm_bf<0, 1, true, false, false><<<dim3(cdiv(E, 128), 1), 256, 0, stream>>>(
      edge_attr, nullptr, nullptr, W_ee, b_ee, eab, E, 59, 128);
  // 2. ew + te + prep + gh
  k_ew<<<cdiv(E, 4), 256, 0, stream>>>(eab, memb, srcI, W_ewg, b_ewg, ew, E);
  k_te<<<1, 128, 0, stream>>>(delta_t, W_t, b_t, te);
  k_prep<<<320, 256, 0, stream>>>(Wo_l, Wv_l, bv_l, bo_l, Wq_l, bq_l, Wk_l, Wq_g, bq_g,
                                  Wl2b, blv, Wqkgb, bqkg);
  gemm_bf<0, 0, false, false, false><<<dim3(cdiv(N, 128), 3), 256, 0, stream>>>(
      memory, nullptr, nullptr, W_hh, b_hh, gh, N, 128, 384);
  // 3. GIN layer 1 (h == broadcast memory)
  k_agg<1><<<cdiv(N, 2), 256, 0, stream>>>(memb, eab, ew, dstI, ofs, eid, aggb, N);
  k_gin<1><<<cdiv(N * 8, 128), 256, 0, stream>>>(
      memb, aggb, memory, nullptr, h1b, ginW1b, gin_b1, ginW2b, gin_b2, N * 8);
  // 4. GIN layer 2 -> h (d_out f32)
  k_agg<2><<<cdiv(N, 2), 256, 0, stream>>>(h1b, eab, ew, dstI, ofs, eid, aggb, N);
  k_gin<2><<<cdiv(N * 8, 128), 256, 0, stream>>>(
      h1b, aggb, nullptr, h, nullptr, ginW1b + 16384, gin_b1 + 128,
      ginW2b + 16384, gin_b2 + 128, N * 8);
  // 5. fused gi GEMM + GRU -> hnb
  k_giru<<<cdiv(N * 8, 64), 512, 0, stream>>>(h, te, Wihb, b_ih, gh, memory, hnb, N * 8);
  // 6. pooled + global K/G
  hipMemsetAsync(prw, 0, 1024 * sizeof(float), stream);
  k_pool<<<256, 256, 0, stream>>>(hnb, prw, N);
  k_kgg<<<1, 256, 0, stream>>>(prw, Wk_g, Wv_g, bv_g, Wo_g, Kg, G, N);
  // 7. fused q projections (local qk1|qk2 + global q)
  gemm_bf<0, 0, true, true, true><<<dim3(cdiv(E, 128), 3), 256, 0, stream>>>(
      eab, nullptr, nullptr, Wqkgb, bqkg, qkgb, E, 128, 384);
  // 8. local attention
  k_local<<<E, 256, 0, stream>>>(hnb, qkgb, srcI, dstI, wsd, E);
  gemm_bf<0, 0, true, true, true><<<dim3(cdiv(E, 128), 1), 256, 0, stream>>>(
      wsd, nullptr, nullptr, Wl2b, blv, lclb, E, 256, 128);
  // 9. global attention
  k_global<<<cdiv(E, 4), 256, 0, stream>>>(qkgb, Kg, G, bo_g, ag_out, glbb, E);
  // 10. classifier
  gemm_bf<3, 1, true, true, true><<<dim3(cdiv(E, 128), 1), 256, 0, stream>>>(
      eab, lclb, glbb, Wc1b, bc1, hid, E, 384, 128);
  k_logits<<<cdiv(E, 4), 256, 0, stream>>>(hid, Wc2, bc2, logits, E);
}

// Round 6
// 542.780 us; speedup vs baseline: 3.7108x; 1.0788x over previous
//
#include <hip/hip_runtime.h>
#include <cstddef>

// MVMGIN round 6:
//  - k_lg: fused local+global attention, one wave per edge, register-resident
//    (no sf/df LDS, no bank conflicts, packed bf16 loads/stores). Replaces
//    k_local + k_global and the duplicate qkg row fetch.
//  - gh stored bf16; k_giru/k_gin read memb (bf16) for residual/GRU base.
// Algebra (earlier rounds): q_l folded into qkg; local V/O folded into Wl2/blv;
// bk_l/bk_g dropped (cancel in softmax); scatter-add -> CSR gather.
// Outputs (f32, concat): logits(E,5) | ew(E,8) | h_before(N,8,128) | a_g(E,8)

#define HSZ 128
typedef unsigned short ushortT;
typedef unsigned int uintT;
typedef short short8 __attribute__((ext_vector_type(8)));
typedef float f32x4 __attribute__((ext_vector_type(4)));

__device__ __forceinline__ float sigm(float x) { return 1.f / (1.f + __expf(-x)); }

__device__ __forceinline__ ushortT f2bf(float f) {
  unsigned int u = __float_as_uint(f);
  u += 0x7fffu + ((u >> 16) & 1u);
  return (ushortT)(u >> 16);
}
__device__ __forceinline__ float bf2f(ushortT u) {
  return __uint_as_float(((unsigned int)u) << 16);
}
__device__ __forceinline__ float bflo(uintT u) { return __uint_as_float(u << 16); }
__device__ __forceinline__ float bfhi(uintT u) { return __uint_as_float(u & 0xffff0000u); }
__device__ __forceinline__ uintT pk2bf(float a, float b) {
  return ((uintT)f2bf(b) << 16) | (uintT)f2bf(a);
}

// XOR-swizzled LDS chunk index (in shorts): row stride 64 shorts.
__device__ __forceinline__ int swzA(int row, int chunk) {
  return row * 64 + (((chunk ^ row) & 7) << 3);
}
__device__ __forceinline__ int swzT(int row, int chunk) {
  return row * 128 + (((chunk & 8) | ((chunk ^ row) & 7)) << 3);
}

// ---------------- bf16 MFMA GEMM ----------------
template<int ASRC, int ACT, bool OUTBF, bool ABF, bool WBF>
__global__ __launch_bounds__(256) void gemm_bf(
    const void* __restrict__ A1, const void* __restrict__ A2, const void* __restrict__ A3,
    const void* __restrict__ W, const float* __restrict__ bias,
    void* __restrict__ out_, int M, int K, int Nout)
{
  __shared__ short Ash[128 * 64];
  __shared__ short Bsh[128 * 64];
  float* out = (float*)out_;
  ushortT* outh = (ushortT*)out_;
  const int tid = threadIdx.x;
  const int m0 = blockIdx.x * 128;
  const int n0 = blockIdx.y * 128;
  const int l = tid & 63, w = tid >> 6;
  const int wr = w >> 1, wc = w & 1;
  const int lr = l & 15, lq = l >> 4;
  f32x4 acc[4][4] = {};

  for (int k0 = 0; k0 < K; k0 += 64) {
    __syncthreads();
    const bool fast = (k0 + 64 <= K);
    #pragma unroll
    for (int i = 0; i < 4; ++i) {
      int c = i * 256 + tid;
      int row = c >> 3, seg = c & 7;
      int kb = k0 + seg * 8;
      // ---- stage A ----
      {
        int m = m0 + row;
        short8 pk;
        if (ABF) {
          if (m < M) {
            if (ASRC == 3) {
              const ushortT* S = (kb < 128) ? (const ushortT*)A1
                               : (kb < 256) ? (const ushortT*)A2 : (const ushortT*)A3;
              pk = *reinterpret_cast<const short8*>(S + (size_t)m * 128 + (kb & 127));
            } else {
              pk = *reinterpret_cast<const short8*>((const ushortT*)A1 + (size_t)m * K + kb);
            }
          } else {
            #pragma unroll
            for (int j = 0; j < 8; ++j) pk[j] = 0;
          }
        } else {
          const float* A1f = (const float*)A1;
          float v[8];
          if (fast && m < M) {
            const float4* p = reinterpret_cast<const float4*>(A1f + (size_t)m * K + kb);
            float4 x0 = p[0], x1 = p[1];
            v[0]=x0.x; v[1]=x0.y; v[2]=x0.z; v[3]=x0.w;
            v[4]=x1.x; v[5]=x1.y; v[6]=x1.z; v[7]=x1.w;
          } else {
            #pragma unroll
            for (int j = 0; j < 8; ++j) {
              int k = kb + j;
              v[j] = (m < M && k < K) ? A1f[(size_t)m * K + k] : 0.f;
            }
          }
          #pragma unroll
          for (int j = 0; j < 8; ++j) pk[j] = (short)f2bf(v[j]);
        }
        *reinterpret_cast<short8*>(&Ash[swzA(row, seg)]) = pk;
      }
      // ---- stage B ----
      {
        int nn = n0 + row;
        short8 pk;
        if (WBF) {
          if (nn < Nout)
            pk = *reinterpret_cast<const short8*>((const ushortT*)W + (size_t)nn * K + kb);
          else {
            #pragma unroll
            for (int j = 0; j < 8; ++j) pk[j] = 0;
          }
        } else {
          const float* Wf = (const float*)W;
          float v[8];
          if (fast && nn < Nout) {
            const float4* p = reinterpret_cast<const float4*>(Wf + (size_t)nn * K + kb);
            float4 x0 = p[0], x1 = p[1];
            v[0]=x0.x; v[1]=x0.y; v[2]=x0.z; v[3]=x0.w;
            v[4]=x1.x; v[5]=x1.y; v[6]=x1.z; v[7]=x1.w;
          } else {
            #pragma unroll
            for (int j = 0; j < 8; ++j) {
              int k = kb + j;
              v[j] = (nn < Nout && k < K) ? Wf[(size_t)nn * K + k] : 0.f;
            }
          }
          #pragma unroll
          for (int j = 0; j < 8; ++j) pk[j] = (short)f2bf(v[j]);
        }
        *reinterpret_cast<short8*>(&Bsh[swzA(row, seg)]) = pk;
      }
    }
    __syncthreads();
    #pragma unroll
    for (int ks = 0; ks < 2; ++ks) {
      short8 a[4], b[4];
      #pragma unroll
      for (int mi = 0; mi < 4; ++mi)
        a[mi] = *reinterpret_cast<const short8*>(&Ash[swzA(wr*64 + mi*16 + lr, ks*4 + lq)]);
      #pragma unroll
      for (int ni = 0; ni < 4; ++ni)
        b[ni] = *reinterpret_cast<const short8*>(&Bsh[swzA(wc*64 + ni*16 + lr, ks*4 + lq)]);
      #pragma unroll
      for (int mi = 0; mi < 4; ++mi)
        #pragma unroll
        for (int ni = 0; ni < 4; ++ni)
          acc[mi][ni] = __builtin_amdgcn_mfma_f32_16x16x32_bf16(a[mi], b[ni], acc[mi][ni], 0, 0, 0);
    }
  }
  #pragma unroll
  for (int ni = 0; ni < 4; ++ni) {
    int col = n0 + wc*64 + ni*16 + lr;
    if (col >= Nout) continue;
    float bz = bias ? bias[col] : 0.f;
    #pragma unroll
    for (int mi = 0; mi < 4; ++mi) {
      int mb = m0 + wr*64 + mi*16 + lq*4;
      #pragma unroll
      for (int r = 0; r < 4; ++r) {
        int m = mb + r;
        if (m >= M) continue;
        float vv = acc[mi][ni][r] + bz;
        if (ACT == 1) vv = fmaxf(vv, 0.f);
        size_t o = (size_t)m * Nout + col;
        if (OUTBF) outh[o] = f2bf(vv); else out[o] = vv;
      }
    }
  }
}

// ---------------- fused GIN layer (48KB LDS) ----------------
// LMODE 1: A = hb(bcast over v) + aggb; base = bf2f(hb bcast); out -> houtb bf16
// LMODE 2: A = hb + aggb;               base = bf2f(hb);       out -> houtf f32
template<int LMODE>
__global__ __launch_bounds__(256) void k_gin(
    const ushortT* __restrict__ hb, const ushortT* __restrict__ aggb,
    float* __restrict__ houtf, ushortT* __restrict__ houtb,
    const ushortT* __restrict__ W1b, const float* __restrict__ b1,
    const ushortT* __restrict__ W2b, const float* __restrict__ b2, int M)
{
  __shared__ short smem[24576];            // 48 KB
  short* Ash  = smem;
  short* Bsh  = smem + 8192;
  short* Tsh  = smem;                      // overlaps Ash+Bsh
  short* B2sh = smem + 16384;
  const int tid = threadIdx.x;
  const int m0 = blockIdx.x * 128;
  const int l = tid & 63, w = tid >> 6;
  const int wr = w >> 1, wc = w & 1;
  const int lr = l & 15, lq = l >> 4;
  f32x4 acc[4][4] = {};

  for (int ks2 = 0; ks2 < 2; ++ks2) {
    if (ks2) __syncthreads();
    #pragma unroll
    for (int i = 0; i < 4; ++i) {
      int c = i * 256 + tid;
      int row = c >> 3, seg = c & 7;
      int kb = ks2 * 64 + seg * 8;
      {
        int m = m0 + row;
        short8 pk;
        if (m < M) {
          short8 hv;
          if (LMODE == 1) hv = *reinterpret_cast<const short8*>(hb + ((size_t)(m >> 3)) * 128 + kb);
          else            hv = *reinterpret_cast<const short8*>(hb + (size_t)m * 128 + kb);
          short8 av = *reinterpret_cast<const short8*>(aggb + (size_t)m * 128 + kb);
          #pragma unroll
          for (int j = 0; j < 8; ++j)
            pk[j] = (short)f2bf(bf2f((ushortT)hv[j]) + bf2f((ushortT)av[j]));
        } else {
          #pragma unroll
          for (int j = 0; j < 8; ++j) pk[j] = 0;
        }
        *reinterpret_cast<short8*>(&Ash[swzA(row, seg)]) = pk;
      }
      *reinterpret_cast<short8*>(&Bsh[swzA(row, seg)]) =
          *reinterpret_cast<const short8*>(W1b + (size_t)row * 128 + kb);
      if (ks2 == 0)
        *reinterpret_cast<short8*>(&B2sh[swzA(row, seg)]) =
            *reinterpret_cast<const short8*>(W2b + (size_t)row * 128 + seg * 8);
    }
    __syncthreads();
    #pragma unroll
    for (int ks = 0; ks < 2; ++ks) {
      short8 a[4], b[4];
      #pragma unroll
      for (int mi = 0; mi < 4; ++mi)
        a[mi] = *reinterpret_cast<const short8*>(&Ash[swzA(wr*64 + mi*16 + lr, ks*4 + lq)]);
      #pragma unroll
      for (int ni = 0; ni < 4; ++ni)
        b[ni] = *reinterpret_cast<const short8*>(&Bsh[swzA(wc*64 + ni*16 + lr, ks*4 + lq)]);
      #pragma unroll
      for (int mi = 0; mi < 4; ++mi)
        #pragma unroll
        for (int ni = 0; ni < 4; ++ni)
          acc[mi][ni] = __builtin_amdgcn_mfma_f32_16x16x32_bf16(a[mi], b[ni], acc[mi][ni], 0, 0, 0);
    }
  }
  __syncthreads();
  {
    float b1v[4];
    #pragma unroll
    for (int ni = 0; ni < 4; ++ni) b1v[ni] = b1[wc*64 + ni*16 + lr];
    #pragma unroll
    for (int mi = 0; mi < 4; ++mi)
      #pragma unroll
      for (int ni = 0; ni < 4; ++ni) {
        int col = wc*64 + ni*16 + lr;
        #pragma unroll
        for (int r = 0; r < 4; ++r) {
          int row = wr*64 + mi*16 + lq*4 + r;
          float v = fmaxf(acc[mi][ni][r] + b1v[ni], 0.f);
          Tsh[swzT(row, col >> 3) + (col & 7)] = (short)f2bf(v);
        }
      }
  }
  __syncthreads();
  f32x4 acc2[4][4] = {};
  for (int ks2 = 0; ks2 < 2; ++ks2) {
    if (ks2) {
      __syncthreads();
      #pragma unroll
      for (int i = 0; i < 4; ++i) {
        int c = i * 256 + tid;
        int row = c >> 3, seg = c & 7;
        *reinterpret_cast<short8*>(&B2sh[swzA(row, seg)]) =
            *reinterpret_cast<const short8*>(W2b + (size_t)row * 128 + 64 + seg * 8);
      }
      __syncthreads();
    }
    #pragma unroll
    for (int ks = 0; ks < 2; ++ks) {
      short8 a[4], b[4];
      #pragma unroll
      for (int mi = 0; mi < 4; ++mi)
        a[mi] = *reinterpret_cast<const short8*>(&Tsh[swzT(wr*64 + mi*16 + lr, ks2*8 + ks*4 + lq)]);
      #pragma unroll
      for (int ni = 0; ni < 4; ++ni)
        b[ni] = *reinterpret_cast<const short8*>(&B2sh[swzA(wc*64 + ni*16 + lr, ks*4 + lq)]);
      #pragma unroll
      for (int mi = 0; mi < 4; ++mi)
        #pragma unroll
        for (int ni = 0; ni < 4; ++ni)
          acc2[mi][ni] = __builtin_amdgcn_mfma_f32_16x16x32_bf16(a[mi], b[ni], acc2[mi][ni], 0, 0, 0);
    }
  }
  {
    float b2v[4];
    #pragma unroll
    for (int ni = 0; ni < 4; ++ni) b2v[ni] = b2[wc*64 + ni*16 + lr];
    #pragma unroll
    for (int ni = 0; ni < 4; ++ni) {
      int col = wc*64 + ni*16 + lr;
      #pragma unroll
      for (int mi = 0; mi < 4; ++mi) {
        int mb = m0 + wr*64 + mi*16 + lq*4;
        #pragma unroll
        for (int r = 0; r < 4; ++r) {
          int m = mb + r;
          if (m >= M) continue;
          float base = (LMODE == 1) ? bf2f(hb[((size_t)(m >> 3)) * 128 + col])
                                    : bf2f(hb[(size_t)m * 128 + col]);
          float ho = base + acc2[mi][ni][r] + b2v[ni];
          if (LMODE == 1) houtb[(size_t)m * 128 + col] = f2bf(ho);
          else            houtf[(size_t)m * 128 + col] = ho;
        }
      }
    }
  }
}

// ---------------- fused gi GEMM + GRU ----------------
__global__ __launch_bounds__(512) void k_giru(
    const float* __restrict__ hf, const float* __restrict__ te,
    const ushortT* __restrict__ Wihb, const float* __restrict__ b_ih,
    const ushortT* __restrict__ ghb, const ushortT* __restrict__ memb,
    ushortT* __restrict__ hnb, int M)
{
  __shared__ short Ash[8192];     // 64 x 128 (swzT)
  __shared__ short Bsh[24576];    // 384 x 64 (swzA)
  const int tid = threadIdx.x;
  const int m0 = blockIdx.x * 64;
  const int l = tid & 63, w = tid >> 6;
  const int lr = l & 15, lq = l >> 4;
  const int r0 = (w >> 1) * 16, c0 = (w & 1) * 64;
  f32x4 acc[3][4] = {};

  #pragma unroll
  for (int i = 0; i < 2; ++i) {
    int c = i * 512 + tid;
    int row = c >> 4, seg = c & 15;
    int m = m0 + row;
    short8 pk;
    if (m < M) {
      const float4* p = reinterpret_cast<const float4*>(hf + (size_t)m * 128 + seg * 8);
      const float4* t = reinterpret_cast<const float4*>(te + seg * 8);
      float4 x0 = p[0], x1 = p[1], t0 = t[0], t1 = t[1];
      pk[0]=(short)f2bf(x0.x+t0.x); pk[1]=(short)f2bf(x0.y+t0.y);
      pk[2]=(short)f2bf(x0.z+t0.z); pk[3]=(short)f2bf(x0.w+t0.w);
      pk[4]=(short)f2bf(x1.x+t1.x); pk[5]=(short)f2bf(x1.y+t1.y);
      pk[6]=(short)f2bf(x1.z+t1.z); pk[7]=(short)f2bf(x1.w+t1.w);
    } else {
      #pragma unroll
      for (int j = 0; j < 8; ++j) pk[j] = 0;
    }
    *reinterpret_cast<short8*>(&Ash[swzT(row, seg)]) = pk;
  }
  for (int ks2 = 0; ks2 < 2; ++ks2) {
    if (ks2) __syncthreads();
    #pragma unroll
    for (int i = 0; i < 6; ++i) {
      int c = i * 512 + tid;
      int row = c >> 3, seg = c & 7;
      *reinterpret_cast<short8*>(&Bsh[swzA(row, seg)]) =
          *reinterpret_cast<const short8*>(Wihb + (size_t)row * 128 + ks2 * 64 + seg * 8);
    }
    __syncthreads();
    #pragma unroll
    for (int ks = 0; ks < 2; ++ks) {
      short8 a = *reinterpret_cast<const short8*>(&Ash[swzT(r0 + lr, ks2*8 + ks*4 + lq)]);
      #pragma unroll
      for (int s = 0; s < 3; ++s)
        #pragma unroll
        for (int xi = 0; xi < 4; ++xi) {
          short8 b = *reinterpret_cast<const short8*>(
              &Bsh[swzA(s*128 + c0 + xi*16 + lr, ks*4 + lq)]);
          acc[s][xi] = __builtin_amdgcn_mfma_f32_16x16x32_bf16(a, b, acc[s][xi], 0, 0, 0);
        }
    }
  }
  #pragma unroll
  for (int xi = 0; xi < 4; ++xi) {
    int x = c0 + xi * 16 + lr;
    float br = b_ih[x], bz = b_ih[128 + x], bn = b_ih[256 + x];
    #pragma unroll
    for (int rr = 0; rr < 4; ++rr) {
      int m = m0 + r0 + lq * 4 + rr;
      if (m >= M) continue;
      int node = m >> 3;
      float ghr = bf2f(ghb[(size_t)node * 384 + x]);
      float ghz = bf2f(ghb[(size_t)node * 384 + 128 + x]);
      float ghn = bf2f(ghb[(size_t)node * 384 + 256 + x]);
      float mem = bf2f(memb[(size_t)node * 128 + x]);
      float rv = sigm(acc[0][xi][rr] + br + ghr);
      float zv = sigm(acc[1][xi][rr] + bz + ghz);
      float nv = tanhf(acc[2][xi][rr] + bn + rv * ghn);
      hnb[(size_t)m * 128 + x] = f2bf((1.f - zv) * nv + zv * mem);
    }
  }
}

// ---------------- CSR build ----------------
__global__ void k_hist(const int* __restrict__ srcI, int* __restrict__ cnt, int E)
{
  int e = blockIdx.x * 256 + threadIdx.x;
  if (e < E) atomicAdd(&cnt[srcI[e]], 1);
}

__global__ __launch_bounds__(1024) void k_scan(const int* __restrict__ cnt,
    int* __restrict__ ofs, int* __restrict__ cur, int N)
{
  __shared__ int buf[1024];
  __shared__ int carry;
  int tid = threadIdx.x;
  if (tid == 0) carry = 0;
  __syncthreads();
  for (int base = 0; base < N; base += 1024) {
    int i = base + tid;
    int v = (i < N) ? cnt[i] : 0;
    buf[tid] = v;
    __syncthreads();
    for (int off = 1; off < 1024; off <<= 1) {
      int t = (tid >= off) ? buf[tid - off] : 0;
      __syncthreads();
      buf[tid] += t;
      __syncthreads();
    }
    int excl = carry + buf[tid] - v;
    if (i < N) { ofs[i] = excl; cur[i] = excl; }
    __syncthreads();
    if (tid == 0) carry += buf[1023];
    __syncthreads();
  }
  if (tid == 0) ofs[N] = carry;
}

__global__ void k_fill(const int* __restrict__ srcI, int* __restrict__ cur,
                       int* __restrict__ eid, int E)
{
  int e = blockIdx.x * 256 + threadIdx.x;
  if (e >= E) return;
  int p = atomicAdd(&cur[srcI[e]], 1);
  eid[p] = e;
}

// ---------------- GIN aggregation (CSR gather, bf16) ----------------
template<int LMODE>
__global__ __launch_bounds__(256) void k_agg(const ushortT* __restrict__ hb,
    const ushortT* __restrict__ eab, const float* __restrict__ ew,
    const int* __restrict__ dstI, const int* __restrict__ ofs,
    const int* __restrict__ eid, ushortT* __restrict__ aggb, int N)
{
  int half = threadIdx.x >> 7;
  int x = threadIdx.x & 127;
  int n = blockIdx.x * 2 + half;
  if (n >= N) return;
  float acc[8] = {};
  int beg = ofs[n], end = ofs[n + 1];
  for (int i = beg; i < end; ++i) {
    int e = eid[i];
    int d = dstI[e];
    float eav = bf2f(eab[(size_t)e * 128 + x]);
    const float* ewp = ew + (size_t)e * 8;
    if (LMODE == 1) {
      float m = fmaxf(bf2f(hb[(size_t)d * 128 + x]) + eav, 0.f);
      #pragma unroll
      for (int v = 0; v < 8; ++v) acc[v] += m * ewp[v];
    } else {
      const ushortT* hd = hb + (size_t)d * 1024;
      #pragma unroll
      for (int v = 0; v < 8; ++v)
        acc[v] += fmaxf(bf2f(hd[v * 128 + x]) + eav, 0.f) * ewp[v];
    }
  }
  ushortT* ag = aggb + (size_t)n * 1024;
  #pragma unroll
  for (int v = 0; v < 8; ++v) ag[v * 128 + x] = f2bf(acc[v]);
}

// ---------------- edge gate ----------------
__global__ __launch_bounds__(256) void k_ew(const ushortT* __restrict__ eab,
    const ushortT* __restrict__ memb, const int* __restrict__ srcI,
    const float* __restrict__ W_ewg, const float* __restrict__ b_ewg,
    float* __restrict__ ew, int E)
{
  __shared__ float Wsh[2048];
  __shared__ float bsh[8];
  int tid = threadIdx.x;
  for (int i = tid; i < 2048; i += 256) Wsh[i] = W_ewg[i];
  if (tid < 8) bsh[tid] = b_ewg[tid];
  __syncthreads();
  int wv = tid >> 6, lane = tid & 63;
  int e = blockIdx.x * 4 + wv;
  if (e >= E) return;
  int s = srcI[e];
  float c0 = bf2f(eab[(size_t)e * 128 + lane]);
  float c1 = bf2f(eab[(size_t)e * 128 + 64 + lane]);
  float c2 = bf2f(memb[(size_t)s * 128 + lane]);
  float c3 = bf2f(memb[(size_t)s * 128 + 64 + lane]);
  #pragma unroll
  for (int v = 0; v < 8; ++v) {
    float p = c0 * Wsh[v * 256 + lane] + c1 * Wsh[v * 256 + 64 + lane]
            + c2 * Wsh[v * 256 + 128 + lane] + c3 * Wsh[v * 256 + 192 + lane];
    #pragma unroll
    for (int o = 32; o; o >>= 1) p += __shfl_down(p, o);
    if (lane == 0) ew[(size_t)e * 8 + v] = sigm(p + bsh[v]);
  }
}

// ---------------- f32 -> bf16 copy ----------------
__global__ void k_cvt(const float* __restrict__ src, ushortT* __restrict__ dst, int total)
{
  int i = blockIdx.x * 256 + threadIdx.x;
  if (i < total) dst[i] = f2bf(src[i]);
}

// ---------------- te ----------------
__global__ void k_te(const float* __restrict__ delta_t, const float* __restrict__ W_t,
                     const float* __restrict__ b_t, float* __restrict__ te)
{
  int t = threadIdx.x;
  if (t < 128) te[t] = sinf(delta_t[0] * W_t[t] + b_t[t]);
}

// ---------------- pooled partial sums ----------------
__global__ __launch_bounds__(256) void k_pool(const ushortT* __restrict__ hnb,
                                              float* __restrict__ prw, int N)
{
  int tid = threadIdx.x;
  float acc[4] = {0.f, 0.f, 0.f, 0.f};
  for (int n = blockIdx.x; n < N; n += gridDim.x) {
    const ushortT* row = hnb + (size_t)n * 1024;
    #pragma unroll
    for (int j = 0; j < 4; ++j) acc[j] += bf2f(row[tid + j * 256]);
  }
  #pragma unroll
  for (int j = 0; j < 4; ++j) atomicAdd(&prw[tid + j * 256], acc[j]);
}

// ---------------- fused small mats (bf16 out) ----------------
__global__ __launch_bounds__(256) void k_prep(
    const float* __restrict__ Wo_l, const float* __restrict__ Wv_l,
    const float* __restrict__ bv_l, const float* __restrict__ bo_l,
    const float* __restrict__ Wq_l, const float* __restrict__ bq_l,
    const float* __restrict__ Wk_l, const float* __restrict__ Wq_g,
    const float* __restrict__ bq_g,
    ushortT* __restrict__ Wl2b, float* __restrict__ blv,
    ushortT* __restrict__ Wqkgb, float* __restrict__ bqkg)
{
  int idx = blockIdx.x * 256 + threadIdx.x;    // 81920 total
  if (idx < 32768) {
    int n = idx >> 8, k = idx & 255;
    float a = 0.f;
    for (int j = 0; j < 128; ++j) a += Wo_l[n * 128 + j] * Wv_l[j * 256 + k];
    Wl2b[idx] = f2bf(a);
  } else if (idx < 65536) {
    int rem = idx - 32768;
    int n = rem >> 7, j = rem & 127;
    float a = 0.f;
    for (int k = 0; k < 128; ++k) a += Wq_l[k * 128 + j] * Wk_l[k * 256 + n];
    Wqkgb[rem] = f2bf(a);
  } else {
    int rem = idx - 65536;
    Wqkgb[32768 + rem] = f2bf(Wq_g[rem]);
  }
  if (blockIdx.x == 0 && threadIdx.x < 128) {
    int n = threadIdx.x;
    float a = bo_l[n];
    for (int j = 0; j < 128; ++j) a += Wo_l[n * 128 + j] * bv_l[j];
    blv[n] = a;
  }
  if (blockIdx.x == 1) {
    int n = threadIdx.x;
    float a = 0.f;
    for (int k = 0; k < 128; ++k) a += bq_l[k] * Wk_l[k * 256 + n];
    bqkg[n] = a;
  }
  if (blockIdx.x == 2 && threadIdx.x < 128) bqkg[256 + threadIdx.x] = bq_g[threadIdx.x];
}

// ---------------- Kg / G for global attention ----------------
__global__ __launch_bounds__(256) void k_kgg(const float* __restrict__ prw,
    const float* __restrict__ Wk_g, const float* __restrict__ Wv_g, const float* __restrict__ bv_g,
    const float* __restrict__ Wo_g, float* __restrict__ Kg, float* __restrict__ G, int N)
{
  __shared__ float pl[1024];
  __shared__ float vg[1024];
  int tid = threadIdx.x;
  float invN = 1.f / (float)N;
  for (int i = tid; i < 1024; i += 256) pl[i] = prw[i] * invN;
  __syncthreads();
  for (int o = tid; o < 1024; o += 256) {
    int v = o >> 7, x = o & 127;
    float a = 0.f, b = 0.f;
    for (int k = 0; k < 128; ++k) {
      float p = pl[v * 128 + k];
      a += p * Wk_g[(size_t)x * 128 + k];
      b += p * Wv_g[(size_t)x * 128 + k];
    }
    Kg[o] = a;
    vg[o] = b + bv_g[x];
  }
  __syncthreads();
  for (int o = tid; o < 1024; o += 256) {
    int v = o >> 7, x = o & 127;
    float a = 0.f;
    for (int k = 0; k < 128; ++k) a += vg[v * 128 + k] * Wo_g[(size_t)x * 128 + k];
    G[o] = a;
  }
}

// ---------------- fused local+global attention: wave-per-edge ----------------
// Per wave (edge e): lane l owns cols x=2l,2l+1. Registers hold sf/df rows.
// Local: scores via (q1,q2)·(sf,df), softmax, ws/wd weighted sums -> wsd bf16.
// Global: scores via qg·Kg (LDS), softmax -> ag_out f32; out = bo_g + a·G -> glbb.
__global__ __launch_bounds__(256) void k_lg(
    const ushortT* __restrict__ hnb, const ushortT* __restrict__ qkgb,
    const int* __restrict__ srcI, const int* __restrict__ dstI,
    const float* __restrict__ Kg, const float* __restrict__ G,
    const float* __restrict__ bo_g,
    float* __restrict__ ag_out, ushortT* __restrict__ wsd,
    ushortT* __restrict__ glbb, int E)
{
  __shared__ float Kgs[1024], Gs[1024], bs[128];
  int tid = threadIdx.x;
  for (int i = tid; i < 1024; i += 256) { Kgs[i] = Kg[i]; Gs[i] = G[i]; }
  if (tid < 128) bs[tid] = bo_g[tid];
  __syncthreads();
  int w = tid >> 6, l = tid & 63;
  int e = blockIdx.x * 4 + w;
  if (e >= E) return;
  int s = srcI[e], d = dstI[e];
  const uintT* qrow = reinterpret_cast<const uintT*>(qkgb + (size_t)e * 384);
  const uintT* srow = reinterpret_cast<const uintT*>(hnb + (size_t)s * 1024);
  const uintT* drow = reinterpret_cast<const uintT*>(hnb + (size_t)d * 1024);
  uintT q1u = qrow[l], q2u = qrow[64 + l], qgu = qrow[128 + l];
  float q1a = bflo(q1u), q1b = bfhi(q1u);
  float q2a = bflo(q2u), q2b = bfhi(q2u);
  float qga = bflo(qgu), qgb_ = bfhi(qgu);
  float sfa[8], sfb[8], dfa[8], dfb[8], pl[8], pg[8];
  #pragma unroll
  for (int v = 0; v < 8; ++v) {
    uintT su = srow[v * 64 + l], du = drow[v * 64 + l];
    sfa[v] = bflo(su); sfb[v] = bfhi(su);
    dfa[v] = bflo(du); dfb[v] = bfhi(du);
    pl[v] = q1a * sfa[v] + q1b * sfb[v] + q2a * dfa[v] + q2b * dfb[v];
    float2 kv = *reinterpret_cast<const float2*>(&Kgs[v * 128 + 2 * l]);
    pg[v] = qga * kv.x + qgb_ * kv.y;
  }
  #pragma unroll
  for (int v = 0; v < 8; ++v) {
    #pragma unroll
    for (int m = 1; m <= 32; m <<= 1) {
      pl[v] += __shfl_xor(pl[v], m);
      pg[v] += __shfl_xor(pg[v], m);
    }
  }
  const float scale = 0.08838834764831845f;   // 1/sqrt(128)
  // local softmax + PV
  float mx = pl[0];
  #pragma unroll
  for (int v = 1; v < 8; ++v) mx = fmaxf(mx, pl[v]);
  float suml = 0.f, al[8];
  #pragma unroll
  for (int v = 0; v < 8; ++v) { al[v] = __expf((pl[v] - mx) * scale); suml += al[v]; }
  float invl = 1.f / suml;
  float wsa = 0.f, wsb = 0.f, wda = 0.f, wdb = 0.f;
  #pragma unroll
  for (int v = 0; v < 8; ++v) {
    float a = al[v];
    wsa += a * sfa[v]; wsb += a * sfb[v];
    wda += a * dfa[v]; wdb += a * dfb[v];
  }
  uintT* wrow = reinterpret_cast<uintT*>(wsd + (size_t)e * 256);
  wrow[l]      = pk2bf(wsa * invl, wsb * invl);
  wrow[64 + l] = pk2bf(wda * invl, wdb * invl);
  // global softmax + out
  float mg = pg[0];
  #pragma unroll
  for (int v = 1; v < 8; ++v) mg = fmaxf(mg, pg[v]);
  float sumg = 0.f, ag[8];
  #pragma unroll
  for (int v = 0; v < 8; ++v) { ag[v] = __expf((pg[v] - mg) * scale); sumg += ag[v]; }
  float invg = 1.f / sumg;
  if (l < 8) ag_out[(size_t)e * 8 + l] = ag[l] * invg;
  float2 bv = *reinterpret_cast<const float2*>(&bs[2 * l]);
  float ga = bv.x, gb = bv.y;
  #pragma unroll
  for (int v = 0; v < 8; ++v) {
    float sv = ag[v] * invg;
    float2 gv = *reinterpret_cast<const float2*>(&Gs[v * 128 + 2 * l]);
    ga += sv * gv.x; gb += sv * gv.y;
  }
  reinterpret_cast<uintT*>(glbb)[(size_t)e * 64 + l] = pk2bf(ga, gb);
}

// ---------------- logits ----------------
__global__ __launch_bounds__(256) void k_logits(const ushortT* __restrict__ hid,
    const float* __restrict__ Wc2, const float* __restrict__ bc2,
    float* __restrict__ logits, int E)
{
  __shared__ float Wsh[640];
  __shared__ float bsh[5];
  int tid = threadIdx.x;
  for (int i = tid; i < 640; i += 256) Wsh[i] = Wc2[i];
  if (tid < 5) bsh[tid] = bc2[tid];
  __syncthreads();
  int wv = tid >> 6, lane = tid & 63;
  int e = blockIdx.x * 4 + wv;
  if (e >= E) return;
  float h0 = bf2f(hid[(size_t)e * 128 + lane]), h1 = bf2f(hid[(size_t)e * 128 + 64 + lane]);
  #pragma unroll
  for (int c = 0; c < 5; ++c) {
    float p = h0 * Wsh[c * 128 + lane] + h1 * Wsh[c * 128 + 64 + lane];
    #pragma unroll
    for (int o = 32; o; o >>= 1) p += __shfl_down(p, o);
    if (lane == 0) logits[(size_t)e * 5 + c] = p + bsh[c];
  }
}

extern "C" void kernel_launch(void* const* d_in, const int* in_sizes, int n_in,
                              void* d_out, int out_size, void* d_ws, size_t ws_size,
                              hipStream_t stream)
{
  const int*   edge_index = (const int*)d_in[0];
  const float* edge_attr  = (const float*)d_in[1];
  const float* delta_t    = (const float*)d_in[2];
  const float* memory     = (const float*)d_in[3];
  const float* W_ee  = (const float*)d_in[4];
  const float* b_ee  = (const float*)d_in[5];
  const float* W_ewg = (const float*)d_in[6];
  const float* b_ewg = (const float*)d_in[7];
  const float* gin_W1 = (const float*)d_in[8];
  const float* gin_b1 = (const float*)d_in[9];
  const float* gin_W2 = (const float*)d_in[10];
  const float* gin_b2 = (const float*)d_in[11];
  const float* W_t  = (const float*)d_in[12];
  const float* b_t  = (const float*)d_in[13];
  const float* W_ih = (const float*)d_in[14];
  const float* b_ih = (const float*)d_in[15];
  const float* W_hh = (const float*)d_in[16];
  const float* b_hh = (const float*)d_in[17];
  const float* Wq_l = (const float*)d_in[20];
  const float* bq_l = (const float*)d_in[21];
  const float* Wk_l = (const float*)d_in[22];
  const float* Wv_l = (const float*)d_in[24];
  const float* bv_l = (const float*)d_in[25];
  const float* Wo_l = (const float*)d_in[26];
  const float* bo_l = (const float*)d_in[27];
  const float* Wq_g = (const float*)d_in[28];
  const float* bq_g = (const float*)d_in[29];
  const float* Wk_g = (const float*)d_in[30];
  const float* Wv_g = (const float*)d_in[32];
  const float* bv_g = (const float*)d_in[33];
  const float* Wo_g = (const float*)d_in[34];
  const float* bo_g = (const float*)d_in[35];
  const float* Wc1  = (const float*)d_in[36];
  const float* bc1  = (const float*)d_in[37];
  const float* Wc2  = (const float*)d_in[38];
  const float* bc2  = (const float*)d_in[39];

  const int E = in_sizes[0] / 2;
  const int N = in_sizes[3] / HSZ;
  const int* srcI = edge_index;
  const int* dstI = edge_index + E;

  float* out    = (float*)d_out;
  float* logits = out;
  float* ew     = out + (size_t)E * 5;
  float* h      = out + (size_t)E * 13;                       // h_before (N,8,128) f32
  float* ag_out = out + (size_t)E * 13 + (size_t)N * 1024;

  // ---- workspace arena (units: f32 slots) ----
  float* ws = (float*)d_ws;
  size_t off = 0;
  auto alloc = [&](size_t n) { size_t o = off; off += (n + 255) & ~(size_t)255; return o; };
  float* te   = ws + alloc(128);
  float* blv  = ws + alloc(128);
  float* bqkg = ws + alloc(384);
  float* Kg   = ws + alloc(1024);
  float* G    = ws + alloc(1024);
  float* prw  = ws + alloc(1024);
  int* cnt = (int*)(ws + alloc(N));
  int* ofs = (int*)(ws + alloc(N + 1));
  int* cur = (int*)(ws + alloc(N));
  int* eid = (int*)(ws + alloc(E));
  ushortT* memb   = (ushortT*)(ws + alloc((size_t)N * 64));
  ushortT* eab    = (ushortT*)(ws + alloc((size_t)E * 64));
  ushortT* h1b    = (ushortT*)(ws + alloc((size_t)N * 512));
  ushortT* hnb    = (ushortT*)(ws + alloc((size_t)N * 512));
  ushortT* ghb    = (ushortT*)(ws + alloc((size_t)N * 192));
  ushortT* ginW1b = (ushortT*)(ws + alloc(16384));
  ushortT* ginW2b = (ushortT*)(ws + alloc(16384));
  ushortT* Wihb   = (ushortT*)(ws + alloc(24576));
  ushortT* Wc1b   = (ushortT*)(ws + alloc(24576));
  ushortT* Wl2b   = (ushortT*)(ws + alloc(16384));
  ushortT* Wqkgb  = (ushortT*)(ws + alloc(24576));
  // BR union: aggb (N*512) | attn (E*448)
  size_t brA = (size_t)N * 512, brC = (size_t)E * 448;
  size_t brsz = brA > brC ? brA : brC;
  float* BR = ws + alloc(brsz);
  if (ws_size < off * sizeof(float)) return;   // needs ~155 MiB

  ushortT* aggb = (ushortT*)BR;
  ushortT* qkgb = (ushortT*)BR;                        // E x 384
  ushortT* wsd  = (ushortT*)(BR + (size_t)E * 192);    // E x 256
  ushortT* lclb = (ushortT*)(BR + (size_t)E * 320);    // E x 128
  ushortT* glbb = (ushortT*)(BR + (size_t)E * 384);    // E x 128
  ushortT* hid  = (ushortT*)BR;                        // E x 128 (over dead qkgb)

  auto cdiv = [](int a, int b) { return (a + b - 1) / b; };

  // 0. CSR + bf16 mirrors/weights
  hipMemsetAsync(cnt, 0, (size_t)N * sizeof(int), stream);
  k_hist<<<cdiv(E, 256), 256, 0, stream>>>(srcI, cnt, E);
  k_scan<<<1, 1024, 0, stream>>>(cnt, ofs, cur, N);
  k_fill<<<cdiv(E, 256), 256, 0, stream>>>(srcI, cur, eid, E);
  k_cvt<<<cdiv(N * 128, 256), 256, 0, stream>>>(memory, memb, N * 128);
  k_cvt<<<128, 256, 0, stream>>>(gin_W1, ginW1b, 32768);
  k_cvt<<<128, 256, 0, stream>>>(gin_W2, ginW2b, 32768);
  k_cvt<<<192, 256, 0, stream>>>(W_ih, Wihb, 49152);
  k_cvt<<<192, 256, 0, stream>>>(Wc1, Wc1b, 49152);
  // 1. ea = relu(edge_attr @ W_ee^T + b_ee) -> bf16
  gemm_bf<0, 1, true, false, false><<<dim3(cdiv(E, 128), 1), 256, 0, stream>>>(
      edge_attr, nullptr, nullptr, W_ee, b_ee, eab, E, 59, 128);
  // 2. ew + te + prep + gh (bf16)
  k_ew<<<cdiv(E, 4), 256, 0, stream>>>(eab, memb, srcI, W_ewg, b_ewg, ew, E);
  k_te<<<1, 128, 0, stream>>>(delta_t, W_t, b_t, te);
  k_prep<<<320, 256, 0, stream>>>(Wo_l, Wv_l, bv_l, bo_l, Wq_l, bq_l, Wk_l, Wq_g, bq_g,
                                  Wl2b, blv, Wqkgb, bqkg);
  gemm_bf<0, 0, true, false, false><<<dim3(cdiv(N, 128), 3), 256, 0, stream>>>(
      memory, nullptr, nullptr, W_hh, b_hh, ghb, N, 128, 384);
  // 3. GIN layer 1 (h == broadcast memory)
  k_agg<1><<<cdiv(N, 2), 256, 0, stream>>>(memb, eab, ew, dstI, ofs, eid, aggb, N);
  k_gin<1><<<cdiv(N * 8, 128), 256, 0, stream>>>(
      memb, aggb, nullptr, h1b, ginW1b, gin_b1, ginW2b, gin_b2, N * 8);
  // 4. GIN layer 2 -> h (d_out f32)
  k_agg<2><<<cdiv(N, 2), 256, 0, stream>>>(h1b, eab, ew, dstI, ofs, eid, aggb, N);
  k_gin<2><<<cdiv(N * 8, 128), 256, 0, stream>>>(
      h1b, aggb, h, nullptr, ginW1b + 16384, gin_b1 + 128,
      ginW2b + 16384, gin_b2 + 128, N * 8);
  // 5. fused gi GEMM + GRU -> hnb
  k_giru<<<cdiv(N * 8, 64), 512, 0, stream>>>(h, te, Wihb, b_ih, ghb, memb, hnb, N * 8);
  // 6. pooled + global K/G
  hipMemsetAsync(prw, 0, 1024 * sizeof(float), stream);
  k_pool<<<256, 256, 0, stream>>>(hnb, prw, N);
  k_kgg<<<1, 256, 0, stream>>>(prw, Wk_g, Wv_g, bv_g, Wo_g, Kg, G, N);
  // 7. fused q projections (local qk1|qk2 + global q)
  gemm_bf<0, 0, true, true, true><<<dim3(cdiv(E, 128), 3), 256, 0, stream>>>(
      eab, nullptr, nullptr, Wqkgb, bqkg, qkgb, E, 128, 384);
  // 8. fused local+global attention
  k_lg<<<cdiv(E, 4), 256, 0, stream>>>(hnb, qkgb, srcI, dstI, Kg, G, bo_g,
                                       ag_out, wsd, glbb, E);
  gemm_bf<0, 0, true, true, true><<<dim3(cdiv(E, 128), 1), 256, 0, stream>>>(
      wsd, nullptr, nullptr, Wl2b, blv, lclb, E, 256, 128);
  // 9. classifier
  gemm_bf<3, 1, true, true, true><<<dim3(cdiv(E, 128), 1), 256, 0, stream>>>(
      eab, lclb, glbb, Wc1b, bc1, hid, E, 384, 128);
  k_logits<<<cdiv(E, 4), 256, 0, stream>>>(hid, Wc2, bc2, logits, E);
}

// Round 7
// 535.469 us; speedup vs baseline: 3.7615x; 1.0137x over previous
//
#include <hip/hip_runtime.h>
#include <cstddef>

// MVMGIN round 7:
//  - global-attention scores folded into the q-projection GEMM (Wsc = Kg@Wq_g built
//    after k_kgg): k_lg loses the whole pg shuffle-reduce and the qg columns.
//  - k_lg: 2 edges/wave (32-lane halves, 4 cols/lane) -> 20 shfl/edge vs 96.
//  - classifier fusion: localout GEMM eliminated via Wxb = Wc1b@Wl2 (K=512 GEMM
//    over {ea, wsd, glbb}).
//  - k_pool merged into k_giru (LDS histogram); te folded into k_prep; one cvt kernel.
// Outputs (f32, concat): logits(E,5) | ew(E,8) | h_before(N,8,128) | a_g(E,8)

#define HSZ 128
typedef unsigned short ushortT;
typedef unsigned int uintT;
typedef short short8 __attribute__((ext_vector_type(8)));
typedef float f32x4 __attribute__((ext_vector_type(4)));

__device__ __forceinline__ float sigm(float x) { return 1.f / (1.f + __expf(-x)); }

__device__ __forceinline__ ushortT f2bf(float f) {
  unsigned int u = __float_as_uint(f);
  u += 0x7fffu + ((u >> 16) & 1u);
  return (ushortT)(u >> 16);
}
__device__ __forceinline__ float bf2f(ushortT u) {
  return __uint_as_float(((unsigned int)u) << 16);
}
__device__ __forceinline__ float bflo(uintT u) { return __uint_as_float(u << 16); }
__device__ __forceinline__ float bfhi(uintT u) { return __uint_as_float(u & 0xffff0000u); }
__device__ __forceinline__ uintT pk2bf(float a, float b) {
  return ((uintT)f2bf(b) << 16) | (uintT)f2bf(a);
}

// XOR-swizzled LDS chunk index (in shorts): row stride 64 shorts.
__device__ __forceinline__ int swzA(int row, int chunk) {
  return row * 64 + (((chunk ^ row) & 7) << 3);
}
__device__ __forceinline__ int swzT(int row, int chunk) {
  return row * 128 + (((chunk & 8) | ((chunk ^ row) & 7)) << 3);
}

// ---------------- bf16 MFMA GEMM ----------------
// ASRC: 0=A1; 4=concat{A1(128), A2(256), A3(128)} bf16. ABF: A bf16 (K%64==0).
template<int ASRC, int ACT, bool OUTBF, bool ABF, bool WBF>
__global__ __launch_bounds__(256) void gemm_bf(
    const void* __restrict__ A1, const void* __restrict__ A2, const void* __restrict__ A3,
    const void* __restrict__ W, const float* __restrict__ bias,
    void* __restrict__ out_, int M, int K, int Nout)
{
  __shared__ short Ash[128 * 64];
  __shared__ short Bsh[128 * 64];
  float* out = (float*)out_;
  ushortT* outh = (ushortT*)out_;
  const int tid = threadIdx.x;
  const int m0 = blockIdx.x * 128;
  const int n0 = blockIdx.y * 128;
  const int l = tid & 63, w = tid >> 6;
  const int wr = w >> 1, wc = w & 1;
  const int lr = l & 15, lq = l >> 4;
  f32x4 acc[4][4] = {};

  for (int k0 = 0; k0 < K; k0 += 64) {
    __syncthreads();
    const bool fast = (k0 + 64 <= K);
    #pragma unroll
    for (int i = 0; i < 4; ++i) {
      int c = i * 256 + tid;
      int row = c >> 3, seg = c & 7;
      int kb = k0 + seg * 8;
      // ---- stage A ----
      {
        int m = m0 + row;
        short8 pk;
        if (ABF) {
          if (m < M) {
            if (ASRC == 4) {
              if (kb < 128)
                pk = *reinterpret_cast<const short8*>((const ushortT*)A1 + (size_t)m * 128 + kb);
              else if (kb < 384)
                pk = *reinterpret_cast<const short8*>((const ushortT*)A2 + (size_t)m * 256 + (kb - 128));
              else
                pk = *reinterpret_cast<const short8*>((const ushortT*)A3 + (size_t)m * 128 + (kb - 384));
            } else {
              pk = *reinterpret_cast<const short8*>((const ushortT*)A1 + (size_t)m * K + kb);
            }
          } else {
            #pragma unroll
            for (int j = 0; j < 8; ++j) pk[j] = 0;
          }
        } else {
          const float* A1f = (const float*)A1;
          float v[8];
          if (fast && m < M) {
            const float4* p = reinterpret_cast<const float4*>(A1f + (size_t)m * K + kb);
            float4 x0 = p[0], x1 = p[1];
            v[0]=x0.x; v[1]=x0.y; v[2]=x0.z; v[3]=x0.w;
            v[4]=x1.x; v[5]=x1.y; v[6]=x1.z; v[7]=x1.w;
          } else {
            #pragma unroll
            for (int j = 0; j < 8; ++j) {
              int k = kb + j;
              v[j] = (m < M && k < K) ? A1f[(size_t)m * K + k] : 0.f;
            }
          }
          #pragma unroll
          for (int j = 0; j < 8; ++j) pk[j] = (short)f2bf(v[j]);
        }
        *reinterpret_cast<short8*>(&Ash[swzA(row, seg)]) = pk;
      }
      // ---- stage B ----
      {
        int nn = n0 + row;
        short8 pk;
        if (WBF) {
          if (nn < Nout)
            pk = *reinterpret_cast<const short8*>((const ushortT*)W + (size_t)nn * K + kb);
          else {
            #pragma unroll
            for (int j = 0; j < 8; ++j) pk[j] = 0;
          }
        } else {
          const float* Wf = (const float*)W;
          float v[8];
          if (fast && nn < Nout) {
            const float4* p = reinterpret_cast<const float4*>(Wf + (size_t)nn * K + kb);
            float4 x0 = p[0], x1 = p[1];
            v[0]=x0.x; v[1]=x0.y; v[2]=x0.z; v[3]=x0.w;
            v[4]=x1.x; v[5]=x1.y; v[6]=x1.z; v[7]=x1.w;
          } else {
            #pragma unroll
            for (int j = 0; j < 8; ++j) {
              int k = kb + j;
              v[j] = (nn < Nout && k < K) ? Wf[(size_t)nn * K + k] : 0.f;
            }
          }
          #pragma unroll
          for (int j = 0; j < 8; ++j) pk[j] = (short)f2bf(v[j]);
        }
        *reinterpret_cast<short8*>(&Bsh[swzA(row, seg)]) = pk;
      }
    }
    __syncthreads();
    #pragma unroll
    for (int ks = 0; ks < 2; ++ks) {
      short8 a[4], b[4];
      #pragma unroll
      for (int mi = 0; mi < 4; ++mi)
        a[mi] = *reinterpret_cast<const short8*>(&Ash[swzA(wr*64 + mi*16 + lr, ks*4 + lq)]);
      #pragma unroll
      for (int ni = 0; ni < 4; ++ni)
        b[ni] = *reinterpret_cast<const short8*>(&Bsh[swzA(wc*64 + ni*16 + lr, ks*4 + lq)]);
      #pragma unroll
      for (int mi = 0; mi < 4; ++mi)
        #pragma unroll
        for (int ni = 0; ni < 4; ++ni)
          acc[mi][ni] = __builtin_amdgcn_mfma_f32_16x16x32_bf16(a[mi], b[ni], acc[mi][ni], 0, 0, 0);
    }
  }
  #pragma unroll
  for (int ni = 0; ni < 4; ++ni) {
    int col = n0 + wc*64 + ni*16 + lr;
    if (col >= Nout) continue;
    float bz = bias ? bias[col] : 0.f;
    #pragma unroll
    for (int mi = 0; mi < 4; ++mi) {
      int mb = m0 + wr*64 + mi*16 + lq*4;
      #pragma unroll
      for (int r = 0; r < 4; ++r) {
        int m = mb + r;
        if (m >= M) continue;
        float vv = acc[mi][ni][r] + bz;
        if (ACT == 1) vv = fmaxf(vv, 0.f);
        size_t o = (size_t)m * Nout + col;
        if (OUTBF) outh[o] = f2bf(vv); else out[o] = vv;
      }
    }
  }
}

// ---------------- fused GIN layer (48KB LDS) ----------------
template<int LMODE>
__global__ __launch_bounds__(256) void k_gin(
    const ushortT* __restrict__ hb, const ushortT* __restrict__ aggb,
    float* __restrict__ houtf, ushortT* __restrict__ houtb,
    const ushortT* __restrict__ W1b, const float* __restrict__ b1,
    const ushortT* __restrict__ W2b, const float* __restrict__ b2, int M)
{
  __shared__ short smem[24576];            // 48 KB
  short* Ash  = smem;
  short* Bsh  = smem + 8192;
  short* Tsh  = smem;                      // overlaps Ash+Bsh
  short* B2sh = smem + 16384;
  const int tid = threadIdx.x;
  const int m0 = blockIdx.x * 128;
  const int l = tid & 63, w = tid >> 6;
  const int wr = w >> 1, wc = w & 1;
  const int lr = l & 15, lq = l >> 4;
  f32x4 acc[4][4] = {};

  for (int ks2 = 0; ks2 < 2; ++ks2) {
    if (ks2) __syncthreads();
    #pragma unroll
    for (int i = 0; i < 4; ++i) {
      int c = i * 256 + tid;
      int row = c >> 3, seg = c & 7;
      int kb = ks2 * 64 + seg * 8;
      {
        int m = m0 + row;
        short8 pk;
        if (m < M) {
          short8 hv;
          if (LMODE == 1) hv = *reinterpret_cast<const short8*>(hb + ((size_t)(m >> 3)) * 128 + kb);
          else            hv = *reinterpret_cast<const short8*>(hb + (size_t)m * 128 + kb);
          short8 av = *reinterpret_cast<const short8*>(aggb + (size_t)m * 128 + kb);
          #pragma unroll
          for (int j = 0; j < 8; ++j)
            pk[j] = (short)f2bf(bf2f((ushortT)hv[j]) + bf2f((ushortT)av[j]));
        } else {
          #pragma unroll
          for (int j = 0; j < 8; ++j) pk[j] = 0;
        }
        *reinterpret_cast<short8*>(&Ash[swzA(row, seg)]) = pk;
      }
      *reinterpret_cast<short8*>(&Bsh[swzA(row, seg)]) =
          *reinterpret_cast<const short8*>(W1b + (size_t)row * 128 + kb);
      if (ks2 == 0)
        *reinterpret_cast<short8*>(&B2sh[swzA(row, seg)]) =
            *reinterpret_cast<const short8*>(W2b + (size_t)row * 128 + seg * 8);
    }
    __syncthreads();
    #pragma unroll
    for (int ks = 0; ks < 2; ++ks) {
      short8 a[4], b[4];
      #pragma unroll
      for (int mi = 0; mi < 4; ++mi)
        a[mi] = *reinterpret_cast<const short8*>(&Ash[swzA(wr*64 + mi*16 + lr, ks*4 + lq)]);
      #pragma unroll
      for (int ni = 0; ni < 4; ++ni)
        b[ni] = *reinterpret_cast<const short8*>(&Bsh[swzA(wc*64 + ni*16 + lr, ks*4 + lq)]);
      #pragma unroll
      for (int mi = 0; mi < 4; ++mi)
        #pragma unroll
        for (int ni = 0; ni < 4; ++ni)
          acc[mi][ni] = __builtin_amdgcn_mfma_f32_16x16x32_bf16(a[mi], b[ni], acc[mi][ni], 0, 0, 0);
    }
  }
  __syncthreads();
  {
    float b1v[4];
    #pragma unroll
    for (int ni = 0; ni < 4; ++ni) b1v[ni] = b1[wc*64 + ni*16 + lr];
    #pragma unroll
    for (int mi = 0; mi < 4; ++mi)
      #pragma unroll
      for (int ni = 0; ni < 4; ++ni) {
        int col = wc*64 + ni*16 + lr;
        #pragma unroll
        for (int r = 0; r < 4; ++r) {
          int row = wr*64 + mi*16 + lq*4 + r;
          float v = fmaxf(acc[mi][ni][r] + b1v[ni], 0.f);
          Tsh[swzT(row, col >> 3) + (col & 7)] = (short)f2bf(v);
        }
      }
  }
  __syncthreads();
  f32x4 acc2[4][4] = {};
  for (int ks2 = 0; ks2 < 2; ++ks2) {
    if (ks2) {
      __syncthreads();
      #pragma unroll
      for (int i = 0; i < 4; ++i) {
        int c = i * 256 + tid;
        int row = c >> 3, seg = c & 7;
        *reinterpret_cast<short8*>(&B2sh[swzA(row, seg)]) =
            *reinterpret_cast<const short8*>(W2b + (size_t)row * 128 + 64 + seg * 8);
      }
      __syncthreads();
    }
    #pragma unroll
    for (int ks = 0; ks < 2; ++ks) {
      short8 a[4], b[4];
      #pragma unroll
      for (int mi = 0; mi < 4; ++mi)
        a[mi] = *reinterpret_cast<const short8*>(&Tsh[swzT(wr*64 + mi*16 + lr, ks2*8 + ks*4 + lq)]);
      #pragma unroll
      for (int ni = 0; ni < 4; ++ni)
        b[ni] = *reinterpret_cast<const short8*>(&B2sh[swzA(wc*64 + ni*16 + lr, ks*4 + lq)]);
      #pragma unroll
      for (int mi = 0; mi < 4; ++mi)
        #pragma unroll
        for (int ni = 0; ni < 4; ++ni)
          acc2[mi][ni] = __builtin_amdgcn_mfma_f32_16x16x32_bf16(a[mi], b[ni], acc2[mi][ni], 0, 0, 0);
    }
  }
  {
    float b2v[4];
    #pragma unroll
    for (int ni = 0; ni < 4; ++ni) b2v[ni] = b2[wc*64 + ni*16 + lr];
    #pragma unroll
    for (int ni = 0; ni < 4; ++ni) {
      int col = wc*64 + ni*16 + lr;
      #pragma unroll
      for (int mi = 0; mi < 4; ++mi) {
        int mb = m0 + wr*64 + mi*16 + lq*4;
        #pragma unroll
        for (int r = 0; r < 4; ++r) {
          int m = mb + r;
          if (m >= M) continue;
          float base = (LMODE == 1) ? bf2f(hb[((size_t)(m >> 3)) * 128 + col])
                                    : bf2f(hb[(size_t)m * 128 + col]);
          float ho = base + acc2[mi][ni][r] + b2v[ni];
          if (LMODE == 1) houtb[(size_t)m * 128 + col] = f2bf(ho);
          else            houtf[(size_t)m * 128 + col] = ho;
        }
      }
    }
  }
}

// ---------------- fused gi GEMM + GRU + pooled partial ----------------
__global__ __launch_bounds__(512) void k_giru(
    const float* __restrict__ hf, const float* __restrict__ te,
    const ushortT* __restrict__ Wihb, const float* __restrict__ b_ih,
    const ushortT* __restrict__ ghb, const ushortT* __restrict__ memb,
    ushortT* __restrict__ hnb, float* __restrict__ prw, int M)
{
  __shared__ short Ash[8192];     // 16 KB; pool histogram aliases this after MFMA
  __shared__ short Bsh[24576];    // 48 KB
  float* poolsh = reinterpret_cast<float*>(Ash);
  const int tid = threadIdx.x;
  const int m0 = blockIdx.x * 64;
  const int l = tid & 63, w = tid >> 6;
  const int lr = l & 15, lq = l >> 4;
  const int r0 = (w >> 1) * 16, c0 = (w & 1) * 64;
  f32x4 acc[3][4] = {};

  #pragma unroll
  for (int i = 0; i < 2; ++i) {
    int c = i * 512 + tid;
    int row = c >> 4, seg = c & 15;
    int m = m0 + row;
    short8 pk;
    if (m < M) {
      const float4* p = reinterpret_cast<const float4*>(hf + (size_t)m * 128 + seg * 8);
      const float4* t = reinterpret_cast<const float4*>(te + seg * 8);
      float4 x0 = p[0], x1 = p[1], t0 = t[0], t1 = t[1];
      pk[0]=(short)f2bf(x0.x+t0.x); pk[1]=(short)f2bf(x0.y+t0.y);
      pk[2]=(short)f2bf(x0.z+t0.z); pk[3]=(short)f2bf(x0.w+t0.w);
      pk[4]=(short)f2bf(x1.x+t1.x); pk[5]=(short)f2bf(x1.y+t1.y);
      pk[6]=(short)f2bf(x1.z+t1.z); pk[7]=(short)f2bf(x1.w+t1.w);
    } else {
      #pragma unroll
      for (int j = 0; j < 8; ++j) pk[j] = 0;
    }
    *reinterpret_cast<short8*>(&Ash[swzT(row, seg)]) = pk;
  }
  for (int ks2 = 0; ks2 < 2; ++ks2) {
    if (ks2) __syncthreads();
    #pragma unroll
    for (int i = 0; i < 6; ++i) {
      int c = i * 512 + tid;
      int row = c >> 3, seg = c & 7;
      *reinterpret_cast<short8*>(&Bsh[swzA(row, seg)]) =
          *reinterpret_cast<const short8*>(Wihb + (size_t)row * 128 + ks2 * 64 + seg * 8);
    }
    __syncthreads();
    #pragma unroll
    for (int ks = 0; ks < 2; ++ks) {
      short8 a = *reinterpret_cast<const short8*>(&Ash[swzT(r0 + lr, ks2*8 + ks*4 + lq)]);
      #pragma unroll
      for (int s = 0; s < 3; ++s)
        #pragma unroll
        for (int xi = 0; xi < 4; ++xi) {
          short8 b = *reinterpret_cast<const short8*>(
              &Bsh[swzA(s*128 + c0 + xi*16 + lr, ks*4 + lq)]);
          acc[s][xi] = __builtin_amdgcn_mfma_f32_16x16x32_bf16(a, b, acc[s][xi], 0, 0, 0);
        }
    }
  }
  // pool histogram over dead Ash
  __syncthreads();
  for (int i = tid; i < 1024; i += 512) poolsh[i] = 0.f;
  __syncthreads();
  #pragma unroll
  for (int xi = 0; xi < 4; ++xi) {
    int x = c0 + xi * 16 + lr;
    float br = b_ih[x], bz = b_ih[128 + x], bn = b_ih[256 + x];
    #pragma unroll
    for (int rr = 0; rr < 4; ++rr) {
      int m = m0 + r0 + lq * 4 + rr;
      if (m >= M) continue;
      int node = m >> 3;
      float ghr = bf2f(ghb[(size_t)node * 384 + x]);
      float ghz = bf2f(ghb[(size_t)node * 384 + 128 + x]);
      float ghn = bf2f(ghb[(size_t)node * 384 + 256 + x]);
      float mem = bf2f(memb[(size_t)node * 128 + x]);
      float rv = sigm(acc[0][xi][rr] + br + ghr);
      float zv = sigm(acc[1][xi][rr] + bz + ghz);
      float nv = tanhf(acc[2][xi][rr] + bn + rv * ghn);
      float hn = (1.f - zv) * nv + zv * mem;
      hnb[(size_t)m * 128 + x] = f2bf(hn);
      atomicAdd(&poolsh[(m & 7) * 128 + x], hn);
    }
  }
  __syncthreads();
  for (int i = tid; i < 1024; i += 512) atomicAdd(&prw[i], poolsh[i]);
}

// ---------------- CSR build ----------------
__global__ void k_hist(const int* __restrict__ srcI, int* __restrict__ cnt, int E)
{
  int e = blockIdx.x * 256 + threadIdx.x;
  if (e < E) atomicAdd(&cnt[srcI[e]], 1);
}

__global__ __launch_bounds__(1024) void k_scan(const int* __restrict__ cnt,
    int* __restrict__ ofs, int* __restrict__ cur, int N)
{
  __shared__ int buf[1024];
  __shared__ int carry;
  int tid = threadIdx.x;
  if (tid == 0) carry = 0;
  __syncthreads();
  for (int base = 0; base < N; base += 1024) {
    int i = base + tid;
    int v = (i < N) ? cnt[i] : 0;
    buf[tid] = v;
    __syncthreads();
    for (int off = 1; off < 1024; off <<= 1) {
      int t = (tid >= off) ? buf[tid - off] : 0;
      __syncthreads();
      buf[tid] += t;
      __syncthreads();
    }
    int excl = carry + buf[tid] - v;
    if (i < N) { ofs[i] = excl; cur[i] = excl; }
    __syncthreads();
    if (tid == 0) carry += buf[1023];
    __syncthreads();
  }
  if (tid == 0) ofs[N] = carry;
}

__global__ void k_fill(const int* __restrict__ srcI, int* __restrict__ cur,
                       int* __restrict__ eid, int E)
{
  int e = blockIdx.x * 256 + threadIdx.x;
  if (e >= E) return;
  int p = atomicAdd(&cur[srcI[e]], 1);
  eid[p] = e;
}

// ---------------- GIN aggregation (CSR gather, bf16) ----------------
template<int LMODE>
__global__ __launch_bounds__(256) void k_agg(const ushortT* __restrict__ hb,
    const ushortT* __restrict__ eab, const float* __restrict__ ew,
    const int* __restrict__ dstI, const int* __restrict__ ofs,
    const int* __restrict__ eid, ushortT* __restrict__ aggb, int N)
{
  int half = threadIdx.x >> 7;
  int x = threadIdx.x & 127;
  int n = blockIdx.x * 2 + half;
  if (n >= N) return;
  float acc[8] = {};
  int beg = ofs[n], end = ofs[n + 1];
  for (int i = beg; i < end; ++i) {
    int e = eid[i];
    int d = dstI[e];
    float eav = bf2f(eab[(size_t)e * 128 + x]);
    const float* ewp = ew + (size_t)e * 8;
    if (LMODE == 1) {
      float m = fmaxf(bf2f(hb[(size_t)d * 128 + x]) + eav, 0.f);
      #pragma unroll
      for (int v = 0; v < 8; ++v) acc[v] += m * ewp[v];
    } else {
      const ushortT* hd = hb + (size_t)d * 1024;
      #pragma unroll
      for (int v = 0; v < 8; ++v)
        acc[v] += fmaxf(bf2f(hd[v * 128 + x]) + eav, 0.f) * ewp[v];
    }
  }
  ushortT* ag = aggb + (size_t)n * 1024;
  #pragma unroll
  for (int v = 0; v < 8; ++v) ag[v * 128 + x] = f2bf(acc[v]);
}

// ---------------- edge gate ----------------
__global__ __launch_bounds__(256) void k_ew(const ushortT* __restrict__ eab,
    const ushortT* __restrict__ memb, const int* __restrict__ srcI,
    const float* __restrict__ W_ewg, const float* __restrict__ b_ewg,
    float* __restrict__ ew, int E)
{
  __shared__ float Wsh[2048];
  __shared__ float bsh[8];
  int tid = threadIdx.x;
  for (int i = tid; i < 2048; i += 256) Wsh[i] = W_ewg[i];
  if (tid < 8) bsh[tid] = b_ewg[tid];
  __syncthreads();
  int wv = tid >> 6, lane = tid & 63;
  int e = blockIdx.x * 4 + wv;
  if (e >= E) return;
  int s = srcI[e];
  float c0 = bf2f(eab[(size_t)e * 128 + lane]);
  float c1 = bf2f(eab[(size_t)e * 128 + 64 + lane]);
  float c2 = bf2f(memb[(size_t)s * 128 + lane]);
  float c3 = bf2f(memb[(size_t)s * 128 + 64 + lane]);
  #pragma unroll
  for (int v = 0; v < 8; ++v) {
    float p = c0 * Wsh[v * 256 + lane] + c1 * Wsh[v * 256 + 64 + lane]
            + c2 * Wsh[v * 256 + 128 + lane] + c3 * Wsh[v * 256 + 192 + lane];
    #pragma unroll
    for (int o = 32; o; o >>= 1) p += __shfl_down(p, o);
    if (lane == 0) ew[(size_t)e * 8 + v] = sigm(p + bsh[v]);
  }
}

// ---------------- multi-tensor f32 -> bf16 ----------------
__global__ void k_cvtall(const float* __restrict__ s0, ushortT* __restrict__ d0, int n0,
                         const float* __restrict__ s1, ushortT* __restrict__ d1, int n1,
                         const float* __restrict__ s2, ushortT* __restrict__ d2, int n2,
                         const float* __restrict__ s3, ushortT* __restrict__ d3, int n3)
{
  int i = blockIdx.x * 256 + threadIdx.x;
  if (i < n0) { d0[i] = f2bf(s0[i]); return; }
  i -= n0;
  if (i < n1) { d1[i] = f2bf(s1[i]); return; }
  i -= n1;
  if (i < n2) { d2[i] = f2bf(s2[i]); return; }
  i -= n2;
  if (i < n3) d3[i] = f2bf(s3[i]);
}

// ---------------- fused small mats + te ----------------
// Wqkgb rows 0..255 = (Wq_l^T Wk_l)^T bf16; bqkg[0..256) = bq_l@Wk_l
// Wl2f(128,256) f32 = Wo_l@Wv_l; blv = bo_l + Wo_l@bv_l; te (block 2)
__global__ __launch_bounds__(256) void k_prep(
    const float* __restrict__ Wo_l, const float* __restrict__ Wv_l,
    const float* __restrict__ bv_l, const float* __restrict__ bo_l,
    const float* __restrict__ Wq_l, const float* __restrict__ bq_l,
    const float* __restrict__ Wk_l,
    const float* __restrict__ delta_t, const float* __restrict__ W_t,
    const float* __restrict__ b_t,
    float* __restrict__ Wl2f, float* __restrict__ blv,
    ushortT* __restrict__ Wqkgb, float* __restrict__ bqkg, float* __restrict__ te)
{
  int idx = blockIdx.x * 256 + threadIdx.x;    // 65536 total
  if (idx < 32768) {
    int n = idx >> 8, k = idx & 255;
    float a = 0.f;
    for (int j = 0; j < 128; ++j) a += Wo_l[n * 128 + j] * Wv_l[j * 256 + k];
    Wl2f[idx] = a;
  } else {
    int rem = idx - 32768;
    int n = rem >> 7, j = rem & 127;
    float a = 0.f;
    for (int k = 0; k < 128; ++k) a += Wq_l[k * 128 + j] * Wk_l[k * 256 + n];
    Wqkgb[rem] = f2bf(a);
  }
  if (blockIdx.x == 0 && threadIdx.x < 128) {
    int n = threadIdx.x;
    float a = bo_l[n];
    for (int j = 0; j < 128; ++j) a += Wo_l[n * 128 + j] * bv_l[j];
    blv[n] = a;
  }
  if (blockIdx.x == 1) {
    int n = threadIdx.x;
    float a = 0.f;
    for (int k = 0; k < 128; ++k) a += bq_l[k] * Wk_l[k * 256 + n];
    bqkg[n] = a;
  }
  if (blockIdx.x == 2 && threadIdx.x < 128) {
    int t = threadIdx.x;
    te[t] = sinf(delta_t[0] * W_t[t] + b_t[t]);
  }
}

// ---------------- classifier weight fusion: Wc1p(128,512), bc1p ----------------
// k<128: Wc1a; 128<=k<384: Wxb = Wc1b@Wl2; k>=384: Wc1c. bc1p = bc1 + Wc1b@blv.
__global__ __launch_bounds__(256) void k_prep2(
    const float* __restrict__ Wc1, const float* __restrict__ bc1,
    const float* __restrict__ Wl2f, const float* __restrict__ blv,
    ushortT* __restrict__ Wc1p, float* __restrict__ bc1p)
{
  int idx = blockIdx.x * 256 + threadIdx.x;    // 65536 total
  int n = idx >> 9, k = idx & 511;
  float a;
  if (k < 128) a = Wc1[(size_t)n * 384 + k];
  else if (k < 384) {
    int kk = k - 128;
    a = 0.f;
    for (int j = 0; j < 128; ++j) a += Wc1[(size_t)n * 384 + 128 + j] * Wl2f[j * 256 + kk];
  } else a = Wc1[(size_t)n * 384 + 256 + (k - 384)];
  Wc1p[idx] = f2bf(a);
  if (blockIdx.x == 0 && threadIdx.x < 128) {
    int nn = threadIdx.x;
    float b = bc1[nn];
    for (int j = 0; j < 128; ++j) b += Wc1[(size_t)nn * 384 + 128 + j] * blv[j];
    bc1p[nn] = b;
  }
}

// ---------------- Kg / G for global attention ----------------
__global__ __launch_bounds__(256) void k_kgg(const float* __restrict__ prw,
    const float* __restrict__ Wk_g, const float* __restrict__ Wv_g, const float* __restrict__ bv_g,
    const float* __restrict__ Wo_g, float* __restrict__ Kg, float* __restrict__ G, int N)
{
  __shared__ float pl[1024];
  __shared__ float vg[1024];
  int tid = threadIdx.x;
  float invN = 1.f / (float)N;
  for (int i = tid; i < 1024; i += 256) pl[i] = prw[i] * invN;
  __syncthreads();
  for (int o = tid; o < 1024; o += 256) {
    int v = o >> 7, x = o & 127;
    float a = 0.f, b = 0.f;
    for (int k = 0; k < 128; ++k) {
      float p = pl[v * 128 + k];
      a += p * Wk_g[(size_t)x * 128 + k];
      b += p * Wv_g[(size_t)x * 128 + k];
    }
    Kg[o] = a;
    vg[o] = b + bv_g[x];
  }
  __syncthreads();
  for (int o = tid; o < 1024; o += 256) {
    int v = o >> 7, x = o & 127;
    float a = 0.f;
    for (int k = 0; k < 128; ++k) a += vg[v * 128 + k] * Wo_g[(size_t)x * 128 + k];
    G[o] = a;
  }
}

// ---------------- global-score projection: Wqkgb rows 256..263, bqkg[256..264) ----
// Wsc[v][j] = sum_x Kg[v][x] * Wq_g[x][j];  bsc[v] = sum_x bq_g[x]*Kg[v][x]
__global__ __launch_bounds__(256) void k_sc(const float* __restrict__ Kg,
    const float* __restrict__ Wq_g, const float* __restrict__ bq_g,
    ushortT* __restrict__ Wqkgb, float* __restrict__ bqkg)
{
  int idx = blockIdx.x * 256 + threadIdx.x;    // 1024
  int v = idx >> 7, j = idx & 127;
  float a = 0.f;
  for (int x = 0; x < 128; ++x) a += Kg[v * 128 + x] * Wq_g[(size_t)x * 128 + j];
  Wqkgb[(size_t)(256 + v) * 128 + j] = f2bf(a);
  if (blockIdx.x == 0 && threadIdx.x < 8) {
    int vv = threadIdx.x;
    float b = 0.f;
    for (int x = 0; x < 128; ++x) b += bq_g[x] * Kg[vv * 128 + x];
    bqkg[256 + vv] = b;
  }
}

// ---------------- fused local+global attention: 2 edges/wave ----------------
// Lane owns 4 cols (x = 4*l31..4*l31+3). Global scores precomputed (qkg cols 256..263).
__global__ __launch_bounds__(256) void k_lg(
    const ushortT* __restrict__ hnb, const ushortT* __restrict__ qkgb,
    const int* __restrict__ srcI, const int* __restrict__ dstI,
    const float* __restrict__ G, const float* __restrict__ bo_g,
    float* __restrict__ ag_out, ushortT* __restrict__ wsd,
    ushortT* __restrict__ glbb, int E)
{
  __shared__ float Gs[1024], bsh[128];
  int tid = threadIdx.x;
  for (int i = tid; i < 1024; i += 256) Gs[i] = G[i];
  if (tid < 128) bsh[tid] = bo_g[tid];
  __syncthreads();
  int w = tid >> 6, l = tid & 63, half = l >> 5, l31 = l & 31;
  int e = blockIdx.x * 8 + w * 2 + half;
  int ec = (e < E) ? e : (E - 1);
  int s = srcI[ec], d = dstI[ec];
  const uint2* qrow = reinterpret_cast<const uint2*>(qkgb + (size_t)ec * 264);
  uint2 q1u = qrow[l31], q2u = qrow[32 + l31];
  uint4 scu = *reinterpret_cast<const uint4*>(qkgb + (size_t)ec * 264 + 256);
  const uint2* srow = reinterpret_cast<const uint2*>(hnb + (size_t)s * 1024);
  const uint2* drow = reinterpret_cast<const uint2*>(hnb + (size_t)d * 1024);
  uint2 su[8], du[8];
  #pragma unroll
  for (int v = 0; v < 8; ++v) { su[v] = srow[v * 32 + l31]; du[v] = drow[v * 32 + l31]; }
  float q1f[4] = {bflo(q1u.x), bfhi(q1u.x), bflo(q1u.y), bfhi(q1u.y)};
  float q2f[4] = {bflo(q2u.x), bfhi(q2u.x), bflo(q2u.y), bfhi(q2u.y)};
  float pl[8];
  #pragma unroll
  for (int v = 0; v < 8; ++v) {
    pl[v] = q1f[0] * bflo(su[v].x) + q1f[1] * bfhi(su[v].x)
          + q1f[2] * bflo(su[v].y) + q1f[3] * bfhi(su[v].y)
          + q2f[0] * bflo(du[v].x) + q2f[1] * bfhi(du[v].x)
          + q2f[2] * bflo(du[v].y) + q2f[3] * bfhi(du[v].y);
  }
  #pragma unroll
  for (int v = 0; v < 8; ++v) {
    #pragma unroll
    for (int m = 1; m <= 16; m <<= 1) pl[v] += __shfl_xor(pl[v], m);
  }
  const float scale = 0.08838834764831845f;   // 1/sqrt(128)
  // local softmax + weighted sums
  float mx = fmaxf(fmaxf(fmaxf(pl[0], pl[1]), fmaxf(pl[2], pl[3])),
                   fmaxf(fmaxf(pl[4], pl[5]), fmaxf(pl[6], pl[7])));
  float suml = 0.f, al[8];
  #pragma unroll
  for (int v = 0; v < 8; ++v) { al[v] = __expf((pl[v] - mx) * scale); suml += al[v]; }
  float invl = 1.f / suml;
  float ws0 = 0.f, ws1 = 0.f, ws2 = 0.f, ws3 = 0.f;
  float wd0 = 0.f, wd1 = 0.f, wd2 = 0.f, wd3 = 0.f;
  #pragma unroll
  for (int v = 0; v < 8; ++v) {
    float a = al[v];
    ws0 += a * bflo(su[v].x); ws1 += a * bfhi(su[v].x);
    ws2 += a * bflo(su[v].y); ws3 += a * bfhi(su[v].y);
    wd0 += a * bflo(du[v].x); wd1 += a * bfhi(du[v].x);
    wd2 += a * bflo(du[v].y); wd3 += a * bfhi(du[v].y);
  }
  if (e < E) {
    uint2* wrow = reinterpret_cast<uint2*>(wsd + (size_t)e * 256);
    uint2 t0; t0.x = pk2bf(ws0 * invl, ws1 * invl); t0.y = pk2bf(ws2 * invl, ws3 * invl);
    uint2 t1; t1.x = pk2bf(wd0 * invl, wd1 * invl); t1.y = pk2bf(wd2 * invl, wd3 * invl);
    wrow[l31] = t0;
    wrow[32 + l31] = t1;
  }
  // global: precomputed scores
  float sg[8] = {bflo(scu.x), bfhi(scu.x), bflo(scu.y), bfhi(scu.y),
                 bflo(scu.z), bfhi(scu.z), bflo(scu.w), bfhi(scu.w)};
  float mg = fmaxf(fmaxf(fmaxf(sg[0], sg[1]), fmaxf(sg[2], sg[3])),
                   fmaxf(fmaxf(sg[4], sg[5]), fmaxf(sg[6], sg[7])));
  float sumg = 0.f, ag[8];
  #pragma unroll
  for (int v = 0; v < 8; ++v) { ag[v] = __expf((sg[v] - mg) * scale); sumg += ag[v]; }
  float invg = 1.f / sumg;
  if (e < E && l31 < 8) ag_out[(size_t)e * 8 + l31] = ag[l31] * invg;
  float4 b4 = *reinterpret_cast<const float4*>(&bsh[4 * l31]);
  float g0 = b4.x, g1 = b4.y, g2 = b4.z, g3 = b4.w;
  #pragma unroll
  for (int v = 0; v < 8; ++v) {
    float sv = ag[v] * invg;
    float4 gv = *reinterpret_cast<const float4*>(&Gs[v * 128 + 4 * l31]);
    g0 += sv * gv.x; g1 += sv * gv.y; g2 += sv * gv.z; g3 += sv * gv.w;
  }
  if (e < E) {
    uint2 t; t.x = pk2bf(g0, g1); t.y = pk2bf(g2, g3);
    reinterpret_cast<uint2*>(glbb + (size_t)e * 128)[l31] = t;
  }
}

// ---------------- logits ----------------
__global__ __launch_bounds__(256) void k_logits(const ushortT* __restrict__ hid,
    const float* __restrict__ Wc2, const float* __restrict__ bc2,
    float* __restrict__ logits, int E)
{
  __shared__ float Wsh[640];
  __shared__ float bsh[5];
  int tid = threadIdx.x;
  for (int i = tid; i < 640; i += 256) Wsh[i] = Wc2[i];
  if (tid < 5) bsh[tid] = bc2[tid];
  __syncthreads();
  int wv = tid >> 6, lane = tid & 63;
  int e = blockIdx.x * 4 + wv;
  if (e >= E) return;
  float h0 = bf2f(hid[(size_t)e * 128 + lane]), h1 = bf2f(hid[(size_t)e * 128 + 64 + lane]);
  #pragma unroll
  for (int c = 0; c < 5; ++c) {
    float p = h0 * Wsh[c * 128 + lane] + h1 * Wsh[c * 128 + 64 + lane];
    #pragma unroll
    for (int o = 32; o; o >>= 1) p += __shfl_down(p, o);
    if (lane == 0) logits[(size_t)e * 5 + c] = p + bsh[c];
  }
}

extern "C" void kernel_launch(void* const* d_in, const int* in_sizes, int n_in,
                              void* d_out, int out_size, void* d_ws, size_t ws_size,
                              hipStream_t stream)
{
  const int*   edge_index = (const int*)d_in[0];
  const float* edge_attr  = (const float*)d_in[1];
  const float* delta_t    = (const float*)d_in[2];
  const float* memory     = (const float*)d_in[3];
  const float* W_ee  = (const float*)d_in[4];
  const float* b_ee  = (const float*)d_in[5];
  const float* W_ewg = (const float*)d_in[6];
  const float* b_ewg = (const float*)d_in[7];
  const float* gin_W1 = (const float*)d_in[8];
  const float* gin_b1 = (const float*)d_in[9];
  const float* gin_W2 = (const float*)d_in[10];
  const float* gin_b2 = (const float*)d_in[11];
  const float* W_t  = (const float*)d_in[12];
  const float* b_t  = (const float*)d_in[13];
  const float* W_ih = (const float*)d_in[14];
  const float* b_ih = (const float*)d_in[15];
  const float* W_hh = (const float*)d_in[16];
  const float* b_hh = (const float*)d_in[17];
  const float* Wq_l = (const float*)d_in[20];
  const float* bq_l = (const float*)d_in[21];
  const float* Wk_l = (const float*)d_in[22];
  const float* Wv_l = (const float*)d_in[24];
  const float* bv_l = (const float*)d_in[25];
  const float* Wo_l = (const float*)d_in[26];
  const float* bo_l = (const float*)d_in[27];
  const float* Wq_g = (const float*)d_in[28];
  const float* bq_g = (const float*)d_in[29];
  const float* Wk_g = (const float*)d_in[30];
  const float* Wv_g = (const float*)d_in[32];
  const float* bv_g = (const float*)d_in[33];
  const float* Wo_g = (const float*)d_in[34];
  const float* bo_g = (const float*)d_in[35];
  const float* Wc1  = (const float*)d_in[36];
  const float* bc1  = (const float*)d_in[37];
  const float* Wc2  = (const float*)d_in[38];
  const float* bc2  = (const float*)d_in[39];

  const int E = in_sizes[0] / 2;
  const int N = in_sizes[3] / HSZ;
  const int* srcI = edge_index;
  const int* dstI = edge_index + E;

  float* out    = (float*)d_out;
  float* logits = out;
  float* ew     = out + (size_t)E * 5;
  float* h      = out + (size_t)E * 13;                       // h_before (N,8,128) f32
  float* ag_out = out + (size_t)E * 13 + (size_t)N * 1024;

  // ---- workspace arena (units: f32 slots) ----
  float* ws = (float*)d_ws;
  size_t off = 0;
  auto alloc = [&](size_t n) { size_t o = off; off += (n + 255) & ~(size_t)255; return o; };
  float* te   = ws + alloc(128);
  float* blv  = ws + alloc(128);
  float* bqkg = ws + alloc(384);
  float* bc1p = ws + alloc(128);
  float* Kg   = ws + alloc(1024);
  float* G    = ws + alloc(1024);
  float* prw  = ws + alloc(1024);
  int* cnt = (int*)(ws + alloc(N));
  int* ofs = (int*)(ws + alloc(N + 1));
  int* cur = (int*)(ws + alloc(N));
  int* eid = (int*)(ws + alloc(E));
  ushortT* memb   = (ushortT*)(ws + alloc((size_t)N * 64));
  ushortT* eab    = (ushortT*)(ws + alloc((size_t)E * 64));
  ushortT* h1b    = (ushortT*)(ws + alloc((size_t)N * 512));
  ushortT* hnb    = (ushortT*)(ws + alloc((size_t)N * 512));
  ushortT* ghb    = (ushortT*)(ws + alloc((size_t)N * 192));
  ushortT* ginW1b = (ushortT*)(ws + alloc(16384));
  ushortT* ginW2b = (ushortT*)(ws + alloc(16384));
  ushortT* Wihb   = (ushortT*)(ws + alloc(24576));
  float*   Wl2f   = ws + alloc(32768);
  ushortT* Wc1p   = (ushortT*)(ws + alloc(32768));   // 128 x 512 bf16
  ushortT* Wqkgb  = (ushortT*)(ws + alloc(16896));   // 264 x 128 bf16
  // BR union: aggb (N*512) | attn {qkgb 132E | wsd 128E | glbb 64E} (324E)
  size_t brA = (size_t)N * 512, brC = (size_t)E * 324;
  size_t brsz = brA > brC ? brA : brC;
  float* BR = ws + alloc(brsz);
  if (ws_size < off * sizeof(float)) return;   // needs ~130 MiB

  ushortT* aggb = (ushortT*)BR;
  ushortT* qkgb = (ushortT*)BR;                        // E x 264
  ushortT* wsd  = (ushortT*)(BR + (size_t)E * 132);    // E x 256
  ushortT* glbb = (ushortT*)(BR + (size_t)E * 260);    // E x 128
  ushortT* hid  = (ushortT*)BR;                        // E x 128 (over dead qkgb)

  auto cdiv = [](int a, int b) { return (a + b - 1) / b; };

  // 0. CSR + bf16 mirrors/weights + zero pool accumulator
  hipMemsetAsync(cnt, 0, (size_t)N * sizeof(int), stream);
  hipMemsetAsync(prw, 0, 1024 * sizeof(float), stream);
  k_hist<<<cdiv(E, 256), 256, 0, stream>>>(srcI, cnt, E);
  k_scan<<<1, 1024, 0, stream>>>(cnt, ofs, cur, N);
  k_fill<<<cdiv(E, 256), 256, 0, stream>>>(srcI, cur, eid, E);
  {
    int total = N * 128 + 32768 + 32768 + 49152;
    k_cvtall<<<cdiv(total, 256), 256, 0, stream>>>(
        memory, memb, N * 128, gin_W1, ginW1b, 32768,
        gin_W2, ginW2b, 32768, W_ih, Wihb, 49152);
  }
  // 1. ea = relu(edge_attr @ W_ee^T + b_ee) -> bf16
  gemm_bf<0, 1, true, false, false><<<dim3(cdiv(E, 128), 1), 256, 0, stream>>>(
      edge_attr, nullptr, nullptr, W_ee, b_ee, eab, E, 59, 128);
  // 2. ew + prep(+te) + prep2 + gh
  k_ew<<<cdiv(E, 4), 256, 0, stream>>>(eab, memb, srcI, W_ewg, b_ewg, ew, E);
  k_prep<<<256, 256, 0, stream>>>(Wo_l, Wv_l, bv_l, bo_l, Wq_l, bq_l, Wk_l,
                                  delta_t, W_t, b_t, Wl2f, blv, Wqkgb, bqkg, te);
  k_prep2<<<256, 256, 0, stream>>>(Wc1, bc1, Wl2f, blv, Wc1p, bc1p);
  gemm_bf<0, 0, true, false, false><<<dim3(cdiv(N, 128), 3), 256, 0, stream>>>(
      memory, nullptr, nullptr, W_hh, b_hh, ghb, N, 128, 384);
  // 3. GIN layer 1 (h == broadcast memory)
  k_agg<1><<<cdiv(N, 2), 256, 0, stream>>>(memb, eab, ew, dstI, ofs, eid, aggb, N);
  k_gin<1><<<cdiv(N * 8, 128), 256, 0, stream>>>(
      memb, aggb, nullptr, h1b, ginW1b, gin_b1, ginW2b, gin_b2, N * 8);
  // 4. GIN layer 2 -> h (d_out f32)
  k_agg<2><<<cdiv(N, 2), 256, 0, stream>>>(h1b, eab, ew, dstI, ofs, eid, aggb, N);
  k_gin<2><<<cdiv(N * 8, 128), 256, 0, stream>>>(
      h1b, aggb, h, nullptr, ginW1b + 16384, gin_b1 + 128,
      ginW2b + 16384, gin_b2 + 128, N * 8);
  // 5. fused gi GEMM + GRU + pooled partials -> hnb, prw
  k_giru<<<cdiv(N * 8, 64), 512, 0, stream>>>(h, te, Wihb, b_ih, ghb, memb, hnb, prw, N * 8);
  // 6. global K/G + score-projection rows
  k_kgg<<<1, 256, 0, stream>>>(prw, Wk_g, Wv_g, bv_g, Wo_g, Kg, G, N);
  k_sc<<<4, 256, 0, stream>>>(Kg, Wq_g, bq_g, Wqkgb, bqkg);
  // 7. fused q projections + global scores (Nout=264)
  gemm_bf<0, 0, true, true, true><<<dim3(cdiv(E, 128), 3), 256, 0, stream>>>(
      eab, nullptr, nullptr, Wqkgb, bqkg, qkgb, E, 128, 264);
  // 8. fused local+global attention (2 edges/wave)
  k_lg<<<cdiv(E, 8), 256, 0, stream>>>(hnb, qkgb, srcI, dstI, G, bo_g,
                                       ag_out, wsd, glbb, E);
  // 9. classifier (localout folded in): K=512 over {ea, wsd, glbb}
  gemm_bf<4, 1, true, true, true><<<dim3(cdiv(E, 128), 1), 256, 0, stream>>>(
      eab, wsd, glbb, Wc1p, bc1p, hid, E, 512, 128);
  k_logits<<<cdiv(E, 4), 256, 0, stream>>>(hid, Wc2, bc2, logits, E);
}